// Round 5
// baseline (8606.556 us; speedup 1.0000x reference)
//
#include <hip/hip_runtime.h>
#include <cstdint>
#include <cstddef>

typedef __attribute__((ext_vector_type(4))) float f32x4;
using u16 = unsigned short;

constexpr int NL   = 4;
constexpr int DIN_ = 512;
constexpr int HM   = 1024;
constexpr int NE   = 4;
constexpr int TPD  = 4096;   // tokens per direction (B*L)
constexpr int TOK  = 8192;   // both directions

__device__ __forceinline__ float sigm(float x){ return 1.f/(1.f + __expf(-x)); }

// ---------------- prep kernels ----------------
__global__ void aneg_k(const float* __restrict__ a, float* __restrict__ o, int n){
  int i = blockIdx.x*256 + threadIdx.x;
  if (i < n) o[i] = -__expf(a[i]);
}

__global__ void xall_k(const float* __restrict__ x, float* __restrict__ o){
  const int i = blockIdx.x*256 + threadIdx.x;           // [0, 2*4*1024*256)
  const int d = i & 255, l = (i>>8)&1023, b2 = (i>>18)&3, dir = i>>20;
  const int ls = dir ? (1023 - l) : l;
  o[i] = x[((size_t)(b2<<10) + ls)*256 + d];
}

// ---------------- LN (+residual) ----------------
template<int MODE>
__global__ __launch_bounds__(256)
void lnres_k(const float* __restrict__ s1, const float* __restrict__ s2,
             const float* __restrict__ w, const float* __restrict__ b,
             float* __restrict__ fout, float* __restrict__ hnout)
{
  const int wv = threadIdx.x >> 6, lane = threadIdx.x & 63;
  const int tok = blockIdx.x*4 + wv;
  const int dir = tok >> 12;
  const size_t base = (size_t)tok*256 + lane*4;
  f32x4 r = *(const f32x4*)(s1 + base);
  if (s2){ f32x4 c = *(const f32x4*)(s2 + base); r += c; }
  float sv = r[0]+r[1]+r[2]+r[3];
  float qv = r[0]*r[0]+r[1]*r[1]+r[2]*r[2]+r[3]*r[3];
  #pragma unroll
  for (int o=32;o;o>>=1){ sv += __shfl_xor(sv,o); qv += __shfl_xor(qv,o); }
  const float mu = sv*(1.f/256.f);
  const float var = qv*(1.f/256.f) - mu*mu;
  const float inv = rsqrtf(var + 1e-5f);
  const int woff = (MODE==0) ? dir*(NL*256) : 0;
  const f32x4 w4 = *(const f32x4*)(w + woff + lane*4);
  const f32x4 b4 = *(const f32x4*)(b + woff + lane*4);
  f32x4 y;
  #pragma unroll
  for (int j=0;j<4;++j) y[j] = (r[j]-mu)*inv*w4[j] + b4[j];
  if constexpr (MODE==0){
    *(f32x4*)(fout + base) = r;
    *(f32x4*)(hnout + base) = y;
  } else {
    *(f32x4*)(fout + base) = y;
  }
}

// ---------------- fp32 tiled GEMM: C = A @ W^T ----------------
template<int CFG>
__global__ __launch_bounds__(256)
void fgemm_k(const float* __restrict__ A0, const float* __restrict__ W0,
             float* __restrict__ OF,
             const float* __restrict__ P0, const float* __restrict__ P1,
             const float* __restrict__ P2, int eidx)
{
  constexpr int KD = (CFG==0||CFG==2) ? 256 : (CFG==1 ? 512 : 1024);
  __shared__ float sAT[32*64];
  __shared__ float sBT[32*64];
  const int tid = threadIdx.x;
  const int tx = tid & 15, ty = tid >> 4;
  const int bm0 = blockIdx.x*64, bn0 = blockIdx.y*64;
  const int dir = blockIdx.z;

  const float* Az; const float* Wz;
  if constexpr (CFG==0){ Az = A0 + (size_t)dir*TPD*256; Wz = W0 + (size_t)dir*(NL*1024*256); }
  else if constexpr (CFG==1){ Az = A0 + (size_t)dir*TPD*512; Wz = W0 + (size_t)dir*(NL*256*512); }
  else if constexpr (CFG==2){ Az = A0 + (size_t)dir*TPD*256;
                              Wz = W0 + (size_t)dir*((size_t)NL*NE*HM*256) + (size_t)eidx*(HM*256); }
  else { Az = A0 + (size_t)dir*TPD*HM;
         Wz = W0 + (size_t)dir*((size_t)NL*NE*256*HM) + (size_t)eidx*(256*HM); }

  float acc[4][4] = {};

  for (int k0 = 0; k0 < KD; k0 += 32){
    #pragma unroll
    for (int s=0;s<2;++s){
      const int sl = tid + s*256;          // 0..511
      const int row = sl >> 3, kq = sl & 7;
      const f32x4 v = *(const f32x4*)(Az + (size_t)(bm0+row)*KD + k0 + kq*4);
      #pragma unroll
      for (int j=0;j<4;++j) sAT[(kq*4+j)*64 + row] = v[j];
      const f32x4 wv = *(const f32x4*)(Wz + (size_t)(bn0+row)*KD + k0 + kq*4);
      #pragma unroll
      for (int j=0;j<4;++j) sBT[(kq*4+j)*64 + row] = wv[j];
    }
    __syncthreads();
    #pragma unroll 8
    for (int k=0;k<32;++k){
      const f32x4 a4 = *(const f32x4*)(sAT + k*64 + ty*4);
      const f32x4 b4 = *(const f32x4*)(sBT + k*64 + tx*4);
      #pragma unroll
      for (int i=0;i<4;++i)
        #pragma unroll
        for (int j=0;j<4;++j) acc[i][j] += a4[i]*b4[j];
    }
    __syncthreads();
  }

  #pragma unroll
  for (int i=0;i<4;++i){
    const int row = bm0 + ty*4 + i;
    #pragma unroll
    for (int j=0;j<4;++j){
      const int col = bn0 + tx*4 + j;
      const float v = acc[i][j];
      if constexpr (CFG==0){
        OF[((size_t)dir*TPD + row)*1024 + col] = v;
      } else if constexpr (CFG==1){
        OF[((size_t)dir*TPD + row)*256 + col] = v;
      } else if constexpr (CFG==2){
        const float xv = v + P0[(size_t)dir*(NL*NE*HM) + (size_t)eidx*HM + col];
        const float ge = 0.5f*xv*(1.f + erff(xv*0.70710678118654752f));
        const float gt = P1[((size_t)dir*TPD + row)*4 + eidx];
        OF[((size_t)dir*TPD + row)*1024 + col] = ge*gt;
      } else {
        const float gt = P1[((size_t)dir*TPD + row)*4 + eidx];
        const float bias = gt * P2[(size_t)dir*(NL*NE*256) + (size_t)eidx*256 + col];
        const size_t oi = ((size_t)dir*TPD + row)*256 + col;
        OF[oi] = OF[oi] + v + bias;
      }
    }
  }
}

// ---------------- simple conv + silu ----------------
__global__ __launch_bounds__(256)
void conv_silu_k(const float* __restrict__ xz,
                 const float* __restrict__ cw, const float* __restrict__ cb,
                 float* __restrict__ uo)
{
  const int idx = blockIdx.x*256 + threadIdx.x;     // TOK*512
  const int c = idx & 511;
  const int tok = idx >> 9;                         // 0..8191
  const int dir = tok >> 12, t = tok & 1023;
  const float* cwp = cw + (size_t)dir*(NL*DIN_*4) + (size_t)c*4;
  float a = cb[(size_t)dir*(NL*DIN_) + c];
  #pragma unroll
  for (int k=0;k<4;++k){
    const int tt = t - 3 + k;
    if (tt >= 0) a += xz[((size_t)tok - 3 + k)*1024 + c] * cwp[k];
  }
  uo[(size_t)idx] = a * sigm(a);
}

// ---------------- x_proj: xd[tok,j] = sum_k u[tok,k]*xpw[j,k] ----------------
__global__ __launch_bounds__(256)
void xproj_k(const float* __restrict__ u, const float* __restrict__ xpw,
             float* __restrict__ xd)
{
  const int idx = blockIdx.x*256 + threadIdx.x;     // TOK*48
  const int j = idx % 48;
  const int tok = idx / 48;
  const int dir = tok >> 12;
  const float* wr = xpw + (size_t)dir*(NL*48*DIN_) + (size_t)j*DIN_;
  const float* ur = u + (size_t)tok*DIN_;
  float a = 0.f;
  #pragma unroll 8
  for (int k=0;k<DIN_;++k) a += ur[k]*wr[k];
  xd[(size_t)tok*48 + j] = a;
}

// ---------------- dt_proj + softplus ----------------
__global__ __launch_bounds__(256)
void dtsp_k(const float* __restrict__ xd, const float* __restrict__ dtw,
            const float* __restrict__ dtb, float* __restrict__ dto)
{
  const int idx = blockIdx.x*256 + threadIdx.x;     // TOK*512
  const int d = idx & 511;
  const int tok = idx >> 9;
  const int dir = tok >> 12;
  const float* wr = dtw + (size_t)dir*(NL*DIN_*16) + (size_t)d*16;
  const float* xr = xd + (size_t)tok*48;
  float a = dtb[(size_t)dir*(NL*DIN_) + d];
  #pragma unroll
  for (int r=0;r<16;++r) a += xr[r]*wr[r];
  dto[(size_t)idx] = (a > 20.f) ? a : log1pf(__expf(a));
}

// ---------------- direct serial scan ----------------
__global__ __launch_bounds__(256)
void scan_serial_k(const float* __restrict__ dt, const float* __restrict__ u,
                   const float* __restrict__ xd, const float* __restrict__ an,
                   const float* __restrict__ xz, const float* __restrict__ dsk,
                   float* __restrict__ ybar)
{
  const int id = blockIdx.x*256 + threadIdx.x;      // 0..4095
  const int ch = id & 511, bb = (id>>9)&3, dir = id>>11;
  const float* ap = an + (size_t)dir*(NL*DIN_*16) + (size_t)ch*16;
  float A_[16], h[16];
  #pragma unroll
  for (int n=0;n<16;++n){ A_[n] = ap[n]; h[n] = 0.f; }
  const float dval = dsk[(size_t)dir*(NL*DIN_) + ch];
  const size_t tokbase = (size_t)(dir*4+bb)*1024;
  for (int t=0;t<1024;++t){
    const size_t tok = tokbase + t;
    const float dtv = dt[tok*DIN_ + ch];
    const float uv  = u[tok*DIN_ + ch];
    const float dtu = dtv*uv;
    const float* xr = xd + tok*48;
    float y = 0.f;
    #pragma unroll
    for (int n=0;n<16;++n){
      const float e = __expf(dtv*A_[n]);
      const float hn2 = h[n]*e + dtu*xr[16+n];
      h[n] = hn2;
      y += hn2*xr[32+n];
    }
    const float zv = xz[tok*1024 + 512 + ch];
    ybar[tok*DIN_ + ch] = (y + uv*dval) * (zv * sigm(zv));
  }
}

// ---------------- curr = states + resid ; gating ----------------
__global__ __launch_bounds__(256)
void currgate_k(const float* __restrict__ st, const float* __restrict__ rs,
                const float* __restrict__ gw, const float* __restrict__ gb,
                float* __restrict__ currf, float* __restrict__ gate)
{
  const int wv = threadIdx.x>>6, lane = threadIdx.x&63;
  const int tok = blockIdx.x*4 + wv;
  const int dir = tok>>12;
  const size_t base = (size_t)tok*256 + lane*4;
  f32x4 a = *(const f32x4*)(st+base);
  { f32x4 c = *(const f32x4*)(rs+base); a += c; }
  *(f32x4*)(currf+base) = a;
  const float* gwp = gw + (size_t)dir*(NL*NE*256);
  float lg[4];
  #pragma unroll
  for (int e=0;e<4;++e){
    const float* w4 = gwp + e*256 + lane*4;
    lg[e] = a[0]*w4[0] + a[1]*w4[1] + a[2]*w4[2] + a[3]*w4[3];
  }
  #pragma unroll
  for (int o=32;o;o>>=1){
    #pragma unroll
    for (int e=0;e<4;++e) lg[e] += __shfl_xor(lg[e], o);
  }
  if (lane==0){
    const float* gbp = gb + dir*(NL*NE);
    float sc[4]; float mx = -1e30f;
    #pragma unroll
    for (int e=0;e<4;++e){ sc[e] = lg[e] + gbp[e]; mx = fmaxf(mx, sc[e]); }
    float den = 0.f;
    #pragma unroll
    for (int e=0;e<4;++e){ sc[e] = __expf(sc[e]-mx); den += sc[e]; }
    const float rden = 1.f/den;
    #pragma unroll
    for (int e=0;e<4;++e) sc[e] *= rden;
    int i1 = 0;
    #pragma unroll
    for (int e=1;e<4;++e) if (sc[e] > sc[i1]) i1 = e;
    int i2 = (i1==0)?1:0;
    #pragma unroll
    for (int e=0;e<4;++e) if (e!=i1 && sc[e] > sc[i2]) i2 = e;
    const float ssum = sc[i1] + sc[i2] + 1e-6f;
    #pragma unroll
    for (int e=0;e<4;++e)
      gate[(size_t)tok*4+e] = (e==i1) ? sc[i1]/ssum : ((e==i2) ? sc[i2]/ssum : 0.f);
  }
}

// ---------------- pooling + head ----------------
__global__ __launch_bounds__(256)
void pool_k(const float* __restrict__ fin, const float* __restrict__ fw,
            const float* __restrict__ fb, const float* __restrict__ bw,
            const float* __restrict__ bbs, float* __restrict__ pooled)
{
  __shared__ float sa[1024];
  __shared__ float red[8];
  const int blk = blockIdx.x;                         // 8 blocks
  const int dir = blk>>2, b = blk&3;
  const float* pw = dir ? bw : fw;
  const float pb = dir ? bbs[0] : fb[0];
  const int wv = threadIdx.x>>6, lane = threadIdx.x&63;
  const size_t fbase = (size_t)(dir*4+b)*1024*256;
  for (int l = wv; l < 1024; l += 4){
    const f32x4 f4 = *(const f32x4*)(fin + fbase + (size_t)l*256 + lane*4);
    const f32x4 w4 = *(const f32x4*)(pw + lane*4);
    float p = f4[0]*w4[0] + f4[1]*w4[1] + f4[2]*w4[2] + f4[3]*w4[3];
    #pragma unroll
    for (int o=32;o;o>>=1) p += __shfl_xor(p,o);
    if (lane==0) sa[l] = p + pb;
  }
  __syncthreads();
  float m = -1e30f;
  for (int l = threadIdx.x; l < 1024; l += 256) m = fmaxf(m, sa[l]);
  #pragma unroll
  for (int o=32;o;o>>=1) m = fmaxf(m, __shfl_xor(m,o));
  if (lane==0) red[wv] = m;
  __syncthreads();
  m = fmaxf(fmaxf(red[0],red[1]), fmaxf(red[2],red[3]));
  float ssum = 0.f;
  for (int l = threadIdx.x; l < 1024; l += 256){
    const float e = __expf(sa[l]-m); sa[l] = e; ssum += e;
  }
  #pragma unroll
  for (int o=32;o;o>>=1) ssum += __shfl_xor(ssum,o);
  if (lane==0) red[4+wv] = ssum;
  __syncthreads();
  const float inv = 1.f/(red[4]+red[5]+red[6]+red[7]);
  const int d = threadIdx.x;
  float acc = 0.f;
  #pragma unroll 4
  for (int l=0;l<1024;++l) acc += sa[l]*fin[fbase + (size_t)l*256 + d];
  pooled[(size_t)(dir*4+b)*256 + d] = acc*inv;
}

// output is FLOAT32 (reference returns f32) — the round-1..4 bug was writing bf16 here
__global__ void head_k(const float* __restrict__ pooled, const float* __restrict__ llw,
                       const float* __restrict__ llb, float* __restrict__ out)
{
  const int o = threadIdx.x;                          // 256
  for (int b=0;b<4;++b){
    float acc = llb[o];
    const float* wr = llw + (size_t)o*512;
    const float* pf = pooled + b*256;
    const float* pk = pooled + (4+b)*256;
    #pragma unroll 8
    for (int j=0;j<256;++j) acc += pf[j]*wr[j];
    #pragma unroll 8
    for (int j=0;j<256;++j) acc += pk[j]*wr[256+j];
    out[b*256+o] = acc;
  }
}

// ---------------- host ----------------
extern "C" void kernel_launch(void* const* d_in, const int* in_sizes, int n_in,
                              void* d_out, int out_size, void* d_ws, size_t ws_size,
                              hipStream_t stream)
{
  const float* in_x    = (const float*)d_in[0];
  const float* in_inw  = (const float*)d_in[1];
  const float* in_cw   = (const float*)d_in[2];
  const float* in_cb   = (const float*)d_in[3];
  const float* in_xpw  = (const float*)d_in[4];
  const float* in_dtw  = (const float*)d_in[5];
  const float* in_dtb  = (const float*)d_in[6];
  const float* in_alog = (const float*)d_in[7];
  const float* in_dsk  = (const float*)d_in[8];
  const float* in_ow   = (const float*)d_in[9];
  const float* in_nw   = (const float*)d_in[10];
  const float* in_nb   = (const float*)d_in[11];
  const float* in_gw   = (const float*)d_in[12];
  const float* in_gb   = (const float*)d_in[13];
  const float* in_e1w  = (const float*)d_in[14];
  const float* in_e1b  = (const float*)d_in[15];
  const float* in_e2w  = (const float*)d_in[16];
  const float* in_e2b  = (const float*)d_in[17];
  const float* in_nfw  = (const float*)d_in[18];
  const float* in_nfb  = (const float*)d_in[19];
  const float* in_fpw  = (const float*)d_in[20];
  const float* in_fpb  = (const float*)d_in[21];
  const float* in_bpw  = (const float*)d_in[22];
  const float* in_bpb  = (const float*)d_in[23];
  const float* in_llw  = (const float*)d_in[24];
  const float* in_llb  = (const float*)d_in[25];

  uint8_t* ws = (uint8_t*)d_ws;
  size_t off = 0;
  auto take = [&](size_t bytes)->size_t{
    size_t o = off; off += (bytes + 255) & ~(size_t)255; return o;
  };
  float* f_xall = (float*)(ws + take((size_t)TOK*256*4));   // reused as f_fin
  float* f_res  = (float*)(ws + take((size_t)TOK*256*4));
  float* f_st   = (float*)(ws + take((size_t)TOK*256*4));
  float* f_hn   = (float*)(ws + take((size_t)TOK*256*4));
  float* f_curr = (float*)(ws + take((size_t)TOK*256*4));
  float* f_xz   = (float*)(ws + take((size_t)TOK*1024*4));
  float* f_u    = (float*)(ws + take((size_t)TOK*DIN_*4));
  float* f_dt   = (float*)(ws + take((size_t)TOK*DIN_*4));
  float* f_ybar = (float*)(ws + take((size_t)TOK*DIN_*4));
  float* f_he   = (float*)(ws + take((size_t)TOK*HM*4));
  float* f_xd   = (float*)(ws + take((size_t)TOK*48*4));
  float* f_gate = (float*)(ws + take((size_t)TOK*4*4));
  float* f_an   = (float*)(ws + take((size_t)2*NL*DIN_*16*4));
  float* f_pool = (float*)(ws + take((size_t)8*256*4));
  float* f_fin  = f_xall;
  (void)ws_size; (void)in_sizes; (void)n_in; (void)out_size;

  aneg_k<<<256,256,0,stream>>>(in_alog, f_an, 2*NL*DIN_*16);
  xall_k<<<8192,256,0,stream>>>(in_x, f_xall);

  for (int i=0;i<NL;++i){
    lnres_k<0><<<2048,256,0,stream>>>(i==0 ? f_xall : f_res, i==0 ? nullptr : f_st,
                                      in_nw + i*256, in_nb + i*256, f_res, f_hn);
    fgemm_k<0><<<dim3(64,16,2),256,0,stream>>>(f_hn, in_inw + (size_t)i*1024*256,
                                               f_xz, nullptr, nullptr, nullptr, 0);
    conv_silu_k<<<16384,256,0,stream>>>(f_xz, in_cw + i*DIN_*4, in_cb + i*DIN_, f_u);
    xproj_k<<<1536,256,0,stream>>>(f_u, in_xpw + i*48*DIN_, f_xd);
    dtsp_k<<<16384,256,0,stream>>>(f_xd, in_dtw + i*DIN_*16, in_dtb + i*DIN_, f_dt);
    scan_serial_k<<<16,256,0,stream>>>(f_dt, f_u, f_xd, f_an + i*DIN_*16,
                                       f_xz, in_dsk + i*DIN_, f_ybar);
    fgemm_k<1><<<dim3(64,4,2),256,0,stream>>>(f_ybar, in_ow + (size_t)i*256*512,
                                              f_st, nullptr, nullptr, nullptr, 0);
    currgate_k<<<2048,256,0,stream>>>(f_st, f_res, in_gw + i*NE*256, in_gb + i*NE,
                                      f_curr, f_gate);
    for (int e=0;e<NE;++e){
      fgemm_k<2><<<dim3(64,16,2),256,0,stream>>>(f_curr, in_e1w + (size_t)i*NE*HM*256,
                                                 f_he, in_e1b + (size_t)i*NE*HM,
                                                 f_gate, nullptr, e);
      fgemm_k<3><<<dim3(64,4,2),256,0,stream>>>(f_he, in_e2w + (size_t)i*NE*256*HM,
                                                f_res, nullptr,
                                                f_gate, in_e2b + (size_t)i*NE*256, e);
    }
  }

  lnres_k<1><<<2048,256,0,stream>>>(f_res, f_st, in_nfw, in_nfb, f_fin, nullptr);
  pool_k<<<8,256,0,stream>>>(f_fin, in_fpw, in_fpb, in_bpw, in_bpb, f_pool);
  head_k<<<1,256,0,stream>>>(f_pool, in_llw, in_llb, (float*)d_out);
}

// Round 6
// 2232.923 us; speedup vs baseline: 3.8544x; 3.8544x over previous
//
#include <hip/hip_runtime.h>
#include <cstdint>
#include <cstddef>

typedef __attribute__((ext_vector_type(4))) float f32x4;
typedef __attribute__((ext_vector_type(8))) short s16x8;
typedef __attribute__((ext_vector_type(4))) short s16x4;
using u16 = unsigned short;

constexpr int NL   = 4;
constexpr int DIN_ = 512;
constexpr int HM   = 1024;
constexpr int NE   = 4;
constexpr int TPD  = 4096;   // tokens per direction (B*L)
constexpr int TOK  = 8192;   // both directions

__device__ __forceinline__ u16 f2b(float f){
  unsigned u = __builtin_bit_cast(unsigned, f);
  u += 0x7fffu + ((u >> 16) & 1u);
  return (u16)(u >> 16);
}
__device__ __forceinline__ float sigm(float x){ return 1.f/(1.f + __expf(-x)); }

// ---------------- prep kernels ----------------
__global__ void cvt_bf16_k(const float* __restrict__ s, u16* __restrict__ d, int n4){
  int i = blockIdx.x*blockDim.x + threadIdx.x;
  const int st = gridDim.x*blockDim.x;
  for (; i < n4; i += st){
    const f32x4 v = *(const f32x4*)(s + (size_t)i*4);
    s16x4 o;
    #pragma unroll
    for (int j=0;j<4;++j) o[j] = (short)f2b(v[j]);
    *(s16x4*)(d + (size_t)i*4) = o;
  }
}

__global__ void aneg_k(const float* __restrict__ a, float* __restrict__ o, int n){
  int i = blockIdx.x*256 + threadIdx.x;
  if (i < n) o[i] = -__expf(a[i]);
}

__global__ void xall_k(const float* __restrict__ x, float* __restrict__ o){
  const int i = blockIdx.x*256 + threadIdx.x;           // [0, 2*4*1024*256)
  const int d = i & 255, l = (i>>8)&1023, b2 = (i>>18)&3, dir = i>>20;
  const int ls = dir ? (1023 - l) : l;
  o[i] = x[((size_t)(b2<<10) + ls)*256 + d];
}

// ---------------- LN (+residual) ----------------
template<int MODE>
__global__ __launch_bounds__(256)
void lnres_k(const float* __restrict__ s1, const float* __restrict__ s2,
             const float* __restrict__ w, const float* __restrict__ b,
             float* __restrict__ fout, float* __restrict__ hnout)
{
  const int wv = threadIdx.x >> 6, lane = threadIdx.x & 63;
  const int tok = blockIdx.x*4 + wv;
  const int dir = tok >> 12;
  const size_t base = (size_t)tok*256 + lane*4;
  f32x4 r = *(const f32x4*)(s1 + base);
  if (s2){ f32x4 c = *(const f32x4*)(s2 + base); r += c; }
  float sv = r[0]+r[1]+r[2]+r[3];
  float qv = r[0]*r[0]+r[1]*r[1]+r[2]*r[2]+r[3]*r[3];
  #pragma unroll
  for (int o=32;o;o>>=1){ sv += __shfl_xor(sv,o); qv += __shfl_xor(qv,o); }
  const float mu = sv*(1.f/256.f);
  const float var = qv*(1.f/256.f) - mu*mu;
  const float inv = rsqrtf(var + 1e-5f);
  const int woff = (MODE==0) ? dir*(NL*256) : 0;
  const f32x4 w4 = *(const f32x4*)(w + woff + lane*4);
  const f32x4 b4 = *(const f32x4*)(b + woff + lane*4);
  f32x4 y;
  #pragma unroll
  for (int j=0;j<4;++j) y[j] = (r[j]-mu)*inv*w4[j] + b4[j];
  if constexpr (MODE==0){
    *(f32x4*)(fout + base) = r;
    *(f32x4*)(hnout + base) = y;
  } else {
    *(f32x4*)(fout + base) = y;
  }
}

// ---------------- fp32 tiled GEMM (in_proj / out_proj — gate-exact path) ----------------
// CFG 0: in_proj  K=256  N=1024 -> OF = f_xz
// CFG 1: out_proj K=512  N=256  -> OF = f_st
template<int CFG>
__global__ __launch_bounds__(256)
void fgemm_k(const float* __restrict__ A0, const float* __restrict__ W0,
             float* __restrict__ OF)
{
  constexpr int KD = (CFG==0) ? 256 : 512;
  __shared__ float sAT[32*64];
  __shared__ float sBT[32*64];
  const int tid = threadIdx.x;
  const int tx = tid & 15, ty = tid >> 4;
  const int bm0 = blockIdx.x*64, bn0 = blockIdx.y*64;
  const int dir = blockIdx.z;

  const float* Az; const float* Wz;
  if constexpr (CFG==0){ Az = A0 + (size_t)dir*TPD*256; Wz = W0 + (size_t)dir*(NL*1024*256); }
  else { Az = A0 + (size_t)dir*TPD*512; Wz = W0 + (size_t)dir*(NL*256*512); }

  float acc[4][4] = {};

  for (int k0 = 0; k0 < KD; k0 += 32){
    #pragma unroll
    for (int s=0;s<2;++s){
      const int sl = tid + s*256;          // 0..511
      const int row = sl >> 3, kq = sl & 7;
      const f32x4 v = *(const f32x4*)(Az + (size_t)(bm0+row)*KD + k0 + kq*4);
      #pragma unroll
      for (int j=0;j<4;++j) sAT[(kq*4+j)*64 + row] = v[j];
      const f32x4 wv = *(const f32x4*)(Wz + (size_t)(bn0+row)*KD + k0 + kq*4);
      #pragma unroll
      for (int j=0;j<4;++j) sBT[(kq*4+j)*64 + row] = wv[j];
    }
    __syncthreads();
    #pragma unroll 8
    for (int k=0;k<32;++k){
      const f32x4 a4 = *(const f32x4*)(sAT + k*64 + ty*4);
      const f32x4 b4 = *(const f32x4*)(sBT + k*64 + tx*4);
      #pragma unroll
      for (int i=0;i<4;++i)
        #pragma unroll
        for (int j=0;j<4;++j) acc[i][j] += a4[i]*b4[j];
    }
    __syncthreads();
  }

  #pragma unroll
  for (int i=0;i<4;++i){
    const int row = bm0 + ty*4 + i;
    #pragma unroll
    for (int j=0;j<4;++j){
      const int col = bn0 + tx*4 + j;
      if constexpr (CFG==0) OF[((size_t)dir*TPD + row)*1024 + col] = acc[i][j];
      else                  OF[((size_t)dir*TPD + row)*256  + col] = acc[i][j];
    }
  }
}

// ---------------- MFMA bf16 GEMM (MoE only; downstream of gate selection) ----------------
// CFG 2: moe h  z=dir*4+e, N=1024 K=256 -> bf16 out = gate*gelu(acc+b1)
// CFG 3: moe o  folded K=4096, N=256   -> f32 resid += acc + sum_e g*b2
template<int CFG>
__global__ __launch_bounds__(256, 2)
void gemm_k(const u16* __restrict__ A0, const u16* __restrict__ W0,
            float* OF, u16* OB,
            const float* __restrict__ P0, const float* __restrict__ P1,
            const float* __restrict__ P2)
{
  constexpr int BM = 128;
  constexpr int BN = (CFG==3) ? 64 : 128;
  constexpr int KD = (CFG==2) ? 256 : 4096;
  constexpr int LDA = KD;
  constexpr int FM = 4;
  constexpr int FN = BN/32;
  constexpr int IA = 2;
  constexpr int IB = BN/64;

  __shared__ u16 sA[BM*32];
  __shared__ u16 sB[BN*32];

  const int tid = threadIdx.x;
  const int wave = tid >> 6, lane = tid & 63;
  const int bm0 = blockIdx.x * BM, bn0 = blockIdx.y * BN;
  const int z = blockIdx.z;
  const int wm0 = (wave >> 1) * 64;
  const int wn0 = (wave & 1) * (BN/2);

  const u16* Az; const u16* Wz;
  if constexpr (CFG==2){ Az = A0 + (size_t)(z>>2)*TPD*256;
                         Wz = W0 + (size_t)(z>>2)*((size_t)NL*NE*HM*256) + (size_t)(z&3)*(HM*256); }
  else { Az = A0 + (size_t)z*TPD*4096; Wz = W0 + (size_t)z*((size_t)NL*NE*256*HM); }

  f32x4 acc[FM][FN];
  #pragma unroll
  for (int i=0;i<FM;++i)
    #pragma unroll
    for (int j=0;j<FN;++j) acc[i][j] = (f32x4){0.f,0.f,0.f,0.f};

  const int r = lane & 15, q = lane >> 4;

  for (int k0 = 0; k0 < KD; k0 += 32){
    #pragma unroll
    for (int j=0;j<IA;++j){
      const int c = (wave*IA + j)*64 + lane;
      const int m = c >> 2, kq = c & 3;
      const u16* g = Az + (size_t)(bm0 + m)*LDA + (k0 + kq*8);
      __builtin_amdgcn_global_load_lds((const __attribute__((address_space(1))) void*)g,
          (__attribute__((address_space(3))) void*)(sA + (size_t)(wave*IA + j)*512), 16, 0, 0);
    }
    #pragma unroll
    for (int j=0;j<IB;++j){
      const int c = (wave*IB + j)*64 + lane;
      const int n = c >> 2, kq = c & 3;
      const u16* g;
      if constexpr (CFG==3){
        g = Wz + ((size_t)(k0 >> 10)*256 + (bn0 + n))*1024 + ((k0 & 1023) + kq*8);
      } else {
        g = Wz + (size_t)(bn0 + n)*KD + (k0 + kq*8);
      }
      __builtin_amdgcn_global_load_lds((const __attribute__((address_space(1))) void*)g,
          (__attribute__((address_space(3))) void*)(sB + (size_t)(wave*IB + j)*512), 16, 0, 0);
    }
    __syncthreads();
    s16x8 av[FM], bv[FN];
    #pragma unroll
    for (int mi=0;mi<FM;++mi) av[mi] = *(const s16x8*)(sA + (wm0 + mi*16 + r)*32 + q*8);
    #pragma unroll
    for (int ni=0;ni<FN;++ni) bv[ni] = *(const s16x8*)(sB + (wn0 + ni*16 + r)*32 + q*8);
    #pragma unroll
    for (int mi=0;mi<FM;++mi)
      #pragma unroll
      for (int ni=0;ni<FN;++ni)
        acc[mi][ni] = __builtin_amdgcn_mfma_f32_16x16x32_bf16(av[mi], bv[ni], acc[mi][ni], 0, 0, 0);
    __syncthreads();
  }

  #pragma unroll
  for (int mi=0;mi<FM;++mi){
    #pragma unroll
    for (int ni=0;ni<FN;++ni){
      const int col = bn0 + wn0 + ni*16 + r;
      #pragma unroll
      for (int rr=0;rr<4;++rr){
        const int row = bm0 + wm0 + mi*16 + q*4 + rr;
        const float v = acc[mi][ni][rr];
        if constexpr (CFG==2){
          const int dir = z>>2, e = z&3;
          const float xv = v + P0[(size_t)dir*(NL*NE*HM) + (size_t)e*HM + col];
          const float ge = 0.5f*xv*(1.f + erff(xv*0.70710678118654752f));
          const float gt = P1[((size_t)dir*TPD + row)*4 + e];
          OB[((size_t)dir*TPD + row)*4096 + (size_t)e*1024 + col] = f2b(ge*gt);
        } else {
          const float* b2p = P2 + (size_t)z*(NL*NE*256);
          const float* gp  = P1 + ((size_t)z*TPD + row)*4;
          const float bias = gp[0]*b2p[col] + gp[1]*b2p[256+col]
                           + gp[2]*b2p[512+col] + gp[3]*b2p[768+col];
          const size_t oi = ((size_t)z*TPD + row)*256 + col;
          OF[oi] = OF[oi] + v + bias;
        }
      }
    }
  }
}

// ---------------- simple conv + silu ----------------
__global__ __launch_bounds__(256)
void conv_silu_k(const float* __restrict__ xz,
                 const float* __restrict__ cw, const float* __restrict__ cb,
                 float* __restrict__ uo)
{
  const int idx = blockIdx.x*256 + threadIdx.x;     // TOK*512
  const int c = idx & 511;
  const int tok = idx >> 9;                         // 0..8191
  const int dir = tok >> 12, t = tok & 1023;
  const float* cwp = cw + (size_t)dir*(NL*DIN_*4) + (size_t)c*4;
  float a = cb[(size_t)dir*(NL*DIN_) + c];
  #pragma unroll
  for (int k=0;k<4;++k){
    const int tt = t - 3 + k;
    if (tt >= 0) a += xz[((size_t)tok - 3 + k)*1024 + c] * cwp[k];
  }
  uo[(size_t)idx] = a * sigm(a);
}

// ---------------- x_proj ----------------
__global__ __launch_bounds__(256)
void xproj_k(const float* __restrict__ u, const float* __restrict__ xpw,
             float* __restrict__ xd)
{
  const int idx = blockIdx.x*256 + threadIdx.x;     // TOK*48
  const int j = idx % 48;
  const int tok = idx / 48;
  const int dir = tok >> 12;
  const float* wr = xpw + (size_t)dir*(NL*48*DIN_) + (size_t)j*DIN_;
  const float* ur = u + (size_t)tok*DIN_;
  float a = 0.f;
  #pragma unroll 8
  for (int k=0;k<DIN_;++k) a += ur[k]*wr[k];
  xd[(size_t)tok*48 + j] = a;
}

// ---------------- dt_proj + softplus ----------------
__global__ __launch_bounds__(256)
void dtsp_k(const float* __restrict__ xd, const float* __restrict__ dtw,
            const float* __restrict__ dtb, float* __restrict__ dto)
{
  const int idx = blockIdx.x*256 + threadIdx.x;     // TOK*512
  const int d = idx & 511;
  const int tok = idx >> 9;
  const int dir = tok >> 12;
  const float* wr = dtw + (size_t)dir*(NL*DIN_*16) + (size_t)d*16;
  const float* xr = xd + (size_t)tok*48;
  float a = dtb[(size_t)dir*(NL*DIN_) + d];
  #pragma unroll
  for (int r=0;r<16;++r) a += xr[r]*wr[r];
  dto[(size_t)idx] = (a > 20.f) ? a : log1pf(__expf(a));
}

// ---------------- chunked selective scan ----------------
// PASS 1: per-chunk local scan (h0=0) + decay product P; PASS 2: real scan
// with composed initial state, emits ybar = (y + u*D)*silu(z)
template<int PASS>
__global__ __launch_bounds__(512)
void scan_k(const float* __restrict__ dt, const float* __restrict__ u,
            const float* __restrict__ xd, const float* __restrict__ an,
            const float* __restrict__ xz, const float* __restrict__ dsk,
            float* __restrict__ hp, float* __restrict__ pp,
            float* __restrict__ ybar)
{
  const int ch = threadIdx.x;                         // 0..511
  const int blk = blockIdx.x;                         // (dir*4+b)*16 + chunk
  const int chunk = blk & 15, bb = (blk>>4)&3, dir = blk>>6;
  const size_t tokbase = (size_t)(dir*4+bb)*1024 + (size_t)chunk*64;
  const float* ap = an + (size_t)dir*(NL*DIN_*16) + (size_t)ch*16;
  float A_[16];
  #pragma unroll
  for (int n=0;n<16;++n) A_[n] = ap[n];
  const size_t scanid = (size_t)(dir*4+bb)*512 + ch;
  const size_t hbase = (scanid*16 + chunk)*16;
  float h[16], P[16];
  if constexpr (PASS==1){
    #pragma unroll
    for (int n=0;n<16;++n){ h[n]=0.f; P[n]=1.f; }
  } else {
    #pragma unroll
    for (int n=0;n<16;++n) h[n] = hp[hbase+n];
  }
  float dval = 0.f;
  if constexpr (PASS==2) dval = dsk[(size_t)dir*(NL*DIN_) + ch];
  for (int t=0;t<64;++t){
    const size_t tok = tokbase + t;
    const float dtv = dt[tok*DIN_ + ch];
    const float uv  = u[tok*DIN_ + ch];
    const float dtu = dtv*uv;
    const float* xr = xd + tok*48;
    float y = 0.f;
    #pragma unroll
    for (int n=0;n<16;++n){
      const float e = __expf(dtv*A_[n]);
      const float hn2 = h[n]*e + dtu*xr[16+n];
      h[n] = hn2;
      if constexpr (PASS==1) P[n] *= e;
      else y += hn2*xr[32+n];
    }
    if constexpr (PASS==2){
      const float zv = xz[tok*1024 + 512 + ch];
      ybar[tok*DIN_ + ch] = (y + uv*dval) * (zv * sigm(zv));
    }
  }
  if constexpr (PASS==1){
    #pragma unroll
    for (int n=0;n<16;++n){ hp[hbase+n] = h[n]; pp[hbase+n] = P[n]; }
  }
}

// compose chunk transitions: hp[chunk] := initial state for that chunk
__global__ void scanfix_k(float* __restrict__ hp, const float* __restrict__ pp){
  const int id = blockIdx.x*256 + threadIdx.x;        // 0..4095
  float s[16];
  #pragma unroll
  for (int n=0;n<16;++n) s[n] = 0.f;
  for (int c=0;c<16;++c){
    const size_t base = ((size_t)id*16 + c)*16;
    #pragma unroll
    for (int n=0;n<16;++n){
      const float hv = hp[base+n];
      const float pv = pp[base+n];
      hp[base+n] = s[n];
      s[n] = hv + pv*s[n];
    }
  }
}

// ---------------- curr = states + resid ; gating (f32-exact) ----------------
__global__ __launch_bounds__(256)
void currgate_k(const float* __restrict__ st, const float* __restrict__ rs,
                const float* __restrict__ gw, const float* __restrict__ gb,
                u16* __restrict__ currb, float* __restrict__ gate)
{
  const int wv = threadIdx.x>>6, lane = threadIdx.x&63;
  const int tok = blockIdx.x*4 + wv;
  const int dir = tok>>12;
  const size_t base = (size_t)tok*256 + lane*4;
  f32x4 a = *(const f32x4*)(st+base);
  { f32x4 c = *(const f32x4*)(rs+base); a += c; }
  s16x4 cc;
  #pragma unroll
  for (int j=0;j<4;++j) cc[j] = (short)f2b(a[j]);
  *(s16x4*)(currb+base) = cc;
  const float* gwp = gw + (size_t)dir*(NL*NE*256);
  float lg[4];
  #pragma unroll
  for (int e=0;e<4;++e){
    const float* w4 = gwp + e*256 + lane*4;
    lg[e] = a[0]*w4[0] + a[1]*w4[1] + a[2]*w4[2] + a[3]*w4[3];
  }
  #pragma unroll
  for (int o=32;o;o>>=1){
    #pragma unroll
    for (int e=0;e<4;++e) lg[e] += __shfl_xor(lg[e], o);
  }
  if (lane==0){
    const float* gbp = gb + dir*(NL*NE);
    float sc[4]; float mx = -1e30f;
    #pragma unroll
    for (int e=0;e<4;++e){ sc[e] = lg[e] + gbp[e]; mx = fmaxf(mx, sc[e]); }
    float den = 0.f;
    #pragma unroll
    for (int e=0;e<4;++e){ sc[e] = __expf(sc[e]-mx); den += sc[e]; }
    const float rden = 1.f/den;
    #pragma unroll
    for (int e=0;e<4;++e) sc[e] *= rden;
    int i1 = 0;
    #pragma unroll
    for (int e=1;e<4;++e) if (sc[e] > sc[i1]) i1 = e;
    int i2 = (i1==0)?1:0;
    #pragma unroll
    for (int e=0;e<4;++e) if (e!=i1 && sc[e] > sc[i2]) i2 = e;
    const float ssum = sc[i1] + sc[i2] + 1e-6f;
    #pragma unroll
    for (int e=0;e<4;++e)
      gate[(size_t)tok*4+e] = (e==i1) ? sc[i1]/ssum : ((e==i2) ? sc[i2]/ssum : 0.f);
  }
}

// ---------------- pooling + head ----------------
__global__ __launch_bounds__(256)
void pool_k(const float* __restrict__ fin, const float* __restrict__ fw,
            const float* __restrict__ fb, const float* __restrict__ bw,
            const float* __restrict__ bbs, float* __restrict__ pooled)
{
  __shared__ float sa[1024];
  __shared__ float red[8];
  const int blk = blockIdx.x;                         // 8 blocks
  const int dir = blk>>2, b = blk&3;
  const float* pw = dir ? bw : fw;
  const float pb = dir ? bbs[0] : fb[0];
  const int wv = threadIdx.x>>6, lane = threadIdx.x&63;
  const size_t fbase = (size_t)(dir*4+b)*1024*256;
  for (int l = wv; l < 1024; l += 4){
    const f32x4 f4 = *(const f32x4*)(fin + fbase + (size_t)l*256 + lane*4);
    const f32x4 w4 = *(const f32x4*)(pw + lane*4);
    float p = f4[0]*w4[0] + f4[1]*w4[1] + f4[2]*w4[2] + f4[3]*w4[3];
    #pragma unroll
    for (int o=32;o;o>>=1) p += __shfl_xor(p,o);
    if (lane==0) sa[l] = p + pb;
  }
  __syncthreads();
  float m = -1e30f;
  for (int l = threadIdx.x; l < 1024; l += 256) m = fmaxf(m, sa[l]);
  #pragma unroll
  for (int o=32;o;o>>=1) m = fmaxf(m, __shfl_xor(m,o));
  if (lane==0) red[wv] = m;
  __syncthreads();
  m = fmaxf(fmaxf(red[0],red[1]), fmaxf(red[2],red[3]));
  float ssum = 0.f;
  for (int l = threadIdx.x; l < 1024; l += 256){
    const float e = __expf(sa[l]-m); sa[l] = e; ssum += e;
  }
  #pragma unroll
  for (int o=32;o;o>>=1) ssum += __shfl_xor(ssum,o);
  if (lane==0) red[4+wv] = ssum;
  __syncthreads();
  const float inv = 1.f/(red[4]+red[5]+red[6]+red[7]);
  const int d = threadIdx.x;
  float acc = 0.f;
  #pragma unroll 4
  for (int l=0;l<1024;++l) acc += sa[l]*fin[fbase + (size_t)l*256 + d];
  pooled[(size_t)(dir*4+b)*256 + d] = acc*inv;
}

// output is FLOAT32
__global__ void head_k(const float* __restrict__ pooled, const float* __restrict__ llw,
                       const float* __restrict__ llb, float* __restrict__ out)
{
  const int o = threadIdx.x;                          // 256
  for (int b=0;b<4;++b){
    float acc = llb[o];
    const float* wr = llw + (size_t)o*512;
    const float* pf = pooled + b*256;
    const float* pk = pooled + (4+b)*256;
    #pragma unroll 8
    for (int j=0;j<256;++j) acc += pf[j]*wr[j];
    #pragma unroll 8
    for (int j=0;j<256;++j) acc += pk[j]*wr[256+j];
    out[b*256+o] = acc;
  }
}

// ---------------- host ----------------
extern "C" void kernel_launch(void* const* d_in, const int* in_sizes, int n_in,
                              void* d_out, int out_size, void* d_ws, size_t ws_size,
                              hipStream_t stream)
{
  const float* in_x    = (const float*)d_in[0];
  const float* in_inw  = (const float*)d_in[1];
  const float* in_cw   = (const float*)d_in[2];
  const float* in_cb   = (const float*)d_in[3];
  const float* in_xpw  = (const float*)d_in[4];
  const float* in_dtw  = (const float*)d_in[5];
  const float* in_dtb  = (const float*)d_in[6];
  const float* in_alog = (const float*)d_in[7];
  const float* in_dsk  = (const float*)d_in[8];
  const float* in_ow   = (const float*)d_in[9];
  const float* in_nw   = (const float*)d_in[10];
  const float* in_nb   = (const float*)d_in[11];
  const float* in_gw   = (const float*)d_in[12];
  const float* in_gb   = (const float*)d_in[13];
  const float* in_e1w  = (const float*)d_in[14];
  const float* in_e1b  = (const float*)d_in[15];
  const float* in_e2w  = (const float*)d_in[16];
  const float* in_e2b  = (const float*)d_in[17];
  const float* in_nfw  = (const float*)d_in[18];
  const float* in_nfb  = (const float*)d_in[19];
  const float* in_fpw  = (const float*)d_in[20];
  const float* in_fpb  = (const float*)d_in[21];
  const float* in_bpw  = (const float*)d_in[22];
  const float* in_bpb  = (const float*)d_in[23];
  const float* in_llw  = (const float*)d_in[24];
  const float* in_llb  = (const float*)d_in[25];

  uint8_t* ws = (uint8_t*)d_ws;
  size_t off = 0;
  auto take = [&](size_t bytes)->size_t{
    size_t o = off; off += (bytes + 255) & ~(size_t)255; return o;
  };
  float* f_xall = (float*)(ws + take((size_t)TOK*256*4));   // reused as f_fin
  float* f_res  = (float*)(ws + take((size_t)TOK*256*4));
  float* f_st   = (float*)(ws + take((size_t)TOK*256*4));
  float* f_hn   = (float*)(ws + take((size_t)TOK*256*4));
  float* f_xz   = (float*)(ws + take((size_t)TOK*1024*4));
  float* f_u    = (float*)(ws + take((size_t)TOK*DIN_*4));
  float* f_dt   = (float*)(ws + take((size_t)TOK*DIN_*4));
  float* f_ybar = (float*)(ws + take((size_t)TOK*DIN_*4));
  float* f_xd   = (float*)(ws + take((size_t)TOK*48*4));
  float* f_hp   = (float*)(ws + take((size_t)4096*16*16*4));
  float* f_pp   = (float*)(ws + take((size_t)4096*16*16*4));
  float* f_gate = (float*)(ws + take((size_t)TOK*4*4));
  float* f_an   = (float*)(ws + take((size_t)2*NL*DIN_*16*4));
  float* f_pool = (float*)(ws + take((size_t)8*256*4));
  u16* b_curr = (u16*)(ws + take((size_t)TOK*256*2));
  u16* b_h    = (u16*)(ws + take((size_t)TOK*4096*2));
  u16* b_we1  = (u16*)(ws + take((size_t)2*NL*NE*HM*256*2));
  u16* b_we2  = (u16*)(ws + take((size_t)2*NL*NE*256*HM*2));
  float* f_fin  = f_xall;
  (void)ws_size; (void)in_sizes; (void)n_in; (void)out_size;

  // prep: MoE weights -> bf16 once
  cvt_bf16_k<<<2048,256,0,stream>>>(in_e1w, b_we1, 2*NL*NE*HM*256/4);
  cvt_bf16_k<<<2048,256,0,stream>>>(in_e2w, b_we2, 2*NL*NE*256*HM/4);
  aneg_k<<<256,256,0,stream>>>(in_alog, f_an, 2*NL*DIN_*16);
  xall_k<<<8192,256,0,stream>>>(in_x, f_xall);

  for (int i=0;i<NL;++i){
    lnres_k<0><<<2048,256,0,stream>>>(i==0 ? f_xall : f_res, i==0 ? nullptr : f_st,
                                      in_nw + i*256, in_nb + i*256, f_res, f_hn);
    fgemm_k<0><<<dim3(64,16,2),256,0,stream>>>(f_hn, in_inw + (size_t)i*1024*256, f_xz);
    conv_silu_k<<<16384,256,0,stream>>>(f_xz, in_cw + i*DIN_*4, in_cb + i*DIN_, f_u);
    xproj_k<<<1536,256,0,stream>>>(f_u, in_xpw + i*48*DIN_, f_xd);
    dtsp_k<<<16384,256,0,stream>>>(f_xd, in_dtw + i*DIN_*16, in_dtb + i*DIN_, f_dt);
    scan_k<1><<<128,512,0,stream>>>(f_dt, f_u, f_xd, f_an + i*DIN_*16,
                                    nullptr, nullptr, f_hp, f_pp, nullptr);
    scanfix_k<<<16,256,0,stream>>>(f_hp, f_pp);
    scan_k<2><<<128,512,0,stream>>>(f_dt, f_u, f_xd, f_an + i*DIN_*16,
                                    f_xz, in_dsk + i*DIN_, f_hp, f_pp, f_ybar);
    fgemm_k<1><<<dim3(64,4,2),256,0,stream>>>(f_ybar, in_ow + (size_t)i*256*512, f_st);
    currgate_k<<<2048,256,0,stream>>>(f_st, f_res, in_gw + i*NE*256, in_gb + i*NE,
                                      b_curr, f_gate);
    gemm_k<2><<<dim3(32,8,8),256,0,stream>>>(b_curr, b_we1 + (size_t)i*NE*HM*256,
                                             nullptr, b_h,
                                             in_e1b + i*NE*HM, f_gate, nullptr);
    gemm_k<3><<<dim3(32,4,2),256,0,stream>>>(b_h, b_we2 + (size_t)i*NE*256*HM,
                                             f_res, nullptr,
                                             nullptr, f_gate, in_e2b + i*NE*256);
  }

  lnres_k<1><<<2048,256,0,stream>>>(f_res, f_st, in_nfw, in_nfb, f_fin, nullptr);
  pool_k<<<8,256,0,stream>>>(f_fin, in_fpw, in_fpb, in_bpw, in_bpb, f_pool);
  head_k<<<1,256,0,stream>>>(f_pool, in_llw, in_llb, (float*)d_out);
}

// Round 7
// 1709.728 us; speedup vs baseline: 5.0339x; 1.3060x over previous
//
#include <hip/hip_runtime.h>
#include <cstdint>
#include <cstddef>

typedef __attribute__((ext_vector_type(4))) float f32x4;
typedef __attribute__((ext_vector_type(8))) short s16x8;
typedef __attribute__((ext_vector_type(4))) short s16x4;
using u16 = unsigned short;

constexpr int NL   = 4;
constexpr int DIN_ = 512;
constexpr int HM   = 1024;
constexpr int NE   = 4;
constexpr int TPD  = 4096;   // tokens per direction (B*L)
constexpr int TOK  = 8192;   // both directions

__device__ __forceinline__ u16 f2b(float f){
  unsigned u = __builtin_bit_cast(unsigned, f);
  u += 0x7fffu + ((u >> 16) & 1u);
  return (u16)(u >> 16);
}
__device__ __forceinline__ float sigm(float x){ return 1.f/(1.f + __expf(-x)); }

// ---------------- prep kernels ----------------
__global__ void cvt_bf16_k(const float* __restrict__ s, u16* __restrict__ d, int n4){
  int i = blockIdx.x*blockDim.x + threadIdx.x;
  const int st = gridDim.x*blockDim.x;
  for (; i < n4; i += st){
    const f32x4 v = *(const f32x4*)(s + (size_t)i*4);
    s16x4 o;
    #pragma unroll
    for (int j=0;j<4;++j) o[j] = (short)f2b(v[j]);
    *(s16x4*)(d + (size_t)i*4) = o;
  }
}

__global__ void aneg_k(const float* __restrict__ a, float* __restrict__ o, int n){
  int i = blockIdx.x*256 + threadIdx.x;
  if (i < n) o[i] = -__expf(a[i]);
}

__global__ void xall_k(const float* __restrict__ x, float* __restrict__ o){
  const int i = blockIdx.x*256 + threadIdx.x;           // [0, 2*4*1024*256)
  const int d = i & 255, l = (i>>8)&1023, b2 = (i>>18)&3, dir = i>>20;
  const int ls = dir ? (1023 - l) : l;
  o[i] = x[((size_t)(b2<<10) + ls)*256 + d];
}

// ---------------- LN (+residual) ----------------
// MODE 0: fout = s1(+s2) residual (f32); hnout = LN result (bf16)
// MODE 1: fout = LN(s1+s2) (f32)
template<int MODE>
__global__ __launch_bounds__(256)
void lnres_k(const float* __restrict__ s1, const float* __restrict__ s2,
             const float* __restrict__ w, const float* __restrict__ b,
             float* __restrict__ fout, u16* __restrict__ hnout)
{
  const int wv = threadIdx.x >> 6, lane = threadIdx.x & 63;
  const int tok = blockIdx.x*4 + wv;
  const int dir = tok >> 12;
  const size_t base = (size_t)tok*256 + lane*4;
  f32x4 r = *(const f32x4*)(s1 + base);
  if (s2){ f32x4 c = *(const f32x4*)(s2 + base); r += c; }
  float sv = r[0]+r[1]+r[2]+r[3];
  float qv = r[0]*r[0]+r[1]*r[1]+r[2]*r[2]+r[3]*r[3];
  #pragma unroll
  for (int o=32;o;o>>=1){ sv += __shfl_xor(sv,o); qv += __shfl_xor(qv,o); }
  const float mu = sv*(1.f/256.f);
  const float var = qv*(1.f/256.f) - mu*mu;
  const float inv = rsqrtf(var + 1e-5f);
  const int woff = (MODE==0) ? dir*(NL*256) : 0;
  const f32x4 w4 = *(const f32x4*)(w + woff + lane*4);
  const f32x4 b4 = *(const f32x4*)(b + woff + lane*4);
  f32x4 y;
  #pragma unroll
  for (int j=0;j<4;++j) y[j] = (r[j]-mu)*inv*w4[j] + b4[j];
  if constexpr (MODE==0){
    *(f32x4*)(fout + base) = r;
    s16x4 hh;
    #pragma unroll
    for (int j=0;j<4;++j) hh[j] = (short)f2b(y[j]);
    *(s16x4*)(hnout + base) = hh;
  } else {
    *(f32x4*)(fout + base) = y;
  }
}

// ---------------- MFMA bf16 GEMM: C = A @ W^T ----------------
// CFG 0: in_proj  N=1024 K=256  -> OF f32 (f_xz)
// CFG 1: out_proj N=256  K=512  -> OF f32 (f_st)
// CFG 2: moe h    z=dir*4+e, N=1024 K=256 -> OB bf16 = gate*gelu(acc+b1)
// CFG 3: moe o    folded K=4096, N=256    -> OF f32 resid += acc + sum_e g*b2
template<int CFG>
__global__ __launch_bounds__(256, 2)
void gemm_k(const u16* __restrict__ A0, const u16* __restrict__ W0,
            float* OF, u16* OB,
            const float* __restrict__ P0, const float* __restrict__ P1,
            const float* __restrict__ P2)
{
  constexpr int BM = 128;
  constexpr int BN = (CFG==1 || CFG==3) ? 64 : 128;
  constexpr int KD = (CFG==0 || CFG==2) ? 256 : (CFG==1 ? 512 : 4096);
  constexpr int LDA = KD;
  constexpr int FM = 4;
  constexpr int FN = BN/32;
  constexpr int IA = 2;
  constexpr int IB = BN/64;

  __shared__ u16 sA[BM*32];
  __shared__ u16 sB[BN*32];

  const int tid = threadIdx.x;
  const int wave = tid >> 6, lane = tid & 63;
  const int bm0 = blockIdx.x * BM, bn0 = blockIdx.y * BN;
  const int z = blockIdx.z;
  const int wm0 = (wave >> 1) * 64;
  const int wn0 = (wave & 1) * (BN/2);

  const u16* Az; const u16* Wz;
  if constexpr (CFG==0){ Az = A0 + (size_t)z*TPD*256;  Wz = W0 + (size_t)z*(NL*1024*256); }
  else if constexpr (CFG==1){ Az = A0 + (size_t)z*TPD*512; Wz = W0 + (size_t)z*(NL*256*512); }
  else if constexpr (CFG==2){ Az = A0 + (size_t)(z>>2)*TPD*256;
                              Wz = W0 + (size_t)(z>>2)*((size_t)NL*NE*HM*256) + (size_t)(z&3)*(HM*256); }
  else { Az = A0 + (size_t)z*TPD*4096; Wz = W0 + (size_t)z*((size_t)NL*NE*256*HM); }

  f32x4 acc[FM][FN];
  #pragma unroll
  for (int i=0;i<FM;++i)
    #pragma unroll
    for (int j=0;j<FN;++j) acc[i][j] = (f32x4){0.f,0.f,0.f,0.f};

  const int r = lane & 15, q = lane >> 4;

  for (int k0 = 0; k0 < KD; k0 += 32){
    #pragma unroll
    for (int j=0;j<IA;++j){
      const int c = (wave*IA + j)*64 + lane;
      const int m = c >> 2, kq = c & 3;
      const u16* g = Az + (size_t)(bm0 + m)*LDA + (k0 + kq*8);
      __builtin_amdgcn_global_load_lds((const __attribute__((address_space(1))) void*)g,
          (__attribute__((address_space(3))) void*)(sA + (size_t)(wave*IA + j)*512), 16, 0, 0);
    }
    #pragma unroll
    for (int j=0;j<IB;++j){
      const int c = (wave*IB + j)*64 + lane;
      const int n = c >> 2, kq = c & 3;
      const u16* g;
      if constexpr (CFG==3){
        g = Wz + ((size_t)(k0 >> 10)*256 + (bn0 + n))*1024 + ((k0 & 1023) + kq*8);
      } else {
        g = Wz + (size_t)(bn0 + n)*KD + (k0 + kq*8);
      }
      __builtin_amdgcn_global_load_lds((const __attribute__((address_space(1))) void*)g,
          (__attribute__((address_space(3))) void*)(sB + (size_t)(wave*IB + j)*512), 16, 0, 0);
    }
    __syncthreads();
    s16x8 av[FM], bv[FN];
    #pragma unroll
    for (int mi=0;mi<FM;++mi) av[mi] = *(const s16x8*)(sA + (wm0 + mi*16 + r)*32 + q*8);
    #pragma unroll
    for (int ni=0;ni<FN;++ni) bv[ni] = *(const s16x8*)(sB + (wn0 + ni*16 + r)*32 + q*8);
    #pragma unroll
    for (int mi=0;mi<FM;++mi)
      #pragma unroll
      for (int ni=0;ni<FN;++ni)
        acc[mi][ni] = __builtin_amdgcn_mfma_f32_16x16x32_bf16(av[mi], bv[ni], acc[mi][ni], 0, 0, 0);
    __syncthreads();
  }

  #pragma unroll
  for (int mi=0;mi<FM;++mi){
    #pragma unroll
    for (int ni=0;ni<FN;++ni){
      const int col = bn0 + wn0 + ni*16 + r;
      #pragma unroll
      for (int rr=0;rr<4;++rr){
        const int row = bm0 + wm0 + mi*16 + q*4 + rr;
        const float v = acc[mi][ni][rr];
        if constexpr (CFG==0){
          OF[((size_t)z*TPD + row)*1024 + col] = v;
        } else if constexpr (CFG==1){
          OF[((size_t)z*TPD + row)*256 + col] = v;
        } else if constexpr (CFG==2){
          const int dir = z>>2, e = z&3;
          const float xv = v + P0[(size_t)dir*(NL*NE*HM) + (size_t)e*HM + col];
          const float ge = 0.5f*xv*(1.f + erff(xv*0.70710678118654752f));
          const float gt = P1[((size_t)dir*TPD + row)*4 + e];
          OB[((size_t)dir*TPD + row)*4096 + (size_t)e*1024 + col] = f2b(ge*gt);
        } else {
          const float* b2p = P2 + (size_t)z*(NL*NE*256);
          const float* gp  = P1 + ((size_t)z*TPD + row)*4;
          const float bias = gp[0]*b2p[col] + gp[1]*b2p[256+col]
                           + gp[2]*b2p[512+col] + gp[3]*b2p[768+col];
          const size_t oi = ((size_t)z*TPD + row)*256 + col;
          OF[oi] = OF[oi] + v + bias;
        }
      }
    }
  }
}

// ---------------- simple conv + silu ----------------
__global__ __launch_bounds__(256)
void conv_silu_k(const float* __restrict__ xz,
                 const float* __restrict__ cw, const float* __restrict__ cb,
                 float* __restrict__ uo)
{
  const int idx = blockIdx.x*256 + threadIdx.x;     // TOK*512
  const int c = idx & 511;
  const int tok = idx >> 9;                         // 0..8191
  const int dir = tok >> 12, t = tok & 1023;
  const float* cwp = cw + (size_t)dir*(NL*DIN_*4) + (size_t)c*4;
  float a = cb[(size_t)dir*(NL*DIN_) + c];
  #pragma unroll
  for (int k=0;k<4;++k){
    const int tt = t - 3 + k;
    if (tt >= 0) a += xz[((size_t)tok - 3 + k)*1024 + c] * cwp[k];
  }
  uo[(size_t)idx] = a * sigm(a);
}

// ---------------- x_proj ----------------
__global__ __launch_bounds__(256)
void xproj_k(const float* __restrict__ u, const float* __restrict__ xpw,
             float* __restrict__ xd)
{
  const int idx = blockIdx.x*256 + threadIdx.x;     // TOK*48
  const int j = idx % 48;
  const int tok = idx / 48;
  const int dir = tok >> 12;
  const float* wr = xpw + (size_t)dir*(NL*48*DIN_) + (size_t)j*DIN_;
  const float* ur = u + (size_t)tok*DIN_;
  float a = 0.f;
  #pragma unroll 8
  for (int k=0;k<DIN_;++k) a += ur[k]*wr[k];
  xd[(size_t)tok*48 + j] = a;
}

// ---------------- dt_proj + softplus ----------------
__global__ __launch_bounds__(256)
void dtsp_k(const float* __restrict__ xd, const float* __restrict__ dtw,
            const float* __restrict__ dtb, float* __restrict__ dto)
{
  const int idx = blockIdx.x*256 + threadIdx.x;     // TOK*512
  const int d = idx & 511;
  const int tok = idx >> 9;
  const int dir = tok >> 12;
  const float* wr = dtw + (size_t)dir*(NL*DIN_*16) + (size_t)d*16;
  const float* xr = xd + (size_t)tok*48;
  float a = dtb[(size_t)dir*(NL*DIN_) + d];
  #pragma unroll
  for (int r=0;r<16;++r) a += xr[r]*wr[r];
  dto[(size_t)idx] = (a > 20.f) ? a : log1pf(__expf(a));
}

// ---------------- chunked selective scan ----------------
template<int PASS>
__global__ __launch_bounds__(512)
void scan_k(const float* __restrict__ dt, const float* __restrict__ u,
            const float* __restrict__ xd, const float* __restrict__ an,
            const float* __restrict__ xz, const float* __restrict__ dsk,
            float* __restrict__ hp, float* __restrict__ pp,
            u16* __restrict__ ybar)
{
  const int ch = threadIdx.x;                         // 0..511
  const int blk = blockIdx.x;                         // (dir*4+b)*16 + chunk
  const int chunk = blk & 15, bb = (blk>>4)&3, dir = blk>>6;
  const size_t tokbase = (size_t)(dir*4+bb)*1024 + (size_t)chunk*64;
  const float* ap = an + (size_t)dir*(NL*DIN_*16) + (size_t)ch*16;
  float A_[16];
  #pragma unroll
  for (int n=0;n<16;++n) A_[n] = ap[n];
  const size_t scanid = (size_t)(dir*4+bb)*512 + ch;
  const size_t hbase = (scanid*16 + chunk)*16;
  float h[16], P[16];
  if constexpr (PASS==1){
    #pragma unroll
    for (int n=0;n<16;++n){ h[n]=0.f; P[n]=1.f; }
  } else {
    #pragma unroll
    for (int n=0;n<16;++n) h[n] = hp[hbase+n];
  }
  float dval = 0.f;
  if constexpr (PASS==2) dval = dsk[(size_t)dir*(NL*DIN_) + ch];
  for (int t=0;t<64;++t){
    const size_t tok = tokbase + t;
    const float dtv = dt[tok*DIN_ + ch];
    const float uv  = u[tok*DIN_ + ch];
    const float dtu = dtv*uv;
    const float* xr = xd + tok*48;
    float y = 0.f;
    #pragma unroll
    for (int n=0;n<16;++n){
      const float e = __expf(dtv*A_[n]);
      const float hn2 = h[n]*e + dtu*xr[16+n];
      h[n] = hn2;
      if constexpr (PASS==1) P[n] *= e;
      else y += hn2*xr[32+n];
    }
    if constexpr (PASS==2){
      const float zv = xz[tok*1024 + 512 + ch];
      ybar[tok*DIN_ + ch] = f2b((y + uv*dval) * (zv * sigm(zv)));
    }
  }
  if constexpr (PASS==1){
    #pragma unroll
    for (int n=0;n<16;++n){ hp[hbase+n] = h[n]; pp[hbase+n] = P[n]; }
  }
}

__global__ void scanfix_k(float* __restrict__ hp, const float* __restrict__ pp){
  const int id = blockIdx.x*256 + threadIdx.x;        // 0..4095
  float s[16];
  #pragma unroll
  for (int n=0;n<16;++n) s[n] = 0.f;
  for (int c=0;c<16;++c){
    const size_t base = ((size_t)id*16 + c)*16;
    #pragma unroll
    for (int n=0;n<16;++n){
      const float hv = hp[base+n];
      const float pv = pp[base+n];
      hp[base+n] = s[n];
      s[n] = hv + pv*s[n];
    }
  }
}

// ---------------- curr = states + resid ; gating (f32) ----------------
__global__ __launch_bounds__(256)
void currgate_k(const float* __restrict__ st, const float* __restrict__ rs,
                const float* __restrict__ gw, const float* __restrict__ gb,
                u16* __restrict__ currb, float* __restrict__ gate)
{
  const int wv = threadIdx.x>>6, lane = threadIdx.x&63;
  const int tok = blockIdx.x*4 + wv;
  const int dir = tok>>12;
  const size_t base = (size_t)tok*256 + lane*4;
  f32x4 a = *(const f32x4*)(st+base);
  { f32x4 c = *(const f32x4*)(rs+base); a += c; }
  s16x4 cc;
  #pragma unroll
  for (int j=0;j<4;++j) cc[j] = (short)f2b(a[j]);
  *(s16x4*)(currb+base) = cc;
  const float* gwp = gw + (size_t)dir*(NL*NE*256);
  float lg[4];
  #pragma unroll
  for (int e=0;e<4;++e){
    const float* w4 = gwp + e*256 + lane*4;
    lg[e] = a[0]*w4[0] + a[1]*w4[1] + a[2]*w4[2] + a[3]*w4[3];
  }
  #pragma unroll
  for (int o=32;o;o>>=1){
    #pragma unroll
    for (int e=0;e<4;++e) lg[e] += __shfl_xor(lg[e], o);
  }
  if (lane==0){
    const float* gbp = gb + dir*(NL*NE);
    float sc[4]; float mx = -1e30f;
    #pragma unroll
    for (int e=0;e<4;++e){ sc[e] = lg[e] + gbp[e]; mx = fmaxf(mx, sc[e]); }
    float den = 0.f;
    #pragma unroll
    for (int e=0;e<4;++e){ sc[e] = __expf(sc[e]-mx); den += sc[e]; }
    const float rden = 1.f/den;
    #pragma unroll
    for (int e=0;e<4;++e) sc[e] *= rden;
    int i1 = 0;
    #pragma unroll
    for (int e=1;e<4;++e) if (sc[e] > sc[i1]) i1 = e;
    int i2 = (i1==0)?1:0;
    #pragma unroll
    for (int e=0;e<4;++e) if (e!=i1 && sc[e] > sc[i2]) i2 = e;
    const float ssum = sc[i1] + sc[i2] + 1e-6f;
    #pragma unroll
    for (int e=0;e<4;++e)
      gate[(size_t)tok*4+e] = (e==i1) ? sc[i1]/ssum : ((e==i2) ? sc[i2]/ssum : 0.f);
  }
}

// ---------------- pooling (parallel, 4-stage) ----------------
// stage 1: raw scores, 64 blocks
__global__ __launch_bounds__(256)
void poolscore_k(const float* __restrict__ fin, const float* __restrict__ fw,
                 const float* __restrict__ fb, const float* __restrict__ bw,
                 const float* __restrict__ bbs, float* __restrict__ score)
{
  const int blk = blockIdx.x;                   // p = blk>>3, g = blk&7
  const int p = blk >> 3, g = blk & 7;
  const int dir = p >> 2;
  const float* pw = dir ? bw : fw;
  const float pb = dir ? bbs[0] : fb[0];
  const int wv = threadIdx.x>>6, lane = threadIdx.x&63;
  const size_t fbase = (size_t)p*1024*256;
  const f32x4 w4 = *(const f32x4*)(pw + lane*4);
  for (int l = g*128 + wv; l < (g+1)*128; l += 4){
    const f32x4 f4 = *(const f32x4*)(fin + fbase + (size_t)l*256 + lane*4);
    float pv = f4[0]*w4[0] + f4[1]*w4[1] + f4[2]*w4[2] + f4[3]*w4[3];
    #pragma unroll
    for (int o=32;o;o>>=1) pv += __shfl_xor(pv,o);
    if (lane==0) score[p*1024 + l] = pv + pb;
  }
}

// stage 2: softmax-normalize scores in place, 8 blocks
__global__ __launch_bounds__(256)
void poolnorm_k(float* __restrict__ score)
{
  __shared__ float red[8];
  const int p = blockIdx.x;
  const int tid = threadIdx.x, wv = tid>>6, lane = tid&63;
  float* s = score + p*1024;
  float v[4];
  float m = -1e30f;
  #pragma unroll
  for (int j=0;j<4;++j){ v[j] = s[tid + j*256]; m = fmaxf(m, v[j]); }
  #pragma unroll
  for (int o=32;o;o>>=1) m = fmaxf(m, __shfl_xor(m,o));
  if (lane==0) red[wv] = m;
  __syncthreads();
  m = fmaxf(fmaxf(red[0],red[1]), fmaxf(red[2],red[3]));
  float ssum = 0.f;
  #pragma unroll
  for (int j=0;j<4;++j){ v[j] = __expf(v[j]-m); ssum += v[j]; }
  #pragma unroll
  for (int o=32;o;o>>=1) ssum += __shfl_xor(ssum,o);
  if (lane==0) red[4+wv] = ssum;
  __syncthreads();
  const float inv = 1.f/(red[4]+red[5]+red[6]+red[7]);
  #pragma unroll
  for (int j=0;j<4;++j) s[tid + j*256] = v[j]*inv;
}

// stage 3: partial weighted sums, 128 blocks
__global__ __launch_bounds__(256)
void poolsum_k(const float* __restrict__ fin, const float* __restrict__ score,
               float* __restrict__ part)
{
  const int blk = blockIdx.x;                   // p = blk>>4, g = blk&15
  const int p = blk >> 4, g = blk & 15;
  const int d = threadIdx.x;
  const size_t fbase = (size_t)p*1024*256;
  float acc = 0.f;
  #pragma unroll 4
  for (int l = g*64; l < (g+1)*64; ++l)
    acc += score[p*1024 + l] * fin[fbase + (size_t)l*256 + d];
  part[((size_t)p*16 + g)*256 + d] = acc;
}

// stage 4: reduce partials + head (f32 out)
__global__ __launch_bounds__(256)
void head_k(const float* __restrict__ part, const float* __restrict__ llw,
            const float* __restrict__ llb, float* __restrict__ out)
{
  __shared__ float sp[8*256];
  const int d = threadIdx.x;
  #pragma unroll
  for (int p=0;p<8;++p){
    float a = 0.f;
    #pragma unroll
    for (int g=0;g<16;++g) a += part[((size_t)p*16+g)*256 + d];
    sp[p*256 + d] = a;
  }
  __syncthreads();
  const int o = d;
  for (int b=0;b<4;++b){
    float acc = llb[o];
    const float* wr = llw + (size_t)o*512;
    const float* pf = sp + b*256;
    const float* pk = sp + (4+b)*256;
    #pragma unroll 8
    for (int j=0;j<256;++j) acc += pf[j]*wr[j];
    #pragma unroll 8
    for (int j=0;j<256;++j) acc += pk[j]*wr[256+j];
    out[b*256+o] = acc;
  }
}

// ---------------- host ----------------
extern "C" void kernel_launch(void* const* d_in, const int* in_sizes, int n_in,
                              void* d_out, int out_size, void* d_ws, size_t ws_size,
                              hipStream_t stream)
{
  const float* in_x    = (const float*)d_in[0];
  const float* in_inw  = (const float*)d_in[1];
  const float* in_cw   = (const float*)d_in[2];
  const float* in_cb   = (const float*)d_in[3];
  const float* in_xpw  = (const float*)d_in[4];
  const float* in_dtw  = (const float*)d_in[5];
  const float* in_dtb  = (const float*)d_in[6];
  const float* in_alog = (const float*)d_in[7];
  const float* in_dsk  = (const float*)d_in[8];
  const float* in_ow   = (const float*)d_in[9];
  const float* in_nw   = (const float*)d_in[10];
  const float* in_nb   = (const float*)d_in[11];
  const float* in_gw   = (const float*)d_in[12];
  const float* in_gb   = (const float*)d_in[13];
  const float* in_e1w  = (const float*)d_in[14];
  const float* in_e1b  = (const float*)d_in[15];
  const float* in_e2w  = (const float*)d_in[16];
  const float* in_e2b  = (const float*)d_in[17];
  const float* in_nfw  = (const float*)d_in[18];
  const float* in_nfb  = (const float*)d_in[19];
  const float* in_fpw  = (const float*)d_in[20];
  const float* in_fpb  = (const float*)d_in[21];
  const float* in_bpw  = (const float*)d_in[22];
  const float* in_bpb  = (const float*)d_in[23];
  const float* in_llw  = (const float*)d_in[24];
  const float* in_llb  = (const float*)d_in[25];

  uint8_t* ws = (uint8_t*)d_ws;
  size_t off = 0;
  auto take = [&](size_t bytes)->size_t{
    size_t o = off; off += (bytes + 255) & ~(size_t)255; return o;
  };
  float* f_xall = (float*)(ws + take((size_t)TOK*256*4));   // reused as f_fin
  float* f_res  = (float*)(ws + take((size_t)TOK*256*4));
  float* f_st   = (float*)(ws + take((size_t)TOK*256*4));
  float* f_xz   = (float*)(ws + take((size_t)TOK*1024*4));
  float* f_u    = (float*)(ws + take((size_t)TOK*DIN_*4));
  float* f_dt   = (float*)(ws + take((size_t)TOK*DIN_*4));
  float* f_xd   = (float*)(ws + take((size_t)TOK*48*4));
  float* f_hp   = (float*)(ws + take((size_t)4096*16*16*4));
  float* f_pp   = (float*)(ws + take((size_t)4096*16*16*4));
  float* f_gate = (float*)(ws + take((size_t)TOK*4*4));
  float* f_an   = (float*)(ws + take((size_t)2*NL*DIN_*16*4));
  float* f_score= (float*)(ws + take((size_t)8*1024*4));
  float* f_part = (float*)(ws + take((size_t)8*16*256*4));
  u16* b_hn   = (u16*)(ws + take((size_t)TOK*256*2));
  u16* b_ybar = (u16*)(ws + take((size_t)TOK*DIN_*2));
  u16* b_curr = (u16*)(ws + take((size_t)TOK*256*2));
  u16* b_h    = (u16*)(ws + take((size_t)TOK*4096*2));
  u16* b_win  = (u16*)(ws + take((size_t)2*NL*1024*256*2));
  u16* b_wout = (u16*)(ws + take((size_t)2*NL*256*512*2));
  u16* b_we1  = (u16*)(ws + take((size_t)2*NL*NE*HM*256*2));
  u16* b_we2  = (u16*)(ws + take((size_t)2*NL*NE*256*HM*2));
  float* f_fin  = f_xall;
  (void)ws_size; (void)in_sizes; (void)n_in; (void)out_size;

  // prep: weights -> bf16
  cvt_bf16_k<<<1024,256,0,stream>>>(in_inw, b_win, 2*NL*1024*256/4);
  cvt_bf16_k<<<1024,256,0,stream>>>(in_ow,  b_wout, 2*NL*256*512/4);
  cvt_bf16_k<<<2048,256,0,stream>>>(in_e1w, b_we1, 2*NL*NE*HM*256/4);
  cvt_bf16_k<<<2048,256,0,stream>>>(in_e2w, b_we2, 2*NL*NE*256*HM/4);
  aneg_k<<<256,256,0,stream>>>(in_alog, f_an, 2*NL*DIN_*16);
  xall_k<<<8192,256,0,stream>>>(in_x, f_xall);

  for (int i=0;i<NL;++i){
    lnres_k<0><<<2048,256,0,stream>>>(i==0 ? f_xall : f_res, i==0 ? nullptr : f_st,
                                      in_nw + i*256, in_nb + i*256, f_res, b_hn);
    gemm_k<0><<<dim3(32,8,2),256,0,stream>>>(b_hn, b_win + (size_t)i*1024*256,
                                             f_xz, nullptr, nullptr, nullptr, nullptr);
    conv_silu_k<<<16384,256,0,stream>>>(f_xz, in_cw + i*DIN_*4, in_cb + i*DIN_, f_u);
    xproj_k<<<1536,256,0,stream>>>(f_u, in_xpw + i*48*DIN_, f_xd);
    dtsp_k<<<16384,256,0,stream>>>(f_xd, in_dtw + i*DIN_*16, in_dtb + i*DIN_, f_dt);
    scan_k<1><<<128,512,0,stream>>>(f_dt, f_u, f_xd, f_an + i*DIN_*16,
                                    nullptr, nullptr, f_hp, f_pp, nullptr);
    scanfix_k<<<16,256,0,stream>>>(f_hp, f_pp);
    scan_k<2><<<128,512,0,stream>>>(f_dt, f_u, f_xd, f_an + i*DIN_*16,
                                    f_xz, in_dsk + i*DIN_, f_hp, f_pp, b_ybar);
    gemm_k<1><<<dim3(32,4,2),256,0,stream>>>(b_ybar, b_wout + (size_t)i*256*512,
                                             f_st, nullptr, nullptr, nullptr, nullptr);
    currgate_k<<<2048,256,0,stream>>>(f_st, f_res, in_gw + i*NE*256, in_gb + i*NE,
                                      b_curr, f_gate);
    gemm_k<2><<<dim3(32,8,8),256,0,stream>>>(b_curr, b_we1 + (size_t)i*NE*HM*256,
                                             nullptr, b_h,
                                             in_e1b + i*NE*HM, f_gate, nullptr);
    gemm_k<3><<<dim3(32,4,2),256,0,stream>>>(b_h, b_we2 + (size_t)i*NE*256*HM,
                                             f_res, nullptr,
                                             nullptr, f_gate, in_e2b + i*NE*256);
  }

  lnres_k<1><<<2048,256,0,stream>>>(f_res, f_st, in_nfw, in_nfb, f_fin, nullptr);
  poolscore_k<<<64,256,0,stream>>>(f_fin, in_fpw, in_fpb, in_bpw, in_bpb, f_score);
  poolnorm_k<<<8,256,0,stream>>>(f_score);
  poolsum_k<<<128,256,0,stream>>>(f_fin, f_score, f_part);
  head_k<<<1,256,0,stream>>>(f_part, in_llw, in_llb, (float*)d_out);
}

// Round 8
// 1457.400 us; speedup vs baseline: 5.9054x; 1.1731x over previous
//
#include <hip/hip_runtime.h>
#include <cstdint>
#include <cstddef>

typedef __attribute__((ext_vector_type(4))) float f32x4;
typedef __attribute__((ext_vector_type(8))) short s16x8;
typedef __attribute__((ext_vector_type(4))) short s16x4;
using u16 = unsigned short;

constexpr int NL   = 4;
constexpr int DIN_ = 512;
constexpr int HM   = 1024;
constexpr int NE   = 4;
constexpr int TPD  = 4096;   // tokens per direction (B*L)
constexpr int TOK  = 8192;   // both directions

__device__ __forceinline__ u16 f2b(float f){
  unsigned u = __builtin_bit_cast(unsigned, f);
  u += 0x7fffu + ((u >> 16) & 1u);
  return (u16)(u >> 16);
}
__device__ __forceinline__ float sigm(float x){ return 1.f/(1.f + __expf(-x)); }

// ---------------- prep kernels ----------------
__global__ void cvt_bf16_k(const float* __restrict__ s, u16* __restrict__ d, int n4){
  int i = blockIdx.x*blockDim.x + threadIdx.x;
  const int st = gridDim.x*blockDim.x;
  for (; i < n4; i += st){
    const f32x4 v = *(const f32x4*)(s + (size_t)i*4);
    s16x4 o;
    #pragma unroll
    for (int j=0;j<4;++j) o[j] = (short)f2b(v[j]);
    *(s16x4*)(d + (size_t)i*4) = o;
  }
}

__global__ void aneg_k(const float* __restrict__ a, float* __restrict__ o, int n){
  int i = blockIdx.x*256 + threadIdx.x;
  if (i < n) o[i] = -__expf(a[i]);
}

__global__ void xall_k(const float* __restrict__ x, float* __restrict__ o){
  const int i = blockIdx.x*256 + threadIdx.x;           // [0, 2*4*1024*256)
  const int d = i & 255, l = (i>>8)&1023, b2 = (i>>18)&3, dir = i>>20;
  const int ls = dir ? (1023 - l) : l;
  o[i] = x[((size_t)(b2<<10) + ls)*256 + d];
}

// ---------------- LN (+residual) ----------------
template<int MODE>
__global__ __launch_bounds__(256)
void lnres_k(const float* __restrict__ s1, const float* __restrict__ s2,
             const float* __restrict__ w, const float* __restrict__ b,
             float* __restrict__ fout, u16* __restrict__ hnout)
{
  const int wv = threadIdx.x >> 6, lane = threadIdx.x & 63;
  const int tok = blockIdx.x*4 + wv;
  const int dir = tok >> 12;
  const size_t base = (size_t)tok*256 + lane*4;
  f32x4 r = *(const f32x4*)(s1 + base);
  if (s2){ f32x4 c = *(const f32x4*)(s2 + base); r += c; }
  float sv = r[0]+r[1]+r[2]+r[3];
  float qv = r[0]*r[0]+r[1]*r[1]+r[2]*r[2]+r[3]*r[3];
  #pragma unroll
  for (int o=32;o;o>>=1){ sv += __shfl_xor(sv,o); qv += __shfl_xor(qv,o); }
  const float mu = sv*(1.f/256.f);
  const float var = qv*(1.f/256.f) - mu*mu;
  const float inv = rsqrtf(var + 1e-5f);
  const int woff = (MODE==0) ? dir*(NL*256) : 0;
  const f32x4 w4 = *(const f32x4*)(w + woff + lane*4);
  const f32x4 b4 = *(const f32x4*)(b + woff + lane*4);
  f32x4 y;
  #pragma unroll
  for (int j=0;j<4;++j) y[j] = (r[j]-mu)*inv*w4[j] + b4[j];
  if constexpr (MODE==0){
    *(f32x4*)(fout + base) = r;
    s16x4 hh;
    #pragma unroll
    for (int j=0;j<4;++j) hh[j] = (short)f2b(y[j]);
    *(s16x4*)(hnout + base) = hh;
  } else {
    *(f32x4*)(fout + base) = y;
  }
}

// ---------------- MFMA bf16 GEMM: C = A @ W^T ----------------
// CFG 0: in_proj  N=1024 K=256  -> OF f32 (f_xz)
// CFG 1: out_proj N=256  K=512  -> OF f32 (f_st)
// CFG 2: moe h    z=dir*4+e, N=1024 K=256 -> OB bf16 = gate*gelu(acc+b1)
// CFG 3: moe o    folded K=4096, N=256    -> OF f32 resid += acc + sum_e g*b2
template<int CFG>
__global__ __launch_bounds__(256, 2)
void gemm_k(const u16* __restrict__ A0, const u16* __restrict__ W0,
            float* OF, u16* OB,
            const float* __restrict__ P0, const float* __restrict__ P1,
            const float* __restrict__ P2)
{
  constexpr int BM = 128;
  constexpr int BN = (CFG==1 || CFG==3) ? 64 : 128;
  constexpr int KD = (CFG==0 || CFG==2) ? 256 : (CFG==1 ? 512 : 4096);
  constexpr int LDA = KD;
  constexpr int FM = 4;
  constexpr int FN = BN/32;
  constexpr int IA = 2;
  constexpr int IB = BN/64;

  __shared__ u16 sA[BM*32];
  __shared__ u16 sB[BN*32];

  const int tid = threadIdx.x;
  const int wave = tid >> 6, lane = tid & 63;
  const int bm0 = blockIdx.x * BM, bn0 = blockIdx.y * BN;
  const int z = blockIdx.z;
  const int wm0 = (wave >> 1) * 64;
  const int wn0 = (wave & 1) * (BN/2);

  const u16* Az; const u16* Wz;
  if constexpr (CFG==0){ Az = A0 + (size_t)z*TPD*256;  Wz = W0 + (size_t)z*(NL*1024*256); }
  else if constexpr (CFG==1){ Az = A0 + (size_t)z*TPD*512; Wz = W0 + (size_t)z*(NL*256*512); }
  else if constexpr (CFG==2){ Az = A0 + (size_t)(z>>2)*TPD*256;
                              Wz = W0 + (size_t)(z>>2)*((size_t)NL*NE*HM*256) + (size_t)(z&3)*(HM*256); }
  else { Az = A0 + (size_t)z*TPD*4096; Wz = W0 + (size_t)z*((size_t)NL*NE*256*HM); }

  f32x4 acc[FM][FN];
  #pragma unroll
  for (int i=0;i<FM;++i)
    #pragma unroll
    for (int j=0;j<FN;++j) acc[i][j] = (f32x4){0.f,0.f,0.f,0.f};

  const int r = lane & 15, q = lane >> 4;

  for (int k0 = 0; k0 < KD; k0 += 32){
    #pragma unroll
    for (int j=0;j<IA;++j){
      const int c = (wave*IA + j)*64 + lane;
      const int m = c >> 2, kq = c & 3;
      const u16* g = Az + (size_t)(bm0 + m)*LDA + (k0 + kq*8);
      __builtin_amdgcn_global_load_lds((const __attribute__((address_space(1))) void*)g,
          (__attribute__((address_space(3))) void*)(sA + (size_t)(wave*IA + j)*512), 16, 0, 0);
    }
    #pragma unroll
    for (int j=0;j<IB;++j){
      const int c = (wave*IB + j)*64 + lane;
      const int n = c >> 2, kq = c & 3;
      const u16* g;
      if constexpr (CFG==3){
        g = Wz + ((size_t)(k0 >> 10)*256 + (bn0 + n))*1024 + ((k0 & 1023) + kq*8);
      } else {
        g = Wz + (size_t)(bn0 + n)*KD + (k0 + kq*8);
      }
      __builtin_amdgcn_global_load_lds((const __attribute__((address_space(1))) void*)g,
          (__attribute__((address_space(3))) void*)(sB + (size_t)(wave*IB + j)*512), 16, 0, 0);
    }
    __syncthreads();
    s16x8 av[FM], bv[FN];
    #pragma unroll
    for (int mi=0;mi<FM;++mi) av[mi] = *(const s16x8*)(sA + (wm0 + mi*16 + r)*32 + q*8);
    #pragma unroll
    for (int ni=0;ni<FN;++ni) bv[ni] = *(const s16x8*)(sB + (wn0 + ni*16 + r)*32 + q*8);
    #pragma unroll
    for (int mi=0;mi<FM;++mi)
      #pragma unroll
      for (int ni=0;ni<FN;++ni)
        acc[mi][ni] = __builtin_amdgcn_mfma_f32_16x16x32_bf16(av[mi], bv[ni], acc[mi][ni], 0, 0, 0);
    __syncthreads();
  }

  #pragma unroll
  for (int mi=0;mi<FM;++mi){
    #pragma unroll
    for (int ni=0;ni<FN;++ni){
      const int col = bn0 + wn0 + ni*16 + r;
      #pragma unroll
      for (int rr=0;rr<4;++rr){
        const int row = bm0 + wm0 + mi*16 + q*4 + rr;
        const float v = acc[mi][ni][rr];
        if constexpr (CFG==0){
          OF[((size_t)z*TPD + row)*1024 + col] = v;
        } else if constexpr (CFG==1){
          OF[((size_t)z*TPD + row)*256 + col] = v;
        } else if constexpr (CFG==2){
          const int dir = z>>2, e = z&3;
          const float xv = v + P0[(size_t)dir*(NL*NE*HM) + (size_t)e*HM + col];
          const float ge = 0.5f*xv*(1.f + erff(xv*0.70710678118654752f));
          const float gt = P1[((size_t)dir*TPD + row)*4 + e];
          OB[((size_t)dir*TPD + row)*4096 + (size_t)e*1024 + col] = f2b(ge*gt);
        } else {
          const float* b2p = P2 + (size_t)z*(NL*NE*256);
          const float* gp  = P1 + ((size_t)z*TPD + row)*4;
          const float bias = gp[0]*b2p[col] + gp[1]*b2p[256+col]
                           + gp[2]*b2p[512+col] + gp[3]*b2p[768+col];
          const size_t oi = ((size_t)z*TPD + row)*256 + col;
          OF[oi] = OF[oi] + v + bias;
        }
      }
    }
  }
}

// ---------------- fused conv + silu + x_proj + dt_proj (16 tokens/block) ----------------
__global__ __launch_bounds__(256)
void convproj_k(const float* __restrict__ xz,
                const float* __restrict__ cw, const float* __restrict__ cb,
                const float* __restrict__ xpw,
                const float* __restrict__ dtw, const float* __restrict__ dtb,
                float* __restrict__ uo, float* __restrict__ dto,
                float* __restrict__ xdo)
{
  __shared__ float sxs[19*512];
  __shared__ float sxd[16*48];
  const int tid = threadIdx.x;
  const int blk = blockIdx.x;                       // 512 blocks
  const int tc = blk & 63, bb = (blk>>6)&3, dir = blk>>8;
  const int t0 = tc*16;
  const size_t tokbase = (size_t)(dir*4+bb)*1024;

  // stage 19x512 xz slab (tokens t0-3 .. t0+15, xs half)
  for (int idx = tid; idx < 19*512; idx += 256){
    const int rr = idx >> 9, c = idx & 511;
    const int t = t0 - 3 + rr;
    sxs[idx] = (t < 0) ? 0.f : xz[(tokbase + t)*1024 + c];
  }
  __syncthreads();

  // conv + silu (row tk+k of slab = token t0+tk-3+k)
  const float* cwp = cw + (size_t)dir*(NL*DIN_*4);
  const float* cbp = cb + (size_t)dir*(NL*DIN_);
  float ur[32];
  #pragma unroll
  for (int s=0;s<32;++s){
    const int o = tid + s*256;
    const int tk = o >> 9, c = o & 511;
    const float w0 = cwp[c*4+0], w1 = cwp[c*4+1], w2 = cwp[c*4+2], w3 = cwp[c*4+3];
    float a = cbp[c] + sxs[tk*512+c]*w0 + sxs[(tk+1)*512+c]*w1
            + sxs[(tk+2)*512+c]*w2 + sxs[(tk+3)*512+c]*w3;
    const float uv = a * sigm(a);
    ur[s] = uv;
    uo[(tokbase + t0 + tk)*DIN_ + c] = uv;
  }
  __syncthreads();
  float* su = sxs;                                   // reuse as [16][516]
  #pragma unroll
  for (int s=0;s<32;++s){
    const int o = tid + s*256;
    const int tk = o >> 9, c = o & 511;
    su[tk*516 + c] = ur[s];
  }
  __syncthreads();

  // x_proj: xd[tk][j] = sum_k u[tk][k] * xpw[j][k]   (768 outputs, 3 passes)
  const float* xpwp = xpw + (size_t)dir*(NL*48*DIN_);
  #pragma unroll
  for (int s=0;s<3;++s){
    const int o = tid + s*256;
    const int j = o >> 4, tk = o & 15;
    const float* wr = xpwp + (size_t)j*DIN_;
    const float* sur = su + tk*516;
    float a = 0.f;
    #pragma unroll 8
    for (int k=0;k<DIN_;++k) a += sur[k]*wr[k];
    sxd[tk*48 + j] = a;
    if (j >= 16) xdo[(tokbase + t0 + tk)*48 + j] = a;   // scan reads only 16..47
  }
  __syncthreads();

  // dt_proj + softplus
  const float* dtwp = dtw + (size_t)dir*(NL*DIN_*16);
  const float* dtbp = dtb + (size_t)dir*(NL*DIN_);
  #pragma unroll
  for (int s=0;s<32;++s){
    const int o = tid + s*256;
    const int tk = o >> 9, c = o & 511;
    const float* wr = dtwp + (size_t)c*16;
    const float* xr = sxd + tk*48;
    float a = dtbp[c];
    #pragma unroll
    for (int r2=0;r2<16;++r2) a += xr[r2]*wr[r2];
    dto[(tokbase + t0 + tk)*DIN_ + c] = (a > 20.f) ? a : log1pf(__expf(a));
  }
}

// ---------------- chunked selective scan ----------------
template<int PASS>
__global__ __launch_bounds__(512)
void scan_k(const float* __restrict__ dt, const float* __restrict__ u,
            const float* __restrict__ xd, const float* __restrict__ an,
            const float* __restrict__ xz, const float* __restrict__ dsk,
            float* __restrict__ hp, float* __restrict__ pp,
            u16* __restrict__ ybar)
{
  const int ch = threadIdx.x;                         // 0..511
  const int blk = blockIdx.x;                         // (dir*4+b)*16 + chunk
  const int chunk = blk & 15, bb = (blk>>4)&3, dir = blk>>6;
  const size_t tokbase = (size_t)(dir*4+bb)*1024 + (size_t)chunk*64;
  const float* ap = an + (size_t)dir*(NL*DIN_*16) + (size_t)ch*16;
  float A_[16];
  #pragma unroll
  for (int n=0;n<16;++n) A_[n] = ap[n];
  const size_t scanid = (size_t)(dir*4+bb)*512 + ch;
  const size_t hbase = (scanid*16 + chunk)*16;
  float h[16], P[16];
  if constexpr (PASS==1){
    #pragma unroll
    for (int n=0;n<16;++n){ h[n]=0.f; P[n]=1.f; }
  } else {
    #pragma unroll
    for (int n=0;n<16;++n) h[n] = hp[hbase+n];
  }
  float dval = 0.f;
  if constexpr (PASS==2) dval = dsk[(size_t)dir*(NL*DIN_) + ch];
  for (int t=0;t<64;++t){
    const size_t tok = tokbase + t;
    const float dtv = dt[tok*DIN_ + ch];
    const float uv  = u[tok*DIN_ + ch];
    const float dtu = dtv*uv;
    const float* xr = xd + tok*48;
    float y = 0.f;
    #pragma unroll
    for (int n=0;n<16;++n){
      const float e = __expf(dtv*A_[n]);
      const float hn2 = h[n]*e + dtu*xr[16+n];
      h[n] = hn2;
      if constexpr (PASS==1) P[n] *= e;
      else y += hn2*xr[32+n];
    }
    if constexpr (PASS==2){
      const float zv = xz[tok*1024 + 512 + ch];
      ybar[tok*DIN_ + ch] = f2b((y + uv*dval) * (zv * sigm(zv)));
    }
  }
  if constexpr (PASS==1){
    #pragma unroll
    for (int n=0;n<16;++n){ hp[hbase+n] = h[n]; pp[hbase+n] = P[n]; }
  }
}

__global__ void scanfix_k(float* __restrict__ hp, const float* __restrict__ pp){
  const int id = blockIdx.x*256 + threadIdx.x;        // 0..4095
  float s[16];
  #pragma unroll
  for (int n=0;n<16;++n) s[n] = 0.f;
  for (int c=0;c<16;++c){
    const size_t base = ((size_t)id*16 + c)*16;
    #pragma unroll
    for (int n=0;n<16;++n){
      const float hv = hp[base+n];
      const float pv = pp[base+n];
      hp[base+n] = s[n];
      s[n] = hv + pv*s[n];
    }
  }
}

// ---------------- curr = states + resid ; gating (f32) ----------------
__global__ __launch_bounds__(256)
void currgate_k(const float* __restrict__ st, const float* __restrict__ rs,
                const float* __restrict__ gw, const float* __restrict__ gb,
                u16* __restrict__ currb, float* __restrict__ gate)
{
  const int wv = threadIdx.x>>6, lane = threadIdx.x&63;
  const int tok = blockIdx.x*4 + wv;
  const int dir = tok>>12;
  const size_t base = (size_t)tok*256 + lane*4;
  f32x4 a = *(const f32x4*)(st+base);
  { f32x4 c = *(const f32x4*)(rs+base); a += c; }
  s16x4 cc;
  #pragma unroll
  for (int j=0;j<4;++j) cc[j] = (short)f2b(a[j]);
  *(s16x4*)(currb+base) = cc;
  const float* gwp = gw + (size_t)dir*(NL*NE*256);
  float lg[4];
  #pragma unroll
  for (int e=0;e<4;++e){
    const float* w4 = gwp + e*256 + lane*4;
    lg[e] = a[0]*w4[0] + a[1]*w4[1] + a[2]*w4[2] + a[3]*w4[3];
  }
  #pragma unroll
  for (int o=32;o;o>>=1){
    #pragma unroll
    for (int e=0;e<4;++e) lg[e] += __shfl_xor(lg[e], o);
  }
  if (lane==0){
    const float* gbp = gb + dir*(NL*NE);
    float sc[4]; float mx = -1e30f;
    #pragma unroll
    for (int e=0;e<4;++e){ sc[e] = lg[e] + gbp[e]; mx = fmaxf(mx, sc[e]); }
    float den = 0.f;
    #pragma unroll
    for (int e=0;e<4;++e){ sc[e] = __expf(sc[e]-mx); den += sc[e]; }
    const float rden = 1.f/den;
    #pragma unroll
    for (int e=0;e<4;++e) sc[e] *= rden;
    int i1 = 0;
    #pragma unroll
    for (int e=1;e<4;++e) if (sc[e] > sc[i1]) i1 = e;
    int i2 = (i1==0)?1:0;
    #pragma unroll
    for (int e=0;e<4;++e) if (e!=i1 && sc[e] > sc[i2]) i2 = e;
    const float ssum = sc[i1] + sc[i2] + 1e-6f;
    #pragma unroll
    for (int e=0;e<4;++e)
      gate[(size_t)tok*4+e] = (e==i1) ? sc[i1]/ssum : ((e==i2) ? sc[i2]/ssum : 0.f);
  }
}

// ---------------- pooling (parallel, 4-stage) ----------------
__global__ __launch_bounds__(256)
void poolscore_k(const float* __restrict__ fin, const float* __restrict__ fw,
                 const float* __restrict__ fb, const float* __restrict__ bw,
                 const float* __restrict__ bbs, float* __restrict__ score)
{
  const int blk = blockIdx.x;                   // p = blk>>3, g = blk&7
  const int p = blk >> 3, g = blk & 7;
  const int dir = p >> 2;
  const float* pw = dir ? bw : fw;
  const float pb = dir ? bbs[0] : fb[0];
  const int wv = threadIdx.x>>6, lane = threadIdx.x&63;
  const size_t fbase = (size_t)p*1024*256;
  const f32x4 w4 = *(const f32x4*)(pw + lane*4);
  for (int l = g*128 + wv; l < (g+1)*128; l += 4){
    const f32x4 f4 = *(const f32x4*)(fin + fbase + (size_t)l*256 + lane*4);
    float pv = f4[0]*w4[0] + f4[1]*w4[1] + f4[2]*w4[2] + f4[3]*w4[3];
    #pragma unroll
    for (int o=32;o;o>>=1) pv += __shfl_xor(pv,o);
    if (lane==0) score[p*1024 + l] = pv + pb;
  }
}

__global__ __launch_bounds__(256)
void poolnorm_k(float* __restrict__ score)
{
  __shared__ float red[8];
  const int p = blockIdx.x;
  const int tid = threadIdx.x, wv = tid>>6, lane = tid&63;
  float* s = score + p*1024;
  float v[4];
  float m = -1e30f;
  #pragma unroll
  for (int j=0;j<4;++j){ v[j] = s[tid + j*256]; m = fmaxf(m, v[j]); }
  #pragma unroll
  for (int o=32;o;o>>=1) m = fmaxf(m, __shfl_xor(m,o));
  if (lane==0) red[wv] = m;
  __syncthreads();
  m = fmaxf(fmaxf(red[0],red[1]), fmaxf(red[2],red[3]));
  float ssum = 0.f;
  #pragma unroll
  for (int j=0;j<4;++j){ v[j] = __expf(v[j]-m); ssum += v[j]; }
  #pragma unroll
  for (int o=32;o;o>>=1) ssum += __shfl_xor(ssum,o);
  if (lane==0) red[4+wv] = ssum;
  __syncthreads();
  const float inv = 1.f/(red[4]+red[5]+red[6]+red[7]);
  #pragma unroll
  for (int j=0;j<4;++j) s[tid + j*256] = v[j]*inv;
}

__global__ __launch_bounds__(256)
void poolsum_k(const float* __restrict__ fin, const float* __restrict__ score,
               float* __restrict__ part)
{
  const int blk = blockIdx.x;                   // p = blk>>4, g = blk&15
  const int p = blk >> 4, g = blk & 15;
  const int d = threadIdx.x;
  const size_t fbase = (size_t)p*1024*256;
  float acc = 0.f;
  #pragma unroll 4
  for (int l = g*64; l < (g+1)*64; ++l)
    acc += score[p*1024 + l] * fin[fbase + (size_t)l*256 + d];
  part[((size_t)p*16 + g)*256 + d] = acc;
}

__global__ __launch_bounds__(256)
void head_k(const float* __restrict__ part, const float* __restrict__ llw,
            const float* __restrict__ llb, float* __restrict__ out)
{
  __shared__ float sp[8*256];
  const int d = threadIdx.x;
  #pragma unroll
  for (int p=0;p<8;++p){
    float a = 0.f;
    #pragma unroll
    for (int g=0;g<16;++g) a += part[((size_t)p*16+g)*256 + d];
    sp[p*256 + d] = a;
  }
  __syncthreads();
  const int o = d;
  for (int b=0;b<4;++b){
    float acc = llb[o];
    const float* wr = llw + (size_t)o*512;
    const float* pf = sp + b*256;
    const float* pk = sp + (4+b)*256;
    #pragma unroll 8
    for (int j=0;j<256;++j) acc += pf[j]*wr[j];
    #pragma unroll 8
    for (int j=0;j<256;++j) acc += pk[j]*wr[256+j];
    out[b*256+o] = acc;
  }
}

// ---------------- host ----------------
extern "C" void kernel_launch(void* const* d_in, const int* in_sizes, int n_in,
                              void* d_out, int out_size, void* d_ws, size_t ws_size,
                              hipStream_t stream)
{
  const float* in_x    = (const float*)d_in[0];
  const float* in_inw  = (const float*)d_in[1];
  const float* in_cw   = (const float*)d_in[2];
  const float* in_cb   = (const float*)d_in[3];
  const float* in_xpw  = (const float*)d_in[4];
  const float* in_dtw  = (const float*)d_in[5];
  const float* in_dtb  = (const float*)d_in[6];
  const float* in_alog = (const float*)d_in[7];
  const float* in_dsk  = (const float*)d_in[8];
  const float* in_ow   = (const float*)d_in[9];
  const float* in_nw   = (const float*)d_in[10];
  const float* in_nb   = (const float*)d_in[11];
  const float* in_gw   = (const float*)d_in[12];
  const float* in_gb   = (const float*)d_in[13];
  const float* in_e1w  = (const float*)d_in[14];
  const float* in_e1b  = (const float*)d_in[15];
  const float* in_e2w  = (const float*)d_in[16];
  const float* in_e2b  = (const float*)d_in[17];
  const float* in_nfw  = (const float*)d_in[18];
  const float* in_nfb  = (const float*)d_in[19];
  const float* in_fpw  = (const float*)d_in[20];
  const float* in_fpb  = (const float*)d_in[21];
  const float* in_bpw  = (const float*)d_in[22];
  const float* in_bpb  = (const float*)d_in[23];
  const float* in_llw  = (const float*)d_in[24];
  const float* in_llb  = (const float*)d_in[25];

  uint8_t* ws = (uint8_t*)d_ws;
  size_t off = 0;
  auto take = [&](size_t bytes)->size_t{
    size_t o = off; off += (bytes + 255) & ~(size_t)255; return o;
  };
  float* f_xall = (float*)(ws + take((size_t)TOK*256*4));   // reused as f_fin
  float* f_res  = (float*)(ws + take((size_t)TOK*256*4));
  float* f_st   = (float*)(ws + take((size_t)TOK*256*4));
  float* f_xz   = (float*)(ws + take((size_t)TOK*1024*4));
  float* f_u    = (float*)(ws + take((size_t)TOK*DIN_*4));
  float* f_dt   = (float*)(ws + take((size_t)TOK*DIN_*4));
  float* f_xd   = (float*)(ws + take((size_t)TOK*48*4));
  float* f_hp   = (float*)(ws + take((size_t)4096*16*16*4));
  float* f_pp   = (float*)(ws + take((size_t)4096*16*16*4));
  float* f_gate = (float*)(ws + take((size_t)TOK*4*4));
  float* f_an   = (float*)(ws + take((size_t)2*NL*DIN_*16*4));
  float* f_score= (float*)(ws + take((size_t)8*1024*4));
  float* f_part = (float*)(ws + take((size_t)8*16*256*4));
  u16* b_hn   = (u16*)(ws + take((size_t)TOK*256*2));
  u16* b_ybar = (u16*)(ws + take((size_t)TOK*DIN_*2));
  u16* b_curr = (u16*)(ws + take((size_t)TOK*256*2));
  u16* b_h    = (u16*)(ws + take((size_t)TOK*4096*2));
  u16* b_win  = (u16*)(ws + take((size_t)2*NL*1024*256*2));
  u16* b_wout = (u16*)(ws + take((size_t)2*NL*256*512*2));
  u16* b_we1  = (u16*)(ws + take((size_t)2*NL*NE*HM*256*2));
  u16* b_we2  = (u16*)(ws + take((size_t)2*NL*NE*256*HM*2));
  float* f_fin  = f_xall;
  (void)ws_size; (void)in_sizes; (void)n_in; (void)out_size;

  // prep: weights -> bf16
  cvt_bf16_k<<<1024,256,0,stream>>>(in_inw, b_win, 2*NL*1024*256/4);
  cvt_bf16_k<<<1024,256,0,stream>>>(in_ow,  b_wout, 2*NL*256*512/4);
  cvt_bf16_k<<<2048,256,0,stream>>>(in_e1w, b_we1, 2*NL*NE*HM*256/4);
  cvt_bf16_k<<<2048,256,0,stream>>>(in_e2w, b_we2, 2*NL*NE*256*HM/4);
  aneg_k<<<256,256,0,stream>>>(in_alog, f_an, 2*NL*DIN_*16);
  xall_k<<<8192,256,0,stream>>>(in_x, f_xall);

  for (int i=0;i<NL;++i){
    lnres_k<0><<<2048,256,0,stream>>>(i==0 ? f_xall : f_res, i==0 ? nullptr : f_st,
                                      in_nw + i*256, in_nb + i*256, f_res, b_hn);
    gemm_k<0><<<dim3(32,8,2),256,0,stream>>>(b_hn, b_win + (size_t)i*1024*256,
                                             f_xz, nullptr, nullptr, nullptr, nullptr);
    convproj_k<<<512,256,0,stream>>>(f_xz, in_cw + i*DIN_*4, in_cb + i*DIN_,
                                     in_xpw + i*48*DIN_, in_dtw + i*DIN_*16, in_dtb + i*DIN_,
                                     f_u, f_dt, f_xd);
    scan_k<1><<<128,512,0,stream>>>(f_dt, f_u, f_xd, f_an + i*DIN_*16,
                                    nullptr, nullptr, f_hp, f_pp, nullptr);
    scanfix_k<<<16,256,0,stream>>>(f_hp, f_pp);
    scan_k<2><<<128,512,0,stream>>>(f_dt, f_u, f_xd, f_an + i*DIN_*16,
                                    f_xz, in_dsk + i*DIN_, f_hp, f_pp, b_ybar);
    gemm_k<1><<<dim3(32,4,2),256,0,stream>>>(b_ybar, b_wout + (size_t)i*256*512,
                                             f_st, nullptr, nullptr, nullptr, nullptr);
    currgate_k<<<2048,256,0,stream>>>(f_st, f_res, in_gw + i*NE*256, in_gb + i*NE,
                                      b_curr, f_gate);
    gemm_k<2><<<dim3(32,8,8),256,0,stream>>>(b_curr, b_we1 + (size_t)i*NE*HM*256,
                                             nullptr, b_h,
                                             in_e1b + i*NE*HM, f_gate, nullptr);
    gemm_k<3><<<dim3(32,4,2),256,0,stream>>>(b_h, b_we2 + (size_t)i*NE*256*HM,
                                             f_res, nullptr,
                                             nullptr, f_gate, in_e2b + i*NE*256);
  }

  lnres_k<1><<<2048,256,0,stream>>>(f_res, f_st, in_nfw, in_nfb, f_fin, nullptr);
  poolscore_k<<<64,256,0,stream>>>(f_fin, in_fpw, in_fpb, in_bpw, in_bpb, f_score);
  poolnorm_k<<<8,256,0,stream>>>(f_score);
  poolsum_k<<<128,256,0,stream>>>(f_fin, f_score, f_part);
  head_k<<<1,256,0,stream>>>(f_part, in_llw, in_llb, (float*)d_out);
}

// Round 9
// 1323.177 us; speedup vs baseline: 6.5045x; 1.1014x over previous
//
#include <hip/hip_runtime.h>
#include <cstdint>
#include <cstddef>

typedef __attribute__((ext_vector_type(4))) float f32x4;
typedef __attribute__((ext_vector_type(8))) short s16x8;
typedef __attribute__((ext_vector_type(4))) short s16x4;
using u16 = unsigned short;

constexpr int NL   = 4;
constexpr int DIN_ = 512;
constexpr int HM   = 1024;
constexpr int NE   = 4;
constexpr int TPD  = 4096;   // tokens per direction (B*L)
constexpr int TOK  = 8192;   // both directions

__device__ __forceinline__ u16 f2b(float f){
  unsigned u = __builtin_bit_cast(unsigned, f);
  u += 0x7fffu + ((u >> 16) & 1u);
  return (u16)(u >> 16);
}
__device__ __forceinline__ float sigm(float x){ return 1.f/(1.f + __expf(-x)); }

// ---------------- prep kernels ----------------
__global__ void cvt_bf16_k(const float* __restrict__ s, u16* __restrict__ d, int n4){
  int i = blockIdx.x*blockDim.x + threadIdx.x;
  const int st = gridDim.x*blockDim.x;
  for (; i < n4; i += st){
    const f32x4 v = *(const f32x4*)(s + (size_t)i*4);
    s16x4 o;
    #pragma unroll
    for (int j=0;j<4;++j) o[j] = (short)f2b(v[j]);
    *(s16x4*)(d + (size_t)i*4) = o;
  }
}

__global__ void aneg_k(const float* __restrict__ a, float* __restrict__ o, int n){
  int i = blockIdx.x*256 + threadIdx.x;
  if (i < n) o[i] = -__expf(a[i]);
}

__global__ void xall_k(const float* __restrict__ x, float* __restrict__ o){
  const int i = blockIdx.x*256 + threadIdx.x;           // [0, 2*4*1024*256)
  const int d = i & 255, l = (i>>8)&1023, b2 = (i>>18)&3, dir = i>>20;
  const int ls = dir ? (1023 - l) : l;
  o[i] = x[((size_t)(b2<<10) + ls)*256 + d];
}

// ---------------- LN (+residual) ----------------
template<int MODE>
__global__ __launch_bounds__(256)
void lnres_k(const float* __restrict__ s1, const float* __restrict__ s2,
             const float* __restrict__ w, const float* __restrict__ b,
             float* __restrict__ fout, u16* __restrict__ hnout)
{
  const int wv = threadIdx.x >> 6, lane = threadIdx.x & 63;
  const int tok = blockIdx.x*4 + wv;
  const int dir = tok >> 12;
  const size_t base = (size_t)tok*256 + lane*4;
  f32x4 r = *(const f32x4*)(s1 + base);
  if (s2){ f32x4 c = *(const f32x4*)(s2 + base); r += c; }
  float sv = r[0]+r[1]+r[2]+r[3];
  float qv = r[0]*r[0]+r[1]*r[1]+r[2]*r[2]+r[3]*r[3];
  #pragma unroll
  for (int o=32;o;o>>=1){ sv += __shfl_xor(sv,o); qv += __shfl_xor(qv,o); }
  const float mu = sv*(1.f/256.f);
  const float var = qv*(1.f/256.f) - mu*mu;
  const float inv = rsqrtf(var + 1e-5f);
  const int woff = (MODE==0) ? dir*(NL*256) : 0;
  const f32x4 w4 = *(const f32x4*)(w + woff + lane*4);
  const f32x4 b4 = *(const f32x4*)(b + woff + lane*4);
  f32x4 y;
  #pragma unroll
  for (int j=0;j<4;++j) y[j] = (r[j]-mu)*inv*w4[j] + b4[j];
  if constexpr (MODE==0){
    *(f32x4*)(fout + base) = r;
    s16x4 hh;
    #pragma unroll
    for (int j=0;j<4;++j) hh[j] = (short)f2b(y[j]);
    *(s16x4*)(hnout + base) = hh;
  } else {
    *(f32x4*)(fout + base) = y;
  }
}

// ---------------- MFMA bf16 GEMM: C = A @ W^T ----------------
// CFG 0: in_proj  N=1024 K=256  -> OF f32 (f_xz)
// CFG 1: out_proj N=256  K=512  -> OF f32 (f_st)
// CFG 2: moe h    z=dir*4+e, N=1024 K=256 -> OB bf16 = gate*gelu(acc+b1)
// CFG 3: moe o    folded K=4096, N=256    -> OF f32 resid += acc + sum_e g*b2
template<int CFG>
__global__ __launch_bounds__(256, 2)
void gemm_k(const u16* __restrict__ A0, const u16* __restrict__ W0,
            float* OF, u16* OB,
            const float* __restrict__ P0, const float* __restrict__ P1,
            const float* __restrict__ P2)
{
  constexpr int BM = 128;
  constexpr int BN = (CFG==1 || CFG==3) ? 64 : 128;
  constexpr int KD = (CFG==0 || CFG==2) ? 256 : (CFG==1 ? 512 : 4096);
  constexpr int LDA = KD;
  constexpr int FM = 4;
  constexpr int FN = BN/32;
  constexpr int IA = 2;
  constexpr int IB = BN/64;

  __shared__ u16 sA[BM*32];
  __shared__ u16 sB[BN*32];

  const int tid = threadIdx.x;
  const int wave = tid >> 6, lane = tid & 63;
  const int bm0 = blockIdx.x * BM, bn0 = blockIdx.y * BN;
  const int z = blockIdx.z;
  const int wm0 = (wave >> 1) * 64;
  const int wn0 = (wave & 1) * (BN/2);

  const u16* Az; const u16* Wz;
  if constexpr (CFG==0){ Az = A0 + (size_t)z*TPD*256;  Wz = W0 + (size_t)z*(NL*1024*256); }
  else if constexpr (CFG==1){ Az = A0 + (size_t)z*TPD*512; Wz = W0 + (size_t)z*(NL*256*512); }
  else if constexpr (CFG==2){ Az = A0 + (size_t)(z>>2)*TPD*256;
                              Wz = W0 + (size_t)(z>>2)*((size_t)NL*NE*HM*256) + (size_t)(z&3)*(HM*256); }
  else { Az = A0 + (size_t)z*TPD*4096; Wz = W0 + (size_t)z*((size_t)NL*NE*256*HM); }

  f32x4 acc[FM][FN];
  #pragma unroll
  for (int i=0;i<FM;++i)
    #pragma unroll
    for (int j=0;j<FN;++j) acc[i][j] = (f32x4){0.f,0.f,0.f,0.f};

  const int r = lane & 15, q = lane >> 4;

  for (int k0 = 0; k0 < KD; k0 += 32){
    #pragma unroll
    for (int j=0;j<IA;++j){
      const int c = (wave*IA + j)*64 + lane;
      const int m = c >> 2, kq = c & 3;
      const u16* g = Az + (size_t)(bm0 + m)*LDA + (k0 + kq*8);
      __builtin_amdgcn_global_load_lds((const __attribute__((address_space(1))) void*)g,
          (__attribute__((address_space(3))) void*)(sA + (size_t)(wave*IA + j)*512), 16, 0, 0);
    }
    #pragma unroll
    for (int j=0;j<IB;++j){
      const int c = (wave*IB + j)*64 + lane;
      const int n = c >> 2, kq = c & 3;
      const u16* g;
      if constexpr (CFG==3){
        g = Wz + ((size_t)(k0 >> 10)*256 + (bn0 + n))*1024 + ((k0 & 1023) + kq*8);
      } else {
        g = Wz + (size_t)(bn0 + n)*KD + (k0 + kq*8);
      }
      __builtin_amdgcn_global_load_lds((const __attribute__((address_space(1))) void*)g,
          (__attribute__((address_space(3))) void*)(sB + (size_t)(wave*IB + j)*512), 16, 0, 0);
    }
    __syncthreads();
    s16x8 av[FM], bv[FN];
    #pragma unroll
    for (int mi=0;mi<FM;++mi) av[mi] = *(const s16x8*)(sA + (wm0 + mi*16 + r)*32 + q*8);
    #pragma unroll
    for (int ni=0;ni<FN;++ni) bv[ni] = *(const s16x8*)(sB + (wn0 + ni*16 + r)*32 + q*8);
    #pragma unroll
    for (int mi=0;mi<FM;++mi)
      #pragma unroll
      for (int ni=0;ni<FN;++ni)
        acc[mi][ni] = __builtin_amdgcn_mfma_f32_16x16x32_bf16(av[mi], bv[ni], acc[mi][ni], 0, 0, 0);
    __syncthreads();
  }

  #pragma unroll
  for (int mi=0;mi<FM;++mi){
    #pragma unroll
    for (int ni=0;ni<FN;++ni){
      const int col = bn0 + wn0 + ni*16 + r;
      #pragma unroll
      for (int rr=0;rr<4;++rr){
        const int row = bm0 + wm0 + mi*16 + q*4 + rr;
        const float v = acc[mi][ni][rr];
        if constexpr (CFG==0){
          OF[((size_t)z*TPD + row)*1024 + col] = v;
        } else if constexpr (CFG==1){
          OF[((size_t)z*TPD + row)*256 + col] = v;
        } else if constexpr (CFG==2){
          const int dir = z>>2, e = z&3;
          const float xv = v + P0[(size_t)dir*(NL*NE*HM) + (size_t)e*HM + col];
          const float ge = 0.5f*xv*(1.f + erff(xv*0.70710678118654752f));
          const float gt = P1[((size_t)dir*TPD + row)*4 + e];
          OB[((size_t)dir*TPD + row)*4096 + (size_t)e*1024 + col] = f2b(ge*gt);
        } else {
          const float* b2p = P2 + (size_t)z*(NL*NE*256);
          const float* gp  = P1 + ((size_t)z*TPD + row)*4;
          const float bias = gp[0]*b2p[col] + gp[1]*b2p[256+col]
                           + gp[2]*b2p[512+col] + gp[3]*b2p[768+col];
          const size_t oi = ((size_t)z*TPD + row)*256 + col;
          OF[oi] = OF[oi] + v + bias;
        }
      }
    }
  }
}

// ---------------- fused conv + silu + x_proj + dt_proj (16 tokens/block, f32x4) ----------------
// LDS rows padded to 516 floats -> 16B-aligned vector reads, benign bank pattern.
__global__ __launch_bounds__(256)
void convproj_k(const float* __restrict__ xz,
                const float* __restrict__ cw, const float* __restrict__ cb,
                const float* __restrict__ xpw,
                const float* __restrict__ dtw, const float* __restrict__ dtb,
                float* __restrict__ uo, float* __restrict__ dto,
                float* __restrict__ xdo)
{
  __shared__ float sxs[19*516];
  __shared__ float sxd[16*48];
  const int tid = threadIdx.x;
  const int blk = blockIdx.x;                       // 512 blocks
  const int tc = blk & 63, bb = (blk>>6)&3, dir = blk>>8;
  const int t0 = tc*16;
  const size_t tokbase = (size_t)(dir*4+bb)*1024;

  // stage 19x512 xz slab (tokens t0-3 .. t0+15, xs half), f32x4
  for (int idx = tid; idx < 19*128; idx += 256){
    const int rr = idx >> 7, c4 = idx & 127;
    const int t = t0 - 3 + rr;
    f32x4 v = (f32x4){0.f,0.f,0.f,0.f};
    if (t >= 0) v = *(const f32x4*)(xz + (tokbase + t)*1024 + c4*4);
    *(f32x4*)(sxs + rr*516 + c4*4) = v;
  }
  __syncthreads();

  // conv + silu, f32x4 over channels
  const float* cwp = cw + (size_t)dir*(NL*DIN_*4);
  const float* cbp = cb + (size_t)dir*(NL*DIN_);
  f32x4 ur[8];
  #pragma unroll
  for (int s=0;s<8;++s){
    const int o4 = tid + s*256;                     // 0..2047
    const int tk = o4 >> 7, c4 = o4 & 127;
    // weights for channels c4*4..c4*4+3: 16 contiguous floats
    const f32x4 w0 = *(const f32x4*)(cwp + c4*16);
    const f32x4 w1 = *(const f32x4*)(cwp + c4*16 + 4);
    const f32x4 w2 = *(const f32x4*)(cwp + c4*16 + 8);
    const f32x4 w3 = *(const f32x4*)(cwp + c4*16 + 12);
    const f32x4 cb4 = *(const f32x4*)(cbp + c4*4);
    const f32x4 x0 = *(const f32x4*)(sxs + (tk+0)*516 + c4*4);
    const f32x4 x1 = *(const f32x4*)(sxs + (tk+1)*516 + c4*4);
    const f32x4 x2 = *(const f32x4*)(sxs + (tk+2)*516 + c4*4);
    const f32x4 x3 = *(const f32x4*)(sxs + (tk+3)*516 + c4*4);
    f32x4 a;
    // w layout per channel cc: [cc*4+k]; wk vectors hold w[c][k] groups transposed:
    // w0 = cwp[c4*16 + 0..3] = ch c4*4+0 taps 0..3  -> need per-channel dot
    a[0] = cb4[0] + x0[0]*w0[0] + x1[0]*w0[1] + x2[0]*w0[2] + x3[0]*w0[3];
    a[1] = cb4[1] + x0[1]*w1[0] + x1[1]*w1[1] + x2[1]*w1[2] + x3[1]*w1[3];
    a[2] = cb4[2] + x0[2]*w2[0] + x1[2]*w2[1] + x2[2]*w2[2] + x3[2]*w2[3];
    a[3] = cb4[3] + x0[3]*w3[0] + x1[3]*w3[1] + x2[3]*w3[2] + x3[3]*w3[3];
    f32x4 uv;
    #pragma unroll
    for (int j=0;j<4;++j) uv[j] = a[j]*sigm(a[j]);
    ur[s] = uv;
    *(f32x4*)(uo + (tokbase + t0 + tk)*DIN_ + c4*4) = uv;
  }
  __syncthreads();
  float* su = sxs;                                   // reuse as [16][516]
  #pragma unroll
  for (int s=0;s<8;++s){
    const int o4 = tid + s*256;
    const int tk = o4 >> 7, c4 = o4 & 127;
    *(f32x4*)(su + tk*516 + c4*4) = ur[s];
  }
  __syncthreads();

  // x_proj: xd[tk][j] = sum_k u[tk][k]*xpw[j][k]; f32x4 MACs
  const float* xpwp = xpw + (size_t)dir*(NL*48*DIN_);
  #pragma unroll
  for (int s=0;s<3;++s){
    const int o = tid + s*256;
    const int j = o >> 4, tk = o & 15;
    const float* wr = xpwp + (size_t)j*DIN_;
    const float* sur = su + tk*516;
    f32x4 acc4 = (f32x4){0.f,0.f,0.f,0.f};
    #pragma unroll 8
    for (int k4=0;k4<128;++k4){
      const f32x4 uv = *(const f32x4*)(sur + k4*4);
      const f32x4 wv = *(const f32x4*)(wr + k4*4);
      acc4 += uv*wv;
    }
    const float a = acc4[0]+acc4[1]+acc4[2]+acc4[3];
    sxd[tk*48 + j] = a;
    if (j >= 16) xdo[(tokbase + t0 + tk)*48 + j] = a;   // scan reads only 16..47
  }
  __syncthreads();

  // dt_proj + softplus, f32x4 over the 16 rank dims
  const float* dtwp = dtw + (size_t)dir*(NL*DIN_*16);
  const float* dtbp = dtb + (size_t)dir*(NL*DIN_);
  #pragma unroll
  for (int s=0;s<32;++s){
    const int o = tid + s*256;
    const int tk = o >> 9, c = o & 511;
    const float* wr = dtwp + (size_t)c*16;
    const float* xr = sxd + tk*48;
    f32x4 acc4 = (f32x4){0.f,0.f,0.f,0.f};
    #pragma unroll
    for (int r4=0;r4<4;++r4){
      const f32x4 xv = *(const f32x4*)(xr + r4*4);
      const f32x4 wv = *(const f32x4*)(wr + r4*4);
      acc4 += xv*wv;
    }
    const float a = dtbp[c] + acc4[0]+acc4[1]+acc4[2]+acc4[3];
    dto[(tokbase + t0 + tk)*DIN_ + c] = (a > 20.f) ? a : log1pf(__expf(a));
  }
}

// ---------------- chunked selective scan ----------------
template<int PASS>
__global__ __launch_bounds__(512)
void scan_k(const float* __restrict__ dt, const float* __restrict__ u,
            const float* __restrict__ xd, const float* __restrict__ an,
            const float* __restrict__ xz, const float* __restrict__ dsk,
            float* __restrict__ hp, float* __restrict__ pp,
            u16* __restrict__ ybar)
{
  const int ch = threadIdx.x;                         // 0..511
  const int blk = blockIdx.x;                         // (dir*4+b)*16 + chunk
  const int chunk = blk & 15, bb = (blk>>4)&3, dir = blk>>6;
  const size_t tokbase = (size_t)(dir*4+bb)*1024 + (size_t)chunk*64;
  const float* ap = an + (size_t)dir*(NL*DIN_*16) + (size_t)ch*16;
  float A_[16];
  #pragma unroll
  for (int n=0;n<16;++n) A_[n] = ap[n];
  const size_t scanid = (size_t)(dir*4+bb)*512 + ch;
  const size_t hbase = (scanid*16 + chunk)*16;
  float h[16], P[16];
  if constexpr (PASS==1){
    #pragma unroll
    for (int n=0;n<16;++n){ h[n]=0.f; P[n]=1.f; }
  } else {
    #pragma unroll
    for (int n=0;n<16;++n) h[n] = hp[hbase+n];
  }
  float dval = 0.f;
  if constexpr (PASS==2) dval = dsk[(size_t)dir*(NL*DIN_) + ch];
  for (int t=0;t<64;++t){
    const size_t tok = tokbase + t;
    const float dtv = dt[tok*DIN_ + ch];
    const float uv  = u[tok*DIN_ + ch];
    const float dtu = dtv*uv;
    const float* xr = xd + tok*48;
    float y = 0.f;
    #pragma unroll
    for (int n=0;n<16;++n){
      const float e = __expf(dtv*A_[n]);
      const float hn2 = h[n]*e + dtu*xr[16+n];
      h[n] = hn2;
      if constexpr (PASS==1) P[n] *= e;
      else y += hn2*xr[32+n];
    }
    if constexpr (PASS==2){
      const float zv = xz[tok*1024 + 512 + ch];
      ybar[tok*DIN_ + ch] = f2b((y + uv*dval) * (zv * sigm(zv)));
    }
  }
  if constexpr (PASS==1){
    #pragma unroll
    for (int n=0;n<16;++n){ hp[hbase+n] = h[n]; pp[hbase+n] = P[n]; }
  }
}

__global__ void scanfix_k(float* __restrict__ hp, const float* __restrict__ pp){
  const int id = blockIdx.x*256 + threadIdx.x;        // 0..4095
  float s[16];
  #pragma unroll
  for (int n=0;n<16;++n) s[n] = 0.f;
  for (int c=0;c<16;++c){
    const size_t base = ((size_t)id*16 + c)*16;
    #pragma unroll
    for (int n=0;n<16;++n){
      const float hv = hp[base+n];
      const float pv = pp[base+n];
      hp[base+n] = s[n];
      s[n] = hv + pv*s[n];
    }
  }
}

// ---------------- curr = states + resid ; gating (f32) ----------------
__global__ __launch_bounds__(256)
void currgate_k(const float* __restrict__ st, const float* __restrict__ rs,
                const float* __restrict__ gw, const float* __restrict__ gb,
                u16* __restrict__ currb, float* __restrict__ gate)
{
  const int wv = threadIdx.x>>6, lane = threadIdx.x&63;
  const int tok = blockIdx.x*4 + wv;
  const int dir = tok>>12;
  const size_t base = (size_t)tok*256 + lane*4;
  f32x4 a = *(const f32x4*)(st+base);
  { f32x4 c = *(const f32x4*)(rs+base); a += c; }
  s16x4 cc;
  #pragma unroll
  for (int j=0;j<4;++j) cc[j] = (short)f2b(a[j]);
  *(s16x4*)(currb+base) = cc;
  const float* gwp = gw + (size_t)dir*(NL*NE*256);
  float lg[4];
  #pragma unroll
  for (int e=0;e<4;++e){
    const float* w4 = gwp + e*256 + lane*4;
    lg[e] = a[0]*w4[0] + a[1]*w4[1] + a[2]*w4[2] + a[3]*w4[3];
  }
  #pragma unroll
  for (int o=32;o;o>>=1){
    #pragma unroll
    for (int e=0;e<4;++e) lg[e] += __shfl_xor(lg[e], o);
  }
  if (lane==0){
    const float* gbp = gb + dir*(NL*NE);
    float sc[4]; float mx = -1e30f;
    #pragma unroll
    for (int e=0;e<4;++e){ sc[e] = lg[e] + gbp[e]; mx = fmaxf(mx, sc[e]); }
    float den = 0.f;
    #pragma unroll
    for (int e=0;e<4;++e){ sc[e] = __expf(sc[e]-mx); den += sc[e]; }
    const float rden = 1.f/den;
    #pragma unroll
    for (int e=0;e<4;++e) sc[e] *= rden;
    int i1 = 0;
    #pragma unroll
    for (int e=1;e<4;++e) if (sc[e] > sc[i1]) i1 = e;
    int i2 = (i1==0)?1:0;
    #pragma unroll
    for (int e=0;e<4;++e) if (e!=i1 && sc[e] > sc[i2]) i2 = e;
    const float ssum = sc[i1] + sc[i2] + 1e-6f;
    #pragma unroll
    for (int e=0;e<4;++e)
      gate[(size_t)tok*4+e] = (e==i1) ? sc[i1]/ssum : ((e==i2) ? sc[i2]/ssum : 0.f);
  }
}

// ---------------- pooling (parallel, 4-stage) ----------------
__global__ __launch_bounds__(256)
void poolscore_k(const float* __restrict__ fin, const float* __restrict__ fw,
                 const float* __restrict__ fb, const float* __restrict__ bw,
                 const float* __restrict__ bbs, float* __restrict__ score)
{
  const int blk = blockIdx.x;                   // p = blk>>3, g = blk&7
  const int p = blk >> 3, g = blk & 7;
  const int dir = p >> 2;
  const float* pw = dir ? bw : fw;
  const float pb = dir ? bbs[0] : fb[0];
  const int wv = threadIdx.x>>6, lane = threadIdx.x&63;
  const size_t fbase = (size_t)p*1024*256;
  const f32x4 w4 = *(const f32x4*)(pw + lane*4);
  for (int l = g*128 + wv; l < (g+1)*128; l += 4){
    const f32x4 f4 = *(const f32x4*)(fin + fbase + (size_t)l*256 + lane*4);
    float pv = f4[0]*w4[0] + f4[1]*w4[1] + f4[2]*w4[2] + f4[3]*w4[3];
    #pragma unroll
    for (int o=32;o;o>>=1) pv += __shfl_xor(pv,o);
    if (lane==0) score[p*1024 + l] = pv + pb;
  }
}

__global__ __launch_bounds__(256)
void poolnorm_k(float* __restrict__ score)
{
  __shared__ float red[8];
  const int p = blockIdx.x;
  const int tid = threadIdx.x, wv = tid>>6, lane = tid&63;
  float* s = score + p*1024;
  float v[4];
  float m = -1e30f;
  #pragma unroll
  for (int j=0;j<4;++j){ v[j] = s[tid + j*256]; m = fmaxf(m, v[j]); }
  #pragma unroll
  for (int o=32;o;o>>=1) m = fmaxf(m, __shfl_xor(m,o));
  if (lane==0) red[wv] = m;
  __syncthreads();
  m = fmaxf(fmaxf(red[0],red[1]), fmaxf(red[2],red[3]));
  float ssum = 0.f;
  #pragma unroll
  for (int j=0;j<4;++j){ v[j] = __expf(v[j]-m); ssum += v[j]; }
  #pragma unroll
  for (int o=32;o;o>>=1) ssum += __shfl_xor(ssum,o);
  if (lane==0) red[4+wv] = ssum;
  __syncthreads();
  const float inv = 1.f/(red[4]+red[5]+red[6]+red[7]);
  #pragma unroll
  for (int j=0;j<4;++j) s[tid + j*256] = v[j]*inv;
}

__global__ __launch_bounds__(256)
void poolsum_k(const float* __restrict__ fin, const float* __restrict__ score,
               float* __restrict__ part)
{
  const int blk = blockIdx.x;                   // p = blk>>4, g = blk&15
  const int p = blk >> 4, g = blk & 15;
  const int d = threadIdx.x;
  const size_t fbase = (size_t)p*1024*256;
  float acc = 0.f;
  #pragma unroll 4
  for (int l = g*64; l < (g+1)*64; ++l)
    acc += score[p*1024 + l] * fin[fbase + (size_t)l*256 + d];
  part[((size_t)p*16 + g)*256 + d] = acc;
}

__global__ __launch_bounds__(256)
void head_k(const float* __restrict__ part, const float* __restrict__ llw,
            const float* __restrict__ llb, float* __restrict__ out)
{
  __shared__ float sp[8*256];
  const int d = threadIdx.x;
  #pragma unroll
  for (int p=0;p<8;++p){
    float a = 0.f;
    #pragma unroll
    for (int g=0;g<16;++g) a += part[((size_t)p*16+g)*256 + d];
    sp[p*256 + d] = a;
  }
  __syncthreads();
  const int o = d;
  for (int b=0;b<4;++b){
    float acc = llb[o];
    const float* wr = llw + (size_t)o*512;
    const float* pf = sp + b*256;
    const float* pk = sp + (4+b)*256;
    #pragma unroll 8
    for (int j=0;j<256;++j) acc += pf[j]*wr[j];
    #pragma unroll 8
    for (int j=0;j<256;++j) acc += pk[j]*wr[256+j];
    out[b*256+o] = acc;
  }
}

// ---------------- host ----------------
extern "C" void kernel_launch(void* const* d_in, const int* in_sizes, int n_in,
                              void* d_out, int out_size, void* d_ws, size_t ws_size,
                              hipStream_t stream)
{
  const float* in_x    = (const float*)d_in[0];
  const float* in_inw  = (const float*)d_in[1];
  const float* in_cw   = (const float*)d_in[2];
  const float* in_cb   = (const float*)d_in[3];
  const float* in_xpw  = (const float*)d_in[4];
  const float* in_dtw  = (const float*)d_in[5];
  const float* in_dtb  = (const float*)d_in[6];
  const float* in_alog = (const float*)d_in[7];
  const float* in_dsk  = (const float*)d_in[8];
  const float* in_ow   = (const float*)d_in[9];
  const float* in_nw   = (const float*)d_in[10];
  const float* in_nb   = (const float*)d_in[11];
  const float* in_gw   = (const float*)d_in[12];
  const float* in_gb   = (const float*)d_in[13];
  const float* in_e1w  = (const float*)d_in[14];
  const float* in_e1b  = (const float*)d_in[15];
  const float* in_e2w  = (const float*)d_in[16];
  const float* in_e2b  = (const float*)d_in[17];
  const float* in_nfw  = (const float*)d_in[18];
  const float* in_nfb  = (const float*)d_in[19];
  const float* in_fpw  = (const float*)d_in[20];
  const float* in_fpb  = (const float*)d_in[21];
  const float* in_bpw  = (const float*)d_in[22];
  const float* in_bpb  = (const float*)d_in[23];
  const float* in_llw  = (const float*)d_in[24];
  const float* in_llb  = (const float*)d_in[25];

  uint8_t* ws = (uint8_t*)d_ws;
  size_t off = 0;
  auto take = [&](size_t bytes)->size_t{
    size_t o = off; off += (bytes + 255) & ~(size_t)255; return o;
  };
  float* f_xall = (float*)(ws + take((size_t)TOK*256*4));   // reused as f_fin
  float* f_res  = (float*)(ws + take((size_t)TOK*256*4));
  float* f_st   = (float*)(ws + take((size_t)TOK*256*4));
  float* f_xz   = (float*)(ws + take((size_t)TOK*1024*4));
  float* f_u    = (float*)(ws + take((size_t)TOK*DIN_*4));
  float* f_dt   = (float*)(ws + take((size_t)TOK*DIN_*4));
  float* f_xd   = (float*)(ws + take((size_t)TOK*48*4));
  float* f_hp   = (float*)(ws + take((size_t)4096*16*16*4));
  float* f_pp   = (float*)(ws + take((size_t)4096*16*16*4));
  float* f_gate = (float*)(ws + take((size_t)TOK*4*4));
  float* f_an   = (float*)(ws + take((size_t)2*NL*DIN_*16*4));
  float* f_score= (float*)(ws + take((size_t)8*1024*4));
  float* f_part = (float*)(ws + take((size_t)8*16*256*4));
  u16* b_hn   = (u16*)(ws + take((size_t)TOK*256*2));
  u16* b_ybar = (u16*)(ws + take((size_t)TOK*DIN_*2));
  u16* b_curr = (u16*)(ws + take((size_t)TOK*256*2));
  u16* b_h    = (u16*)(ws + take((size_t)TOK*4096*2));
  u16* b_win  = (u16*)(ws + take((size_t)2*NL*1024*256*2));
  u16* b_wout = (u16*)(ws + take((size_t)2*NL*256*512*2));
  u16* b_we1  = (u16*)(ws + take((size_t)2*NL*NE*HM*256*2));
  u16* b_we2  = (u16*)(ws + take((size_t)2*NL*NE*256*HM*2));
  float* f_fin  = f_xall;
  (void)ws_size; (void)in_sizes; (void)n_in; (void)out_size;

  // prep: weights -> bf16
  cvt_bf16_k<<<1024,256,0,stream>>>(in_inw, b_win, 2*NL*1024*256/4);
  cvt_bf16_k<<<1024,256,0,stream>>>(in_ow,  b_wout, 2*NL*256*512/4);
  cvt_bf16_k<<<2048,256,0,stream>>>(in_e1w, b_we1, 2*NL*NE*HM*256/4);
  cvt_bf16_k<<<2048,256,0,stream>>>(in_e2w, b_we2, 2*NL*NE*256*HM/4);
  aneg_k<<<256,256,0,stream>>>(in_alog, f_an, 2*NL*DIN_*16);
  xall_k<<<8192,256,0,stream>>>(in_x, f_xall);

  for (int i=0;i<NL;++i){
    lnres_k<0><<<2048,256,0,stream>>>(i==0 ? f_xall : f_res, i==0 ? nullptr : f_st,
                                      in_nw + i*256, in_nb + i*256, f_res, b_hn);
    gemm_k<0><<<dim3(32,8,2),256,0,stream>>>(b_hn, b_win + (size_t)i*1024*256,
                                             f_xz, nullptr, nullptr, nullptr, nullptr);
    convproj_k<<<512,256,0,stream>>>(f_xz, in_cw + i*DIN_*4, in_cb + i*DIN_,
                                     in_xpw + i*48*DIN_, in_dtw + i*DIN_*16, in_dtb + i*DIN_,
                                     f_u, f_dt, f_xd);
    scan_k<1><<<128,512,0,stream>>>(f_dt, f_u, f_xd, f_an + i*DIN_*16,
                                    nullptr, nullptr, f_hp, f_pp, nullptr);
    scanfix_k<<<16,256,0,stream>>>(f_hp, f_pp);
    scan_k<2><<<128,512,0,stream>>>(f_dt, f_u, f_xd, f_an + i*DIN_*16,
                                    f_xz, in_dsk + i*DIN_, f_hp, f_pp, b_ybar);
    gemm_k<1><<<dim3(32,4,2),256,0,stream>>>(b_ybar, b_wout + (size_t)i*256*512,
                                             f_st, nullptr, nullptr, nullptr, nullptr);
    currgate_k<<<2048,256,0,stream>>>(f_st, f_res, in_gw + i*NE*256, in_gb + i*NE,
                                      b_curr, f_gate);
    gemm_k<2><<<dim3(32,8,8),256,0,stream>>>(b_curr, b_we1 + (size_t)i*NE*HM*256,
                                             nullptr, b_h,
                                             in_e1b + i*NE*HM, f_gate, nullptr);
    gemm_k<3><<<dim3(32,4,2),256,0,stream>>>(b_h, b_we2 + (size_t)i*NE*256*HM,
                                             f_res, nullptr,
                                             nullptr, f_gate, in_e2b + i*NE*256);
  }

  lnres_k<1><<<2048,256,0,stream>>>(f_res, f_st, in_nfw, in_nfb, f_fin, nullptr);
  poolscore_k<<<64,256,0,stream>>>(f_fin, in_fpw, in_fpb, in_bpw, in_bpb, f_score);
  poolnorm_k<<<8,256,0,stream>>>(f_score);
  poolsum_k<<<128,256,0,stream>>>(f_fin, f_score, f_part);
  head_k<<<1,256,0,stream>>>(f_part, in_llw, in_llb, (float*)d_out);
}

// Round 10
// 1281.971 us; speedup vs baseline: 6.7135x; 1.0321x over previous
//
#include <hip/hip_runtime.h>
#include <cstdint>
#include <cstddef>

typedef __attribute__((ext_vector_type(4))) float f32x4;
typedef __attribute__((ext_vector_type(8))) short s16x8;
typedef __attribute__((ext_vector_type(4))) short s16x4;
using u16 = unsigned short;

constexpr int NL   = 4;
constexpr int DIN_ = 512;
constexpr int HM   = 1024;
constexpr int NE   = 4;
constexpr int TPD  = 4096;   // tokens per direction (B*L)
constexpr int TOK  = 8192;   // both directions
constexpr int NCH  = 32;     // scan chunks per sequence
constexpr int CLEN = 32;     // steps per chunk

__device__ __forceinline__ u16 f2b(float f){
  unsigned u = __builtin_bit_cast(unsigned, f);
  u += 0x7fffu + ((u >> 16) & 1u);
  return (u16)(u >> 16);
}
__device__ __forceinline__ float sigm(float x){ return 1.f/(1.f + __expf(-x)); }

// ---------------- prep kernels ----------------
__global__ void cvt_bf16_k(const float* __restrict__ s, u16* __restrict__ d, int n4){
  int i = blockIdx.x*blockDim.x + threadIdx.x;
  const int st = gridDim.x*blockDim.x;
  for (; i < n4; i += st){
    const f32x4 v = *(const f32x4*)(s + (size_t)i*4);
    s16x4 o;
    #pragma unroll
    for (int j=0;j<4;++j) o[j] = (short)f2b(v[j]);
    *(s16x4*)(d + (size_t)i*4) = o;
  }
}

__global__ void aneg_k(const float* __restrict__ a, float* __restrict__ o, int n){
  int i = blockIdx.x*256 + threadIdx.x;
  if (i < n) o[i] = -__expf(a[i]);
}

__global__ void xall_k(const float* __restrict__ x, float* __restrict__ o){
  const int i = blockIdx.x*256 + threadIdx.x;           // [0, 2*4*1024*256)
  const int d = i & 255, l = (i>>8)&1023, b2 = (i>>18)&3, dir = i>>20;
  const int ls = dir ? (1023 - l) : l;
  o[i] = x[((size_t)(b2<<10) + ls)*256 + d];
}

// ---------------- LN (+residual) ----------------
template<int MODE>
__global__ __launch_bounds__(256)
void lnres_k(const float* __restrict__ s1, const float* __restrict__ s2,
             const float* __restrict__ w, const float* __restrict__ b,
             float* __restrict__ fout, u16* __restrict__ hnout)
{
  const int wv = threadIdx.x >> 6, lane = threadIdx.x & 63;
  const int tok = blockIdx.x*4 + wv;
  const int dir = tok >> 12;
  const size_t base = (size_t)tok*256 + lane*4;
  f32x4 r = *(const f32x4*)(s1 + base);
  if (s2){ f32x4 c = *(const f32x4*)(s2 + base); r += c; }
  float sv = r[0]+r[1]+r[2]+r[3];
  float qv = r[0]*r[0]+r[1]*r[1]+r[2]*r[2]+r[3]*r[3];
  #pragma unroll
  for (int o=32;o;o>>=1){ sv += __shfl_xor(sv,o); qv += __shfl_xor(qv,o); }
  const float mu = sv*(1.f/256.f);
  const float var = qv*(1.f/256.f) - mu*mu;
  const float inv = rsqrtf(var + 1e-5f);
  const int woff = (MODE==0) ? dir*(NL*256) : 0;
  const f32x4 w4 = *(const f32x4*)(w + woff + lane*4);
  const f32x4 b4 = *(const f32x4*)(b + woff + lane*4);
  f32x4 y;
  #pragma unroll
  for (int j=0;j<4;++j) y[j] = (r[j]-mu)*inv*w4[j] + b4[j];
  if constexpr (MODE==0){
    *(f32x4*)(fout + base) = r;
    s16x4 hh;
    #pragma unroll
    for (int j=0;j<4;++j) hh[j] = (short)f2b(y[j]);
    *(s16x4*)(hnout + base) = hh;
  } else {
    *(f32x4*)(fout + base) = y;
  }
}

// ---------------- MFMA bf16 GEMM: C = A @ W^T ----------------
// CFG 0: in_proj  N=1024 K=256  -> OF f32 (f_xz)
// CFG 1: out_proj N=256  K=512  -> OF f32 (f_st)
// CFG 2: moe h    z=dir*4+e, N=1024 K=256 -> OB bf16 = gate*gelu(acc+b1)
// CFG 3: moe o    folded K=4096, N=256    -> OF f32 resid += acc + sum_e g*b2
template<int CFG>
__global__ __launch_bounds__(256, 2)
void gemm_k(const u16* __restrict__ A0, const u16* __restrict__ W0,
            float* OF, u16* OB,
            const float* __restrict__ P0, const float* __restrict__ P1,
            const float* __restrict__ P2)
{
  constexpr int BM = 128;
  constexpr int BN = (CFG==1 || CFG==3) ? 64 : 128;
  constexpr int KD = (CFG==0 || CFG==2) ? 256 : (CFG==1 ? 512 : 4096);
  constexpr int LDA = KD;
  constexpr int FM = 4;
  constexpr int FN = BN/32;
  constexpr int IA = 2;
  constexpr int IB = BN/64;

  __shared__ u16 sA[BM*32];
  __shared__ u16 sB[BN*32];

  const int tid = threadIdx.x;
  const int wave = tid >> 6, lane = tid & 63;
  const int bm0 = blockIdx.x * BM, bn0 = blockIdx.y * BN;
  const int z = blockIdx.z;
  const int wm0 = (wave >> 1) * 64;
  const int wn0 = (wave & 1) * (BN/2);

  const u16* Az; const u16* Wz;
  if constexpr (CFG==0){ Az = A0 + (size_t)z*TPD*256;  Wz = W0 + (size_t)z*(NL*1024*256); }
  else if constexpr (CFG==1){ Az = A0 + (size_t)z*TPD*512; Wz = W0 + (size_t)z*(NL*256*512); }
  else if constexpr (CFG==2){ Az = A0 + (size_t)(z>>2)*TPD*256;
                              Wz = W0 + (size_t)(z>>2)*((size_t)NL*NE*HM*256) + (size_t)(z&3)*(HM*256); }
  else { Az = A0 + (size_t)z*TPD*4096; Wz = W0 + (size_t)z*((size_t)NL*NE*256*HM); }

  f32x4 acc[FM][FN];
  #pragma unroll
  for (int i=0;i<FM;++i)
    #pragma unroll
    for (int j=0;j<FN;++j) acc[i][j] = (f32x4){0.f,0.f,0.f,0.f};

  const int r = lane & 15, q = lane >> 4;

  for (int k0 = 0; k0 < KD; k0 += 32){
    #pragma unroll
    for (int j=0;j<IA;++j){
      const int c = (wave*IA + j)*64 + lane;
      const int m = c >> 2, kq = c & 3;
      const u16* g = Az + (size_t)(bm0 + m)*LDA + (k0 + kq*8);
      __builtin_amdgcn_global_load_lds((const __attribute__((address_space(1))) void*)g,
          (__attribute__((address_space(3))) void*)(sA + (size_t)(wave*IA + j)*512), 16, 0, 0);
    }
    #pragma unroll
    for (int j=0;j<IB;++j){
      const int c = (wave*IB + j)*64 + lane;
      const int n = c >> 2, kq = c & 3;
      const u16* g;
      if constexpr (CFG==3){
        g = Wz + ((size_t)(k0 >> 10)*256 + (bn0 + n))*1024 + ((k0 & 1023) + kq*8);
      } else {
        g = Wz + (size_t)(bn0 + n)*KD + (k0 + kq*8);
      }
      __builtin_amdgcn_global_load_lds((const __attribute__((address_space(1))) void*)g,
          (__attribute__((address_space(3))) void*)(sB + (size_t)(wave*IB + j)*512), 16, 0, 0);
    }
    __syncthreads();
    s16x8 av[FM], bv[FN];
    #pragma unroll
    for (int mi=0;mi<FM;++mi) av[mi] = *(const s16x8*)(sA + (wm0 + mi*16 + r)*32 + q*8);
    #pragma unroll
    for (int ni=0;ni<FN;++ni) bv[ni] = *(const s16x8*)(sB + (wn0 + ni*16 + r)*32 + q*8);
    #pragma unroll
    for (int mi=0;mi<FM;++mi)
      #pragma unroll
      for (int ni=0;ni<FN;++ni)
        acc[mi][ni] = __builtin_amdgcn_mfma_f32_16x16x32_bf16(av[mi], bv[ni], acc[mi][ni], 0, 0, 0);
    __syncthreads();
  }

  #pragma unroll
  for (int mi=0;mi<FM;++mi){
    #pragma unroll
    for (int ni=0;ni<FN;++ni){
      const int col = bn0 + wn0 + ni*16 + r;
      #pragma unroll
      for (int rr=0;rr<4;++rr){
        const int row = bm0 + wm0 + mi*16 + q*4 + rr;
        const float v = acc[mi][ni][rr];
        if constexpr (CFG==0){
          OF[((size_t)z*TPD + row)*1024 + col] = v;
        } else if constexpr (CFG==1){
          OF[((size_t)z*TPD + row)*256 + col] = v;
        } else if constexpr (CFG==2){
          const int dir = z>>2, e = z&3;
          const float xv = v + P0[(size_t)dir*(NL*NE*HM) + (size_t)e*HM + col];
          const float ge = 0.5f*xv*(1.f + erff(xv*0.70710678118654752f));
          const float gt = P1[((size_t)dir*TPD + row)*4 + e];
          OB[((size_t)dir*TPD + row)*4096 + (size_t)e*1024 + col] = f2b(ge*gt);
        } else {
          const float* b2p = P2 + (size_t)z*(NL*NE*256);
          const float* gp  = P1 + ((size_t)z*TPD + row)*4;
          const float bias = gp[0]*b2p[col] + gp[1]*b2p[256+col]
                           + gp[2]*b2p[512+col] + gp[3]*b2p[768+col];
          const size_t oi = ((size_t)z*TPD + row)*256 + col;
          OF[oi] = OF[oi] + v + bias;
        }
      }
    }
  }
}

// ---------------- fused conv + silu + x_proj + dt_proj (16 tokens/block, f32x4) ----------------
__global__ __launch_bounds__(256)
void convproj_k(const float* __restrict__ xz,
                const float* __restrict__ cw, const float* __restrict__ cb,
                const float* __restrict__ xpw,
                const float* __restrict__ dtw, const float* __restrict__ dtb,
                float* __restrict__ uo, float* __restrict__ dto,
                float* __restrict__ xdo)
{
  __shared__ float sxs[19*516];
  __shared__ float sxd[16*48];
  const int tid = threadIdx.x;
  const int blk = blockIdx.x;                       // 512 blocks
  const int tc = blk & 63, bb = (blk>>6)&3, dir = blk>>8;
  const int t0 = tc*16;
  const size_t tokbase = (size_t)(dir*4+bb)*1024;

  for (int idx = tid; idx < 19*128; idx += 256){
    const int rr = idx >> 7, c4 = idx & 127;
    const int t = t0 - 3 + rr;
    f32x4 v = (f32x4){0.f,0.f,0.f,0.f};
    if (t >= 0) v = *(const f32x4*)(xz + (tokbase + t)*1024 + c4*4);
    *(f32x4*)(sxs + rr*516 + c4*4) = v;
  }
  __syncthreads();

  const float* cwp = cw + (size_t)dir*(NL*DIN_*4);
  const float* cbp = cb + (size_t)dir*(NL*DIN_);
  f32x4 ur[8];
  #pragma unroll
  for (int s=0;s<8;++s){
    const int o4 = tid + s*256;                     // 0..2047
    const int tk = o4 >> 7, c4 = o4 & 127;
    const f32x4 w0 = *(const f32x4*)(cwp + c4*16);
    const f32x4 w1 = *(const f32x4*)(cwp + c4*16 + 4);
    const f32x4 w2 = *(const f32x4*)(cwp + c4*16 + 8);
    const f32x4 w3 = *(const f32x4*)(cwp + c4*16 + 12);
    const f32x4 cb4 = *(const f32x4*)(cbp + c4*4);
    const f32x4 x0 = *(const f32x4*)(sxs + (tk+0)*516 + c4*4);
    const f32x4 x1 = *(const f32x4*)(sxs + (tk+1)*516 + c4*4);
    const f32x4 x2 = *(const f32x4*)(sxs + (tk+2)*516 + c4*4);
    const f32x4 x3 = *(const f32x4*)(sxs + (tk+3)*516 + c4*4);
    f32x4 a;
    a[0] = cb4[0] + x0[0]*w0[0] + x1[0]*w0[1] + x2[0]*w0[2] + x3[0]*w0[3];
    a[1] = cb4[1] + x0[1]*w1[0] + x1[1]*w1[1] + x2[1]*w1[2] + x3[1]*w1[3];
    a[2] = cb4[2] + x0[2]*w2[0] + x1[2]*w2[1] + x2[2]*w2[2] + x3[2]*w2[3];
    a[3] = cb4[3] + x0[3]*w3[0] + x1[3]*w3[1] + x2[3]*w3[2] + x3[3]*w3[3];
    f32x4 uv;
    #pragma unroll
    for (int j=0;j<4;++j) uv[j] = a[j]*sigm(a[j]);
    ur[s] = uv;
    *(f32x4*)(uo + (tokbase + t0 + tk)*DIN_ + c4*4) = uv;
  }
  __syncthreads();
  float* su = sxs;                                   // reuse as [16][516]
  #pragma unroll
  for (int s=0;s<8;++s){
    const int o4 = tid + s*256;
    const int tk = o4 >> 7, c4 = o4 & 127;
    *(f32x4*)(su + tk*516 + c4*4) = ur[s];
  }
  __syncthreads();

  const float* xpwp = xpw + (size_t)dir*(NL*48*DIN_);
  #pragma unroll
  for (int s=0;s<3;++s){
    const int o = tid + s*256;
    const int j = o >> 4, tk = o & 15;
    const float* wr = xpwp + (size_t)j*DIN_;
    const float* sur = su + tk*516;
    f32x4 acc4 = (f32x4){0.f,0.f,0.f,0.f};
    #pragma unroll 8
    for (int k4=0;k4<128;++k4){
      const f32x4 uv = *(const f32x4*)(sur + k4*4);
      const f32x4 wv = *(const f32x4*)(wr + k4*4);
      acc4 += uv*wv;
    }
    const float a = acc4[0]+acc4[1]+acc4[2]+acc4[3];
    sxd[tk*48 + j] = a;
    if (j >= 16) xdo[(tokbase + t0 + tk)*48 + j] = a;   // scan reads only 16..47
  }
  __syncthreads();

  const float* dtwp = dtw + (size_t)dir*(NL*DIN_*16);
  const float* dtbp = dtb + (size_t)dir*(NL*DIN_);
  #pragma unroll
  for (int s=0;s<32;++s){
    const int o = tid + s*256;
    const int tk = o >> 9, c = o & 511;
    const float* wr = dtwp + (size_t)c*16;
    const float* xr = sxd + tk*48;
    f32x4 acc4 = (f32x4){0.f,0.f,0.f,0.f};
    #pragma unroll
    for (int r4=0;r4<4;++r4){
      const f32x4 xv = *(const f32x4*)(xr + r4*4);
      const f32x4 wv = *(const f32x4*)(wr + r4*4);
      acc4 += xv*wv;
    }
    const float a = dtbp[c] + acc4[0]+acc4[1]+acc4[2]+acc4[3];
    dto[(tokbase + t0 + tk)*DIN_ + c] = (a > 20.f) ? a : log1pf(__expf(a));
  }
}

// ---------------- chunked selective scan (32 chunks x 32 steps) ----------------
template<int PASS>
__global__ __launch_bounds__(512)
void scan_k(const float* __restrict__ dt, const float* __restrict__ u,
            const float* __restrict__ xd, const float* __restrict__ an,
            const float* __restrict__ xz, const float* __restrict__ dsk,
            float* __restrict__ hp, float* __restrict__ pp,
            u16* __restrict__ ybar)
{
  const int ch = threadIdx.x;                         // 0..511
  const int blk = blockIdx.x;                         // (dir*4+b)*NCH + chunk
  const int chunk = blk & (NCH-1), bb = (blk>>5)&3, dir = blk>>7;
  const size_t tokbase = (size_t)(dir*4+bb)*1024 + (size_t)chunk*CLEN;
  const float* ap = an + (size_t)dir*(NL*DIN_*16) + (size_t)ch*16;
  float A_[16];
  #pragma unroll
  for (int n=0;n<16;++n) A_[n] = ap[n];
  const size_t scanid = (size_t)(dir*4+bb)*512 + ch;
  const size_t hbase = (scanid*NCH + chunk)*16;
  float h[16], P[16];
  if constexpr (PASS==1){
    #pragma unroll
    for (int n=0;n<16;++n){ h[n]=0.f; P[n]=1.f; }
  } else {
    #pragma unroll
    for (int n=0;n<16;++n) h[n] = hp[hbase+n];
  }
  float dval = 0.f;
  if constexpr (PASS==2) dval = dsk[(size_t)dir*(NL*DIN_) + ch];
  for (int t=0;t<CLEN;++t){
    const size_t tok = tokbase + t;
    const float dtv = dt[tok*DIN_ + ch];
    const float uv  = u[tok*DIN_ + ch];
    const float dtu = dtv*uv;
    const float* xr = xd + tok*48;
    float y = 0.f;
    #pragma unroll
    for (int n=0;n<16;++n){
      const float e = __expf(dtv*A_[n]);
      const float hn2 = h[n]*e + dtu*xr[16+n];
      h[n] = hn2;
      if constexpr (PASS==1) P[n] *= e;
      else y += hn2*xr[32+n];
    }
    if constexpr (PASS==2){
      const float zv = xz[tok*1024 + 512 + ch];
      ybar[tok*DIN_ + ch] = f2b((y + uv*dval) * (zv * sigm(zv)));
    }
  }
  if constexpr (PASS==1){
    #pragma unroll
    for (int n=0;n<16;++n){ hp[hbase+n] = h[n]; pp[hbase+n] = P[n]; }
  }
}

__global__ void scanfix_k(float* __restrict__ hp, const float* __restrict__ pp){
  const int id = blockIdx.x*256 + threadIdx.x;        // 0..4095
  float s[16];
  #pragma unroll
  for (int n=0;n<16;++n) s[n] = 0.f;
  for (int c=0;c<NCH;++c){
    const size_t base = ((size_t)id*NCH + c)*16;
    #pragma unroll
    for (int n=0;n<16;++n){
      const float hv = hp[base+n];
      const float pv = pp[base+n];
      hp[base+n] = s[n];
      s[n] = hv + pv*s[n];
    }
  }
}

// ---------------- curr = states + resid ; gating (f32) ----------------
__global__ __launch_bounds__(256)
void currgate_k(const float* __restrict__ st, const float* __restrict__ rs,
                const float* __restrict__ gw, const float* __restrict__ gb,
                u16* __restrict__ currb, float* __restrict__ gate)
{
  const int wv = threadIdx.x>>6, lane = threadIdx.x&63;
  const int tok = blockIdx.x*4 + wv;
  const int dir = tok>>12;
  const size_t base = (size_t)tok*256 + lane*4;
  f32x4 a = *(const f32x4*)(st+base);
  { f32x4 c = *(const f32x4*)(rs+base); a += c; }
  s16x4 cc;
  #pragma unroll
  for (int j=0;j<4;++j) cc[j] = (short)f2b(a[j]);
  *(s16x4*)(currb+base) = cc;
  const float* gwp = gw + (size_t)dir*(NL*NE*256);
  float lg[4];
  #pragma unroll
  for (int e=0;e<4;++e){
    const float* w4 = gwp + e*256 + lane*4;
    lg[e] = a[0]*w4[0] + a[1]*w4[1] + a[2]*w4[2] + a[3]*w4[3];
  }
  #pragma unroll
  for (int o=32;o;o>>=1){
    #pragma unroll
    for (int e=0;e<4;++e) lg[e] += __shfl_xor(lg[e], o);
  }
  if (lane==0){
    const float* gbp = gb + dir*(NL*NE);
    float sc[4]; float mx = -1e30f;
    #pragma unroll
    for (int e=0;e<4;++e){ sc[e] = lg[e] + gbp[e]; mx = fmaxf(mx, sc[e]); }
    float den = 0.f;
    #pragma unroll
    for (int e=0;e<4;++e){ sc[e] = __expf(sc[e]-mx); den += sc[e]; }
    const float rden = 1.f/den;
    #pragma unroll
    for (int e=0;e<4;++e) sc[e] *= rden;
    int i1 = 0;
    #pragma unroll
    for (int e=1;e<4;++e) if (sc[e] > sc[i1]) i1 = e;
    int i2 = (i1==0)?1:0;
    #pragma unroll
    for (int e=0;e<4;++e) if (e!=i1 && sc[e] > sc[i2]) i2 = e;
    const float ssum = sc[i1] + sc[i2] + 1e-6f;
    #pragma unroll
    for (int e=0;e<4;++e)
      gate[(size_t)tok*4+e] = (e==i1) ? sc[i1]/ssum : ((e==i2) ? sc[i2]/ssum : 0.f);
  }
}

// ---------------- pooling (parallel) ----------------
__global__ __launch_bounds__(256)
void poolscore_k(const float* __restrict__ fin, const float* __restrict__ fw,
                 const float* __restrict__ fb, const float* __restrict__ bw,
                 const float* __restrict__ bbs, float* __restrict__ score)
{
  const int blk = blockIdx.x;                   // p = blk>>3, g = blk&7
  const int p = blk >> 3, g = blk & 7;
  const int dir = p >> 2;
  const float* pw = dir ? bw : fw;
  const float pb = dir ? bbs[0] : fb[0];
  const int wv = threadIdx.x>>6, lane = threadIdx.x&63;
  const size_t fbase = (size_t)p*1024*256;
  const f32x4 w4 = *(const f32x4*)(pw + lane*4);
  for (int l = g*128 + wv; l < (g+1)*128; l += 4){
    const f32x4 f4 = *(const f32x4*)(fin + fbase + (size_t)l*256 + lane*4);
    float pv = f4[0]*w4[0] + f4[1]*w4[1] + f4[2]*w4[2] + f4[3]*w4[3];
    #pragma unroll
    for (int o=32;o;o>>=1) pv += __shfl_xor(pv,o);
    if (lane==0) score[p*1024 + l] = pv + pb;
  }
}

__global__ __launch_bounds__(256)
void poolnorm_k(float* __restrict__ score)
{
  __shared__ float red[8];
  const int p = blockIdx.x;
  const int tid = threadIdx.x, wv = tid>>6, lane = tid&63;
  float* s = score + p*1024;
  float v[4];
  float m = -1e30f;
  #pragma unroll
  for (int j=0;j<4;++j){ v[j] = s[tid + j*256]; m = fmaxf(m, v[j]); }
  #pragma unroll
  for (int o=32;o;o>>=1) m = fmaxf(m, __shfl_xor(m,o));
  if (lane==0) red[wv] = m;
  __syncthreads();
  m = fmaxf(fmaxf(red[0],red[1]), fmaxf(red[2],red[3]));
  float ssum = 0.f;
  #pragma unroll
  for (int j=0;j<4;++j){ v[j] = __expf(v[j]-m); ssum += v[j]; }
  #pragma unroll
  for (int o=32;o;o>>=1) ssum += __shfl_xor(ssum,o);
  if (lane==0) red[4+wv] = ssum;
  __syncthreads();
  const float inv = 1.f/(red[4]+red[5]+red[6]+red[7]);
  #pragma unroll
  for (int j=0;j<4;++j) s[tid + j*256] = v[j]*inv;
}

__global__ __launch_bounds__(256)
void poolsum_k(const float* __restrict__ fin, const float* __restrict__ score,
               float* __restrict__ part)
{
  const int blk = blockIdx.x;                   // p = blk>>4, g = blk&15
  const int p = blk >> 4, g = blk & 15;
  const int d = threadIdx.x;
  const size_t fbase = (size_t)p*1024*256;
  float acc = 0.f;
  #pragma unroll 4
  for (int l = g*64; l < (g+1)*64; ++l)
    acc += score[p*1024 + l] * fin[fbase + (size_t)l*256 + d];
  part[((size_t)p*16 + g)*256 + d] = acc;
}

// head: 4 blocks (one per batch), vectorized weight loads
__global__ __launch_bounds__(256)
void head_k(const float* __restrict__ part, const float* __restrict__ llw,
            const float* __restrict__ llb, float* __restrict__ out)
{
  __shared__ float sp[2*256];
  const int d = threadIdx.x;
  const int b = blockIdx.x;                     // 0..3
  float a0 = 0.f, a1 = 0.f;
  #pragma unroll
  for (int g=0;g<16;++g){
    a0 += part[((size_t)b*16 + g)*256 + d];
    a1 += part[((size_t)(4+b)*16 + g)*256 + d];
  }
  sp[d] = a0; sp[256 + d] = a1;
  __syncthreads();
  const int o = d;
  const float* wr = llw + (size_t)o*512;
  f32x4 acc4 = (f32x4){0.f,0.f,0.f,0.f};
  #pragma unroll 8
  for (int k4=0;k4<64;++k4){
    acc4 += (*(const f32x4*)(sp + k4*4)) * (*(const f32x4*)(wr + k4*4));
  }
  #pragma unroll 8
  for (int k4=0;k4<64;++k4){
    acc4 += (*(const f32x4*)(sp + 256 + k4*4)) * (*(const f32x4*)(wr + 256 + k4*4));
  }
  out[b*256 + o] = llb[o] + acc4[0]+acc4[1]+acc4[2]+acc4[3];
}

// ---------------- host ----------------
extern "C" void kernel_launch(void* const* d_in, const int* in_sizes, int n_in,
                              void* d_out, int out_size, void* d_ws, size_t ws_size,
                              hipStream_t stream)
{
  const float* in_x    = (const float*)d_in[0];
  const float* in_inw  = (const float*)d_in[1];
  const float* in_cw   = (const float*)d_in[2];
  const float* in_cb   = (const float*)d_in[3];
  const float* in_xpw  = (const float*)d_in[4];
  const float* in_dtw  = (const float*)d_in[5];
  const float* in_dtb  = (const float*)d_in[6];
  const float* in_alog = (const float*)d_in[7];
  const float* in_dsk  = (const float*)d_in[8];
  const float* in_ow   = (const float*)d_in[9];
  const float* in_nw   = (const float*)d_in[10];
  const float* in_nb   = (const float*)d_in[11];
  const float* in_gw   = (const float*)d_in[12];
  const float* in_gb   = (const float*)d_in[13];
  const float* in_e1w  = (const float*)d_in[14];
  const float* in_e1b  = (const float*)d_in[15];
  const float* in_e2w  = (const float*)d_in[16];
  const float* in_e2b  = (const float*)d_in[17];
  const float* in_nfw  = (const float*)d_in[18];
  const float* in_nfb  = (const float*)d_in[19];
  const float* in_fpw  = (const float*)d_in[20];
  const float* in_fpb  = (const float*)d_in[21];
  const float* in_bpw  = (const float*)d_in[22];
  const float* in_bpb  = (const float*)d_in[23];
  const float* in_llw  = (const float*)d_in[24];
  const float* in_llb  = (const float*)d_in[25];

  uint8_t* ws = (uint8_t*)d_ws;
  size_t off = 0;
  auto take = [&](size_t bytes)->size_t{
    size_t o = off; off += (bytes + 255) & ~(size_t)255; return o;
  };
  float* f_xall = (float*)(ws + take((size_t)TOK*256*4));   // reused as f_fin
  float* f_res  = (float*)(ws + take((size_t)TOK*256*4));
  float* f_st   = (float*)(ws + take((size_t)TOK*256*4));
  float* f_xz   = (float*)(ws + take((size_t)TOK*1024*4));
  float* f_u    = (float*)(ws + take((size_t)TOK*DIN_*4));
  float* f_dt   = (float*)(ws + take((size_t)TOK*DIN_*4));
  float* f_xd   = (float*)(ws + take((size_t)TOK*48*4));
  float* f_hp   = (float*)(ws + take((size_t)4096*NCH*16*4));
  float* f_pp   = (float*)(ws + take((size_t)4096*NCH*16*4));
  float* f_gate = (float*)(ws + take((size_t)TOK*4*4));
  float* f_an   = (float*)(ws + take((size_t)2*NL*DIN_*16*4));
  float* f_score= (float*)(ws + take((size_t)8*1024*4));
  float* f_part = (float*)(ws + take((size_t)8*16*256*4));
  u16* b_hn   = (u16*)(ws + take((size_t)TOK*256*2));
  u16* b_ybar = (u16*)(ws + take((size_t)TOK*DIN_*2));
  u16* b_curr = (u16*)(ws + take((size_t)TOK*256*2));
  u16* b_h    = (u16*)(ws + take((size_t)TOK*4096*2));
  u16* b_win  = (u16*)(ws + take((size_t)2*NL*1024*256*2));
  u16* b_wout = (u16*)(ws + take((size_t)2*NL*256*512*2));
  u16* b_we1  = (u16*)(ws + take((size_t)2*NL*NE*HM*256*2));
  u16* b_we2  = (u16*)(ws + take((size_t)2*NL*NE*256*HM*2));
  float* f_fin  = f_xall;
  (void)ws_size; (void)in_sizes; (void)n_in; (void)out_size;

  // prep: weights -> bf16
  cvt_bf16_k<<<1024,256,0,stream>>>(in_inw, b_win, 2*NL*1024*256/4);
  cvt_bf16_k<<<1024,256,0,stream>>>(in_ow,  b_wout, 2*NL*256*512/4);
  cvt_bf16_k<<<2048,256,0,stream>>>(in_e1w, b_we1, 2*NL*NE*HM*256/4);
  cvt_bf16_k<<<2048,256,0,stream>>>(in_e2w, b_we2, 2*NL*NE*256*HM/4);
  aneg_k<<<256,256,0,stream>>>(in_alog, f_an, 2*NL*DIN_*16);
  xall_k<<<8192,256,0,stream>>>(in_x, f_xall);

  for (int i=0;i<NL;++i){
    lnres_k<0><<<2048,256,0,stream>>>(i==0 ? f_xall : f_res, i==0 ? nullptr : f_st,
                                      in_nw + i*256, in_nb + i*256, f_res, b_hn);
    gemm_k<0><<<dim3(32,8,2),256,0,stream>>>(b_hn, b_win + (size_t)i*1024*256,
                                             f_xz, nullptr, nullptr, nullptr, nullptr);
    convproj_k<<<512,256,0,stream>>>(f_xz, in_cw + i*DIN_*4, in_cb + i*DIN_,
                                     in_xpw + i*48*DIN_, in_dtw + i*DIN_*16, in_dtb + i*DIN_,
                                     f_u, f_dt, f_xd);
    scan_k<1><<<256,512,0,stream>>>(f_dt, f_u, f_xd, f_an + i*DIN_*16,
                                    nullptr, nullptr, f_hp, f_pp, nullptr);
    scanfix_k<<<16,256,0,stream>>>(f_hp, f_pp);
    scan_k<2><<<256,512,0,stream>>>(f_dt, f_u, f_xd, f_an + i*DIN_*16,
                                    f_xz, in_dsk + i*DIN_, f_hp, f_pp, b_ybar);
    gemm_k<1><<<dim3(32,4,2),256,0,stream>>>(b_ybar, b_wout + (size_t)i*256*512,
                                             f_st, nullptr, nullptr, nullptr, nullptr);
    currgate_k<<<2048,256,0,stream>>>(f_st, f_res, in_gw + i*NE*256, in_gb + i*NE,
                                      b_curr, f_gate);
    gemm_k<2><<<dim3(32,8,8),256,0,stream>>>(b_curr, b_we1 + (size_t)i*NE*HM*256,
                                             nullptr, b_h,
                                             in_e1b + i*NE*HM, f_gate, nullptr);
    gemm_k<3><<<dim3(32,4,2),256,0,stream>>>(b_h, b_we2 + (size_t)i*NE*256*HM,
                                             f_res, nullptr,
                                             nullptr, f_gate, in_e2b + i*NE*256);
  }

  lnres_k<1><<<2048,256,0,stream>>>(f_res, f_st, in_nfw, in_nfb, f_fin, nullptr);
  poolscore_k<<<64,256,0,stream>>>(f_fin, in_fpw, in_fpb, in_bpw, in_bpb, f_score);
  poolnorm_k<<<8,256,0,stream>>>(f_score);
  poolsum_k<<<128,256,0,stream>>>(f_fin, f_score, f_part);
  head_k<<<4,256,0,stream>>>(f_part, in_llw, in_llb, (float*)d_out);
}

// Round 11
// 1207.708 us; speedup vs baseline: 7.1264x; 1.0615x over previous
//
#include <hip/hip_runtime.h>
#include <cstdint>
#include <cstddef>

typedef __attribute__((ext_vector_type(4))) float f32x4;
typedef __attribute__((ext_vector_type(8))) short s16x8;
typedef __attribute__((ext_vector_type(4))) short s16x4;
using u16 = unsigned short;

constexpr int NL   = 4;
constexpr int DIN_ = 512;
constexpr int HM   = 1024;
constexpr int NE   = 4;
constexpr int TPD  = 4096;   // tokens per direction (B*L)
constexpr int TOK  = 8192;   // both directions
constexpr int NCH  = 32;     // scan chunks per sequence
constexpr int CLEN = 32;     // steps per chunk

__device__ __forceinline__ u16 f2b(float f){
  unsigned u = __builtin_bit_cast(unsigned, f);
  u += 0x7fffu + ((u >> 16) & 1u);
  return (u16)(u >> 16);
}
__device__ __forceinline__ float sigm(float x){ return 1.f/(1.f + __expf(-x)); }

// ---------------- prep kernels ----------------
__global__ void cvt_bf16_k(const float* __restrict__ s, u16* __restrict__ d, int n4){
  int i = blockIdx.x*blockDim.x + threadIdx.x;
  const int st = gridDim.x*blockDim.x;
  for (; i < n4; i += st){
    const f32x4 v = *(const f32x4*)(s + (size_t)i*4);
    s16x4 o;
    #pragma unroll
    for (int j=0;j<4;++j) o[j] = (short)f2b(v[j]);
    *(s16x4*)(d + (size_t)i*4) = o;
  }
}

__global__ void aneg_k(const float* __restrict__ a, float* __restrict__ o, int n){
  int i = blockIdx.x*256 + threadIdx.x;
  if (i < n) o[i] = -__expf(a[i]);
}

__global__ void xall_k(const float* __restrict__ x, float* __restrict__ o){
  const int i = blockIdx.x*256 + threadIdx.x;           // [0, 2*4*1024*256)
  const int d = i & 255, l = (i>>8)&1023, b2 = (i>>18)&3, dir = i>>20;
  const int ls = dir ? (1023 - l) : l;
  o[i] = x[((size_t)(b2<<10) + ls)*256 + d];
}

// ---------------- LN (+residual) ----------------
template<int MODE>
__global__ __launch_bounds__(256)
void lnres_k(const float* __restrict__ s1, const float* __restrict__ s2,
             const float* __restrict__ w, const float* __restrict__ b,
             float* __restrict__ fout, u16* __restrict__ hnout)
{
  const int wv = threadIdx.x >> 6, lane = threadIdx.x & 63;
  const int tok = blockIdx.x*4 + wv;
  const int dir = tok >> 12;
  const size_t base = (size_t)tok*256 + lane*4;
  f32x4 r = *(const f32x4*)(s1 + base);
  if (s2){ f32x4 c = *(const f32x4*)(s2 + base); r += c; }
  float sv = r[0]+r[1]+r[2]+r[3];
  float qv = r[0]*r[0]+r[1]*r[1]+r[2]*r[2]+r[3]*r[3];
  #pragma unroll
  for (int o=32;o;o>>=1){ sv += __shfl_xor(sv,o); qv += __shfl_xor(qv,o); }
  const float mu = sv*(1.f/256.f);
  const float var = qv*(1.f/256.f) - mu*mu;
  const float inv = rsqrtf(var + 1e-5f);
  const int woff = (MODE==0) ? dir*(NL*256) : 0;
  const f32x4 w4 = *(const f32x4*)(w + woff + lane*4);
  const f32x4 b4 = *(const f32x4*)(b + woff + lane*4);
  f32x4 y;
  #pragma unroll
  for (int j=0;j<4;++j) y[j] = (r[j]-mu)*inv*w4[j] + b4[j];
  if constexpr (MODE==0){
    *(f32x4*)(fout + base) = r;
    s16x4 hh;
    #pragma unroll
    for (int j=0;j<4;++j) hh[j] = (short)f2b(y[j]);
    *(s16x4*)(hnout + base) = hh;
  } else {
    *(f32x4*)(fout + base) = y;
  }
}

// ---------------- MFMA bf16 GEMM: C = A @ W^T ----------------
// LDS slot-swizzle: physical slot p of row m holds logical slot p ^ ((m>>2)&3);
// stage fetches inverse-permuted global slice, reads use q ^ ((r>>2)&3). -> 2-way (free).
// CFG 0: in_proj  N=1024 K=256  -> OF f32 (f_xz)
// CFG 1: out_proj N=256  K=512  -> OF f32 (f_st)
// CFG 2: moe h    z=dir*4+e, N=1024 K=256 -> OB bf16 = gate*gelu(acc+b1)
// CFG 3: moe o2   z=e*2+dir, per-expert K=1024 -> OF f32 partial[z]
template<int CFG>
__global__ __launch_bounds__(256, 2)
void gemm_k(const u16* __restrict__ A0, const u16* __restrict__ W0,
            float* OF, u16* OB,
            const float* __restrict__ P0, const float* __restrict__ P1,
            const float* __restrict__ P2)
{
  constexpr int BM = 128;
  constexpr int BN = (CFG==1 || CFG==3) ? 64 : 128;
  constexpr int KD = (CFG==0 || CFG==2) ? 256 : (CFG==1 ? 512 : 1024);
  constexpr int LDA = (CFG==3) ? 4096 : KD;
  constexpr int FM = 4;
  constexpr int FN = BN/32;
  constexpr int IA = 2;
  constexpr int IB = BN/64;

  __shared__ u16 sA[BM*32];
  __shared__ u16 sB[BN*32];

  const int tid = threadIdx.x;
  const int wave = tid >> 6, lane = tid & 63;
  const int bm0 = blockIdx.x * BM, bn0 = blockIdx.y * BN;
  const int z = blockIdx.z;
  const int wm0 = (wave >> 1) * 64;
  const int wn0 = (wave & 1) * (BN/2);

  const u16* Az; const u16* Wz;
  int koff = 0, eoff = 0;
  if constexpr (CFG==0){ Az = A0 + (size_t)z*TPD*256;  Wz = W0 + (size_t)z*(NL*1024*256); }
  else if constexpr (CFG==1){ Az = A0 + (size_t)z*TPD*512; Wz = W0 + (size_t)z*(NL*256*512); }
  else if constexpr (CFG==2){ Az = A0 + (size_t)(z>>2)*TPD*256;
                              Wz = W0 + (size_t)(z>>2)*((size_t)NL*NE*HM*256) + (size_t)(z&3)*(HM*256); }
  else { Az = A0 + (size_t)(z&1)*TPD*4096;
         Wz = W0 + (size_t)(z&1)*((size_t)NL*NE*256*HM);
         koff = (z>>1)*1024; eoff = (z>>1)*256; }

  f32x4 acc[FM][FN];
  #pragma unroll
  for (int i=0;i<FM;++i)
    #pragma unroll
    for (int j=0;j<FN;++j) acc[i][j] = (f32x4){0.f,0.f,0.f,0.f};

  const int r = lane & 15, q = lane >> 4;
  const int qs8 = (q ^ ((r>>2)&3))*8;     // swizzled 16B-slot for LDS reads

  for (int k0 = 0; k0 < KD; k0 += 32){
    #pragma unroll
    for (int j=0;j<IA;++j){
      const int c = (wave*IA + j)*64 + lane;
      const int m = c >> 2, kq = (c & 3) ^ ((m>>2)&3);
      const u16* g;
      if constexpr (CFG==3) g = Az + (size_t)(bm0 + m)*LDA + (koff + k0 + kq*8);
      else                  g = Az + (size_t)(bm0 + m)*LDA + (k0 + kq*8);
      __builtin_amdgcn_global_load_lds((const __attribute__((address_space(1))) void*)g,
          (__attribute__((address_space(3))) void*)(sA + (size_t)(wave*IA + j)*512), 16, 0, 0);
    }
    #pragma unroll
    for (int j=0;j<IB;++j){
      const int c = (wave*IB + j)*64 + lane;
      const int n = c >> 2, kq = (c & 3) ^ ((n>>2)&3);
      const u16* g;
      if constexpr (CFG==3){
        g = Wz + ((size_t)eoff + (bn0 + n))*1024 + (k0 + kq*8);
      } else {
        g = Wz + (size_t)(bn0 + n)*KD + (k0 + kq*8);
      }
      __builtin_amdgcn_global_load_lds((const __attribute__((address_space(1))) void*)g,
          (__attribute__((address_space(3))) void*)(sB + (size_t)(wave*IB + j)*512), 16, 0, 0);
    }
    __syncthreads();
    s16x8 av[FM], bv[FN];
    #pragma unroll
    for (int mi=0;mi<FM;++mi) av[mi] = *(const s16x8*)(sA + (wm0 + mi*16 + r)*32 + qs8);
    #pragma unroll
    for (int ni=0;ni<FN;++ni) bv[ni] = *(const s16x8*)(sB + (wn0 + ni*16 + r)*32 + qs8);
    #pragma unroll
    for (int mi=0;mi<FM;++mi)
      #pragma unroll
      for (int ni=0;ni<FN;++ni)
        acc[mi][ni] = __builtin_amdgcn_mfma_f32_16x16x32_bf16(av[mi], bv[ni], acc[mi][ni], 0, 0, 0);
    __syncthreads();
  }

  #pragma unroll
  for (int mi=0;mi<FM;++mi){
    #pragma unroll
    for (int ni=0;ni<FN;++ni){
      const int col = bn0 + wn0 + ni*16 + r;
      #pragma unroll
      for (int rr=0;rr<4;++rr){
        const int row = bm0 + wm0 + mi*16 + q*4 + rr;
        const float v = acc[mi][ni][rr];
        if constexpr (CFG==0){
          OF[((size_t)z*TPD + row)*1024 + col] = v;
        } else if constexpr (CFG==1){
          OF[((size_t)z*TPD + row)*256 + col] = v;
        } else if constexpr (CFG==2){
          const int dir = z>>2, e = z&3;
          const float xv = v + P0[(size_t)dir*(NL*NE*HM) + (size_t)e*HM + col];
          const float ge = 0.5f*xv*(1.f + erff(xv*0.70710678118654752f));
          const float gt = P1[((size_t)dir*TPD + row)*4 + e];
          OB[((size_t)dir*TPD + row)*4096 + (size_t)e*1024 + col] = f2b(ge*gt);
        } else {
          OF[((size_t)z*TPD + row)*256 + col] = v;   // partial[z=e*2+dir]
        }
      }
    }
  }
}

// ---------------- MoE partial reduce: res += sum_e partial_e + gate_e*b2_e ----------------
__global__ __launch_bounds__(256)
void moered_k(const float* __restrict__ part, const float* __restrict__ gate,
              const float* __restrict__ b2, float* __restrict__ res)
{
  const int i4 = blockIdx.x*256 + threadIdx.x;       // 0 .. TOK*64-1
  const int tok = i4 >> 6;
  const int c4 = i4 & 63;
  const int dir = tok >> 12, rr = tok & 4095;
  const float* gp = gate + (size_t)tok*4;
  const float* b2p = b2 + (size_t)dir*(NL*NE*256);
  f32x4 acc = *(f32x4*)(res + (size_t)tok*256 + c4*4);
  #pragma unroll
  for (int e=0;e<4;++e){
    const f32x4 pv = *(const f32x4*)(part + ((size_t)(e*2+dir)*TPD + rr)*256 + c4*4);
    const f32x4 bv = *(const f32x4*)(b2p + e*256 + c4*4);
    const float g = gp[e];
    acc += pv;
    acc += g*bv;
  }
  *(f32x4*)(res + (size_t)tok*256 + c4*4) = acc;
}

// ---------------- fused conv + silu + x_proj + dt_proj (16 tokens/block, f32x4) ----------------
__global__ __launch_bounds__(256)
void convproj_k(const float* __restrict__ xz,
                const float* __restrict__ cw, const float* __restrict__ cb,
                const float* __restrict__ xpw,
                const float* __restrict__ dtw, const float* __restrict__ dtb,
                float* __restrict__ uo, float* __restrict__ dto,
                float* __restrict__ xdo)
{
  __shared__ float sxs[19*516];
  __shared__ float sxd[16*48];
  const int tid = threadIdx.x;
  const int blk = blockIdx.x;                       // 512 blocks
  const int tc = blk & 63, bb = (blk>>6)&3, dir = blk>>8;
  const int t0 = tc*16;
  const size_t tokbase = (size_t)(dir*4+bb)*1024;

  for (int idx = tid; idx < 19*128; idx += 256){
    const int rr = idx >> 7, c4 = idx & 127;
    const int t = t0 - 3 + rr;
    f32x4 v = (f32x4){0.f,0.f,0.f,0.f};
    if (t >= 0) v = *(const f32x4*)(xz + (tokbase + t)*1024 + c4*4);
    *(f32x4*)(sxs + rr*516 + c4*4) = v;
  }
  __syncthreads();

  const float* cwp = cw + (size_t)dir*(NL*DIN_*4);
  const float* cbp = cb + (size_t)dir*(NL*DIN_);
  f32x4 ur[8];
  #pragma unroll
  for (int s=0;s<8;++s){
    const int o4 = tid + s*256;                     // 0..2047
    const int tk = o4 >> 7, c4 = o4 & 127;
    const f32x4 w0 = *(const f32x4*)(cwp + c4*16);
    const f32x4 w1 = *(const f32x4*)(cwp + c4*16 + 4);
    const f32x4 w2 = *(const f32x4*)(cwp + c4*16 + 8);
    const f32x4 w3 = *(const f32x4*)(cwp + c4*16 + 12);
    const f32x4 cb4 = *(const f32x4*)(cbp + c4*4);
    const f32x4 x0 = *(const f32x4*)(sxs + (tk+0)*516 + c4*4);
    const f32x4 x1 = *(const f32x4*)(sxs + (tk+1)*516 + c4*4);
    const f32x4 x2 = *(const f32x4*)(sxs + (tk+2)*516 + c4*4);
    const f32x4 x3 = *(const f32x4*)(sxs + (tk+3)*516 + c4*4);
    f32x4 a;
    a[0] = cb4[0] + x0[0]*w0[0] + x1[0]*w0[1] + x2[0]*w0[2] + x3[0]*w0[3];
    a[1] = cb4[1] + x0[1]*w1[0] + x1[1]*w1[1] + x2[1]*w1[2] + x3[1]*w1[3];
    a[2] = cb4[2] + x0[2]*w2[0] + x1[2]*w2[1] + x2[2]*w2[2] + x3[2]*w2[3];
    a[3] = cb4[3] + x0[3]*w3[0] + x1[3]*w3[1] + x2[3]*w3[2] + x3[3]*w3[3];
    f32x4 uv;
    #pragma unroll
    for (int j=0;j<4;++j) uv[j] = a[j]*sigm(a[j]);
    ur[s] = uv;
    *(f32x4*)(uo + (tokbase + t0 + tk)*DIN_ + c4*4) = uv;
  }
  __syncthreads();
  float* su = sxs;                                   // reuse as [16][516]
  #pragma unroll
  for (int s=0;s<8;++s){
    const int o4 = tid + s*256;
    const int tk = o4 >> 7, c4 = o4 & 127;
    *(f32x4*)(su + tk*516 + c4*4) = ur[s];
  }
  __syncthreads();

  const float* xpwp = xpw + (size_t)dir*(NL*48*DIN_);
  #pragma unroll
  for (int s=0;s<3;++s){
    const int o = tid + s*256;
    const int j = o >> 4, tk = o & 15;
    const float* wr = xpwp + (size_t)j*DIN_;
    const float* sur = su + tk*516;
    f32x4 acc4 = (f32x4){0.f,0.f,0.f,0.f};
    #pragma unroll 8
    for (int k4=0;k4<128;++k4){
      const f32x4 uv = *(const f32x4*)(sur + k4*4);
      const f32x4 wv = *(const f32x4*)(wr + k4*4);
      acc4 += uv*wv;
    }
    const float a = acc4[0]+acc4[1]+acc4[2]+acc4[3];
    sxd[tk*48 + j] = a;
    if (j >= 16) xdo[(tokbase + t0 + tk)*48 + j] = a;   // scan reads only 16..47
  }
  __syncthreads();

  const float* dtwp = dtw + (size_t)dir*(NL*DIN_*16);
  const float* dtbp = dtb + (size_t)dir*(NL*DIN_);
  #pragma unroll
  for (int s=0;s<32;++s){
    const int o = tid + s*256;
    const int tk = o >> 9, c = o & 511;
    const float* wr = dtwp + (size_t)c*16;
    const float* xr = sxd + tk*48;
    f32x4 acc4 = (f32x4){0.f,0.f,0.f,0.f};
    #pragma unroll
    for (int r4=0;r4<4;++r4){
      const f32x4 xv = *(const f32x4*)(xr + r4*4);
      const f32x4 wv = *(const f32x4*)(wr + r4*4);
      acc4 += xv*wv;
    }
    const float a = dtbp[c] + acc4[0]+acc4[1]+acc4[2]+acc4[3];
    dto[(tokbase + t0 + tk)*DIN_ + c] = (a > 20.f) ? a : log1pf(__expf(a));
  }
}

// ---------------- chunked selective scan (32 chunks x 32 steps) ----------------
template<int PASS>
__global__ __launch_bounds__(512)
void scan_k(const float* __restrict__ dt, const float* __restrict__ u,
            const float* __restrict__ xd, const float* __restrict__ an,
            const float* __restrict__ xz, const float* __restrict__ dsk,
            float* __restrict__ hp, float* __restrict__ pp,
            u16* __restrict__ ybar)
{
  const int ch = threadIdx.x;                         // 0..511
  const int blk = blockIdx.x;                         // (dir*4+b)*NCH + chunk
  const int chunk = blk & (NCH-1), bb = (blk>>5)&3, dir = blk>>7;
  const size_t tokbase = (size_t)(dir*4+bb)*1024 + (size_t)chunk*CLEN;
  const float* ap = an + (size_t)dir*(NL*DIN_*16) + (size_t)ch*16;
  float A_[16];
  #pragma unroll
  for (int n=0;n<16;++n) A_[n] = ap[n];
  const size_t scanid = (size_t)(dir*4+bb)*512 + ch;
  const size_t hbase = (scanid*NCH + chunk)*16;
  float h[16], P[16];
  if constexpr (PASS==1){
    #pragma unroll
    for (int n=0;n<16;++n){ h[n]=0.f; P[n]=1.f; }
  } else {
    #pragma unroll
    for (int n=0;n<16;++n) h[n] = hp[hbase+n];
  }
  float dval = 0.f;
  if constexpr (PASS==2) dval = dsk[(size_t)dir*(NL*DIN_) + ch];
  for (int t=0;t<CLEN;++t){
    const size_t tok = tokbase + t;
    const float dtv = dt[tok*DIN_ + ch];
    const float uv  = u[tok*DIN_ + ch];
    const float dtu = dtv*uv;
    const float* xr = xd + tok*48;
    float y = 0.f;
    #pragma unroll
    for (int n=0;n<16;++n){
      const float e = __expf(dtv*A_[n]);
      const float hn2 = h[n]*e + dtu*xr[16+n];
      h[n] = hn2;
      if constexpr (PASS==1) P[n] *= e;
      else y += hn2*xr[32+n];
    }
    if constexpr (PASS==2){
      const float zv = xz[tok*1024 + 512 + ch];
      ybar[tok*DIN_ + ch] = f2b((y + uv*dval) * (zv * sigm(zv)));
    }
  }
  if constexpr (PASS==1){
    #pragma unroll
    for (int n=0;n<16;++n){ hp[hbase+n] = h[n]; pp[hbase+n] = P[n]; }
  }
}

__global__ void scanfix_k(float* __restrict__ hp, const float* __restrict__ pp){
  const int id = blockIdx.x*256 + threadIdx.x;        // 0..4095
  float s[16];
  #pragma unroll
  for (int n=0;n<16;++n) s[n] = 0.f;
  for (int c=0;c<NCH;++c){
    const size_t base = ((size_t)id*NCH + c)*16;
    #pragma unroll
    for (int n=0;n<16;++n){
      const float hv = hp[base+n];
      const float pv = pp[base+n];
      hp[base+n] = s[n];
      s[n] = hv + pv*s[n];
    }
  }
}

// ---------------- curr = states + resid ; gating (f32) ----------------
__global__ __launch_bounds__(256)
void currgate_k(const float* __restrict__ st, const float* __restrict__ rs,
                const float* __restrict__ gw, const float* __restrict__ gb,
                u16* __restrict__ currb, float* __restrict__ gate)
{
  const int wv = threadIdx.x>>6, lane = threadIdx.x&63;
  const int tok = blockIdx.x*4 + wv;
  const int dir = tok>>12;
  const size_t base = (size_t)tok*256 + lane*4;
  f32x4 a = *(const f32x4*)(st+base);
  { f32x4 c = *(const f32x4*)(rs+base); a += c; }
  s16x4 cc;
  #pragma unroll
  for (int j=0;j<4;++j) cc[j] = (short)f2b(a[j]);
  *(s16x4*)(currb+base) = cc;
  const float* gwp = gw + (size_t)dir*(NL*NE*256);
  float lg[4];
  #pragma unroll
  for (int e=0;e<4;++e){
    const float* w4 = gwp + e*256 + lane*4;
    lg[e] = a[0]*w4[0] + a[1]*w4[1] + a[2]*w4[2] + a[3]*w4[3];
  }
  #pragma unroll
  for (int o=32;o;o>>=1){
    #pragma unroll
    for (int e=0;e<4;++e) lg[e] += __shfl_xor(lg[e], o);
  }
  if (lane==0){
    const float* gbp = gb + dir*(NL*NE);
    float sc[4]; float mx = -1e30f;
    #pragma unroll
    for (int e=0;e<4;++e){ sc[e] = lg[e] + gbp[e]; mx = fmaxf(mx, sc[e]); }
    float den = 0.f;
    #pragma unroll
    for (int e=0;e<4;++e){ sc[e] = __expf(sc[e]-mx); den += sc[e]; }
    const float rden = 1.f/den;
    #pragma unroll
    for (int e=0;e<4;++e) sc[e] *= rden;
    int i1 = 0;
    #pragma unroll
    for (int e=1;e<4;++e) if (sc[e] > sc[i1]) i1 = e;
    int i2 = (i1==0)?1:0;
    #pragma unroll
    for (int e=0;e<4;++e) if (e!=i1 && sc[e] > sc[i2]) i2 = e;
    const float ssum = sc[i1] + sc[i2] + 1e-6f;
    #pragma unroll
    for (int e=0;e<4;++e)
      gate[(size_t)tok*4+e] = (e==i1) ? sc[i1]/ssum : ((e==i2) ? sc[i2]/ssum : 0.f);
  }
}

// ---------------- pooling (parallel) ----------------
__global__ __launch_bounds__(256)
void poolscore_k(const float* __restrict__ fin, const float* __restrict__ fw,
                 const float* __restrict__ fb, const float* __restrict__ bw,
                 const float* __restrict__ bbs, float* __restrict__ score)
{
  const int blk = blockIdx.x;                   // p = blk>>3, g = blk&7
  const int p = blk >> 3, g = blk & 7;
  const int dir = p >> 2;
  const float* pw = dir ? bw : fw;
  const float pb = dir ? bbs[0] : fb[0];
  const int wv = threadIdx.x>>6, lane = threadIdx.x&63;
  const size_t fbase = (size_t)p*1024*256;
  const f32x4 w4 = *(const f32x4*)(pw + lane*4);
  for (int l = g*128 + wv; l < (g+1)*128; l += 4){
    const f32x4 f4 = *(const f32x4*)(fin + fbase + (size_t)l*256 + lane*4);
    float pv = f4[0]*w4[0] + f4[1]*w4[1] + f4[2]*w4[2] + f4[3]*w4[3];
    #pragma unroll
    for (int o=32;o;o>>=1) pv += __shfl_xor(pv,o);
    if (lane==0) score[p*1024 + l] = pv + pb;
  }
}

__global__ __launch_bounds__(256)
void poolnorm_k(float* __restrict__ score)
{
  __shared__ float red[8];
  const int p = blockIdx.x;
  const int tid = threadIdx.x, wv = tid>>6, lane = tid&63;
  float* s = score + p*1024;
  float v[4];
  float m = -1e30f;
  #pragma unroll
  for (int j=0;j<4;++j){ v[j] = s[tid + j*256]; m = fmaxf(m, v[j]); }
  #pragma unroll
  for (int o=32;o;o>>=1) m = fmaxf(m, __shfl_xor(m,o));
  if (lane==0) red[wv] = m;
  __syncthreads();
  m = fmaxf(fmaxf(red[0],red[1]), fmaxf(red[2],red[3]));
  float ssum = 0.f;
  #pragma unroll
  for (int j=0;j<4;++j){ v[j] = __expf(v[j]-m); ssum += v[j]; }
  #pragma unroll
  for (int o=32;o;o>>=1) ssum += __shfl_xor(ssum,o);
  if (lane==0) red[4+wv] = ssum;
  __syncthreads();
  const float inv = 1.f/(red[4]+red[5]+red[6]+red[7]);
  #pragma unroll
  for (int j=0;j<4;++j) s[tid + j*256] = v[j]*inv;
}

__global__ __launch_bounds__(256)
void poolsum_k(const float* __restrict__ fin, const float* __restrict__ score,
               float* __restrict__ part)
{
  const int blk = blockIdx.x;                   // p = blk>>4, g = blk&15
  const int p = blk >> 4, g = blk & 15;
  const int d = threadIdx.x;
  const size_t fbase = (size_t)p*1024*256;
  float acc = 0.f;
  #pragma unroll 4
  for (int l = g*64; l < (g+1)*64; ++l)
    acc += score[p*1024 + l] * fin[fbase + (size_t)l*256 + d];
  part[((size_t)p*16 + g)*256 + d] = acc;
}

// head: 4 blocks (one per batch), vectorized weight loads
__global__ __launch_bounds__(256)
void head_k(const float* __restrict__ part, const float* __restrict__ llw,
            const float* __restrict__ llb, float* __restrict__ out)
{
  __shared__ float sp[2*256];
  const int d = threadIdx.x;
  const int b = blockIdx.x;                     // 0..3
  float a0 = 0.f, a1 = 0.f;
  #pragma unroll
  for (int g=0;g<16;++g){
    a0 += part[((size_t)b*16 + g)*256 + d];
    a1 += part[((size_t)(4+b)*16 + g)*256 + d];
  }
  sp[d] = a0; sp[256 + d] = a1;
  __syncthreads();
  const int o = d;
  const float* wr = llw + (size_t)o*512;
  f32x4 acc4 = (f32x4){0.f,0.f,0.f,0.f};
  #pragma unroll 8
  for (int k4=0;k4<64;++k4){
    acc4 += (*(const f32x4*)(sp + k4*4)) * (*(const f32x4*)(wr + k4*4));
  }
  #pragma unroll 8
  for (int k4=0;k4<64;++k4){
    acc4 += (*(const f32x4*)(sp + 256 + k4*4)) * (*(const f32x4*)(wr + 256 + k4*4));
  }
  out[b*256 + o] = llb[o] + acc4[0]+acc4[1]+acc4[2]+acc4[3];
}

// ---------------- host ----------------
extern "C" void kernel_launch(void* const* d_in, const int* in_sizes, int n_in,
                              void* d_out, int out_size, void* d_ws, size_t ws_size,
                              hipStream_t stream)
{
  const float* in_x    = (const float*)d_in[0];
  const float* in_inw  = (const float*)d_in[1];
  const float* in_cw   = (const float*)d_in[2];
  const float* in_cb   = (const float*)d_in[3];
  const float* in_xpw  = (const float*)d_in[4];
  const float* in_dtw  = (const float*)d_in[5];
  const float* in_dtb  = (const float*)d_in[6];
  const float* in_alog = (const float*)d_in[7];
  const float* in_dsk  = (const float*)d_in[8];
  const float* in_ow   = (const float*)d_in[9];
  const float* in_nw   = (const float*)d_in[10];
  const float* in_nb   = (const float*)d_in[11];
  const float* in_gw   = (const float*)d_in[12];
  const float* in_gb   = (const float*)d_in[13];
  const float* in_e1w  = (const float*)d_in[14];
  const float* in_e1b  = (const float*)d_in[15];
  const float* in_e2w  = (const float*)d_in[16];
  const float* in_e2b  = (const float*)d_in[17];
  const float* in_nfw  = (const float*)d_in[18];
  const float* in_nfb  = (const float*)d_in[19];
  const float* in_fpw  = (const float*)d_in[20];
  const float* in_fpb  = (const float*)d_in[21];
  const float* in_bpw  = (const float*)d_in[22];
  const float* in_bpb  = (const float*)d_in[23];
  const float* in_llw  = (const float*)d_in[24];
  const float* in_llb  = (const float*)d_in[25];

  uint8_t* ws = (uint8_t*)d_ws;
  size_t off = 0;
  auto take = [&](size_t bytes)->size_t{
    size_t o = off; off += (bytes + 255) & ~(size_t)255; return o;
  };
  float* f_xall = (float*)(ws + take((size_t)TOK*256*4));   // reused as f_fin
  float* f_res  = (float*)(ws + take((size_t)TOK*256*4));
  float* f_st   = (float*)(ws + take((size_t)TOK*256*4));
  float* f_xz   = (float*)(ws + take((size_t)TOK*1024*4));  // aliased as MoE partials after scan<2>
  float* f_u    = (float*)(ws + take((size_t)TOK*DIN_*4));
  float* f_dt   = (float*)(ws + take((size_t)TOK*DIN_*4));
  float* f_xd   = (float*)(ws + take((size_t)TOK*48*4));
  float* f_hp   = (float*)(ws + take((size_t)4096*NCH*16*4));
  float* f_pp   = (float*)(ws + take((size_t)4096*NCH*16*4));
  float* f_gate = (float*)(ws + take((size_t)TOK*4*4));
  float* f_an   = (float*)(ws + take((size_t)2*NL*DIN_*16*4));
  float* f_score= (float*)(ws + take((size_t)8*1024*4));
  float* f_part = (float*)(ws + take((size_t)8*16*256*4));
  u16* b_hn   = (u16*)(ws + take((size_t)TOK*256*2));
  u16* b_ybar = (u16*)(ws + take((size_t)TOK*DIN_*2));
  u16* b_curr = (u16*)(ws + take((size_t)TOK*256*2));
  u16* b_h    = (u16*)(ws + take((size_t)TOK*4096*2));
  u16* b_win  = (u16*)(ws + take((size_t)2*NL*1024*256*2));
  u16* b_wout = (u16*)(ws + take((size_t)2*NL*256*512*2));
  u16* b_we1  = (u16*)(ws + take((size_t)2*NL*NE*HM*256*2));
  u16* b_we2  = (u16*)(ws + take((size_t)2*NL*NE*256*HM*2));
  float* f_fin  = f_xall;
  float* f_mp   = f_xz;       // MoE partials: [8][TPD][256] f32 = 32 MB (f_xz free then)
  (void)ws_size; (void)in_sizes; (void)n_in; (void)out_size;

  // prep: weights -> bf16
  cvt_bf16_k<<<1024,256,0,stream>>>(in_inw, b_win, 2*NL*1024*256/4);
  cvt_bf16_k<<<1024,256,0,stream>>>(in_ow,  b_wout, 2*NL*256*512/4);
  cvt_bf16_k<<<2048,256,0,stream>>>(in_e1w, b_we1, 2*NL*NE*HM*256/4);
  cvt_bf16_k<<<2048,256,0,stream>>>(in_e2w, b_we2, 2*NL*NE*256*HM/4);
  aneg_k<<<256,256,0,stream>>>(in_alog, f_an, 2*NL*DIN_*16);
  xall_k<<<8192,256,0,stream>>>(in_x, f_xall);

  for (int i=0;i<NL;++i){
    lnres_k<0><<<2048,256,0,stream>>>(i==0 ? f_xall : f_res, i==0 ? nullptr : f_st,
                                      in_nw + i*256, in_nb + i*256, f_res, b_hn);
    gemm_k<0><<<dim3(32,8,2),256,0,stream>>>(b_hn, b_win + (size_t)i*1024*256,
                                             f_xz, nullptr, nullptr, nullptr, nullptr);
    convproj_k<<<512,256,0,stream>>>(f_xz, in_cw + i*DIN_*4, in_cb + i*DIN_,
                                     in_xpw + i*48*DIN_, in_dtw + i*DIN_*16, in_dtb + i*DIN_,
                                     f_u, f_dt, f_xd);
    scan_k<1><<<256,512,0,stream>>>(f_dt, f_u, f_xd, f_an + i*DIN_*16,
                                    nullptr, nullptr, f_hp, f_pp, nullptr);
    scanfix_k<<<16,256,0,stream>>>(f_hp, f_pp);
    scan_k<2><<<256,512,0,stream>>>(f_dt, f_u, f_xd, f_an + i*DIN_*16,
                                    f_xz, in_dsk + i*DIN_, f_hp, f_pp, b_ybar);
    gemm_k<1><<<dim3(32,4,2),256,0,stream>>>(b_ybar, b_wout + (size_t)i*256*512,
                                             f_st, nullptr, nullptr, nullptr, nullptr);
    currgate_k<<<2048,256,0,stream>>>(f_st, f_res, in_gw + i*NE*256, in_gb + i*NE,
                                      b_curr, f_gate);
    gemm_k<2><<<dim3(32,8,8),256,0,stream>>>(b_curr, b_we1 + (size_t)i*NE*HM*256,
                                             nullptr, b_h,
                                             in_e1b + i*NE*HM, f_gate, nullptr);
    gemm_k<3><<<dim3(32,4,8),256,0,stream>>>(b_h, b_we2 + (size_t)i*NE*256*HM,
                                             f_mp, nullptr,
                                             nullptr, nullptr, nullptr);
    moered_k<<<2048,256,0,stream>>>(f_mp, f_gate, in_e2b + i*NE*256, f_res);
  }

  lnres_k<1><<<2048,256,0,stream>>>(f_res, f_st, in_nfw, in_nfb, f_fin, nullptr);
  poolscore_k<<<64,256,0,stream>>>(f_fin, in_fpw, in_fpb, in_bpw, in_bpb, f_score);
  poolnorm_k<<<8,256,0,stream>>>(f_score);
  poolsum_k<<<128,256,0,stream>>>(f_fin, f_score, f_part);
  head_k<<<4,256,0,stream>>>(f_part, in_llw, in_llb, (float*)d_out);
}

// Round 12
// 1017.300 us; speedup vs baseline: 8.4602x; 1.1872x over previous
//
#include <hip/hip_runtime.h>
#include <cstdint>
#include <cstddef>

typedef __attribute__((ext_vector_type(4))) float f32x4;
typedef __attribute__((ext_vector_type(8))) short s16x8;
typedef __attribute__((ext_vector_type(4))) short s16x4;
using u16 = unsigned short;

constexpr int NL   = 4;
constexpr int DIN_ = 512;
constexpr int HM   = 1024;
constexpr int NE   = 4;
constexpr int TPD  = 4096;   // tokens per direction (B*L)
constexpr int TOK  = 8192;   // both directions
constexpr int NCH  = 64;     // scan chunks per sequence
constexpr int CLEN = 16;     // steps per chunk

__device__ __forceinline__ u16 f2b(float f){
  unsigned u = __builtin_bit_cast(unsigned, f);
  u += 0x7fffu + ((u >> 16) & 1u);
  return (u16)(u >> 16);
}
__device__ __forceinline__ float sigm(float x){ return 1.f/(1.f + __expf(-x)); }

// ---------------- prep kernels ----------------
__global__ void cvt_bf16_k(const float* __restrict__ s, u16* __restrict__ d, int n4){
  int i = blockIdx.x*blockDim.x + threadIdx.x;
  const int st = gridDim.x*blockDim.x;
  for (; i < n4; i += st){
    const f32x4 v = *(const f32x4*)(s + (size_t)i*4);
    s16x4 o;
    #pragma unroll
    for (int j=0;j<4;++j) o[j] = (short)f2b(v[j]);
    *(s16x4*)(d + (size_t)i*4) = o;
  }
}

__global__ void aneg_k(const float* __restrict__ a, float* __restrict__ o, int n){
  int i = blockIdx.x*256 + threadIdx.x;
  if (i < n) o[i] = -__expf(a[i]);
}

__global__ void xall_k(const float* __restrict__ x, float* __restrict__ o){
  const int i = blockIdx.x*256 + threadIdx.x;           // [0, 2*4*1024*256)
  const int d = i & 255, l = (i>>8)&1023, b2 = (i>>18)&3, dir = i>>20;
  const int ls = dir ? (1023 - l) : l;
  o[i] = x[((size_t)(b2<<10) + ls)*256 + d];
}

// ---------------- LN (+residual) ----------------
template<int MODE>
__global__ __launch_bounds__(256)
void lnres_k(const float* __restrict__ s1, const float* __restrict__ s2,
             const float* __restrict__ w, const float* __restrict__ b,
             float* __restrict__ fout, u16* __restrict__ hnout)
{
  const int wv = threadIdx.x >> 6, lane = threadIdx.x & 63;
  const int tok = blockIdx.x*4 + wv;
  const int dir = tok >> 12;
  const size_t base = (size_t)tok*256 + lane*4;
  f32x4 r = *(const f32x4*)(s1 + base);
  if (s2){ f32x4 c = *(const f32x4*)(s2 + base); r += c; }
  float sv = r[0]+r[1]+r[2]+r[3];
  float qv = r[0]*r[0]+r[1]*r[1]+r[2]*r[2]+r[3]*r[3];
  #pragma unroll
  for (int o=32;o;o>>=1){ sv += __shfl_xor(sv,o); qv += __shfl_xor(qv,o); }
  const float mu = sv*(1.f/256.f);
  const float var = qv*(1.f/256.f) - mu*mu;
  const float inv = rsqrtf(var + 1e-5f);
  const int woff = (MODE==0) ? dir*(NL*256) : 0;
  const f32x4 w4 = *(const f32x4*)(w + woff + lane*4);
  const f32x4 b4 = *(const f32x4*)(b + woff + lane*4);
  f32x4 y;
  #pragma unroll
  for (int j=0;j<4;++j) y[j] = (r[j]-mu)*inv*w4[j] + b4[j];
  if constexpr (MODE==0){
    *(f32x4*)(fout + base) = r;
    s16x4 hh;
    #pragma unroll
    for (int j=0;j<4;++j) hh[j] = (short)f2b(y[j]);
    *(s16x4*)(hnout + base) = hh;
  } else {
    *(f32x4*)(fout + base) = y;
  }
}

// ---------------- MFMA bf16 GEMM: C = A @ W^T ----------------
// LDS slot-swizzle: physical slot p of row m holds logical slot p ^ ((m>>2)&3).
// CFG 0: in_proj  N=1024 K=256  -> OF f32 (f_xz)
// CFG 1: out_proj N=256  K=512  -> OF f32 (f_st)
// CFG 2: moe h    z=dir*4+e, N=1024 K=256 -> OB bf16 = gate*gelu(acc+b1)
// CFG 3: moe o2   z=e*2+dir, per-expert K=1024 -> OF f32 partial[z]
template<int CFG>
__global__ __launch_bounds__(256, 2)
void gemm_k(const u16* __restrict__ A0, const u16* __restrict__ W0,
            float* OF, u16* OB,
            const float* __restrict__ P0, const float* __restrict__ P1,
            const float* __restrict__ P2)
{
  constexpr int BM = 128;
  constexpr int BN = (CFG==1 || CFG==3) ? 64 : 128;
  constexpr int KD = (CFG==0 || CFG==2) ? 256 : (CFG==1 ? 512 : 1024);
  constexpr int LDA = (CFG==3) ? 4096 : KD;
  constexpr int FM = 4;
  constexpr int FN = BN/32;
  constexpr int IA = 2;
  constexpr int IB = BN/64;

  __shared__ u16 sA[BM*32];
  __shared__ u16 sB[BN*32];

  const int tid = threadIdx.x;
  const int wave = tid >> 6, lane = tid & 63;
  const int bm0 = blockIdx.x * BM, bn0 = blockIdx.y * BN;
  const int z = blockIdx.z;
  const int wm0 = (wave >> 1) * 64;
  const int wn0 = (wave & 1) * (BN/2);

  const u16* Az; const u16* Wz;
  int koff = 0, eoff = 0;
  if constexpr (CFG==0){ Az = A0 + (size_t)z*TPD*256;  Wz = W0 + (size_t)z*(NL*1024*256); }
  else if constexpr (CFG==1){ Az = A0 + (size_t)z*TPD*512; Wz = W0 + (size_t)z*(NL*256*512); }
  else if constexpr (CFG==2){ Az = A0 + (size_t)(z>>2)*TPD*256;
                              Wz = W0 + (size_t)(z>>2)*((size_t)NL*NE*HM*256) + (size_t)(z&3)*(HM*256); }
  else { Az = A0 + (size_t)(z&1)*TPD*4096;
         Wz = W0 + (size_t)(z&1)*((size_t)NL*NE*256*HM);
         koff = (z>>1)*1024; eoff = (z>>1)*256; }

  f32x4 acc[FM][FN];
  #pragma unroll
  for (int i=0;i<FM;++i)
    #pragma unroll
    for (int j=0;j<FN;++j) acc[i][j] = (f32x4){0.f,0.f,0.f,0.f};

  const int r = lane & 15, q = lane >> 4;
  const int qs8 = (q ^ ((r>>2)&3))*8;     // swizzled 16B-slot for LDS reads

  for (int k0 = 0; k0 < KD; k0 += 32){
    #pragma unroll
    for (int j=0;j<IA;++j){
      const int c = (wave*IA + j)*64 + lane;
      const int m = c >> 2, kq = (c & 3) ^ ((m>>2)&3);
      const u16* g;
      if constexpr (CFG==3) g = Az + (size_t)(bm0 + m)*LDA + (koff + k0 + kq*8);
      else                  g = Az + (size_t)(bm0 + m)*LDA + (k0 + kq*8);
      __builtin_amdgcn_global_load_lds((const __attribute__((address_space(1))) void*)g,
          (__attribute__((address_space(3))) void*)(sA + (size_t)(wave*IA + j)*512), 16, 0, 0);
    }
    #pragma unroll
    for (int j=0;j<IB;++j){
      const int c = (wave*IB + j)*64 + lane;
      const int n = c >> 2, kq = (c & 3) ^ ((n>>2)&3);
      const u16* g;
      if constexpr (CFG==3){
        g = Wz + ((size_t)eoff + (bn0 + n))*1024 + (k0 + kq*8);
      } else {
        g = Wz + (size_t)(bn0 + n)*KD + (k0 + kq*8);
      }
      __builtin_amdgcn_global_load_lds((const __attribute__((address_space(1))) void*)g,
          (__attribute__((address_space(3))) void*)(sB + (size_t)(wave*IB + j)*512), 16, 0, 0);
    }
    __syncthreads();
    s16x8 av[FM], bv[FN];
    #pragma unroll
    for (int mi=0;mi<FM;++mi) av[mi] = *(const s16x8*)(sA + (wm0 + mi*16 + r)*32 + qs8);
    #pragma unroll
    for (int ni=0;ni<FN;++ni) bv[ni] = *(const s16x8*)(sB + (wn0 + ni*16 + r)*32 + qs8);
    #pragma unroll
    for (int mi=0;mi<FM;++mi)
      #pragma unroll
      for (int ni=0;ni<FN;++ni)
        acc[mi][ni] = __builtin_amdgcn_mfma_f32_16x16x32_bf16(av[mi], bv[ni], acc[mi][ni], 0, 0, 0);
    __syncthreads();
  }

  #pragma unroll
  for (int mi=0;mi<FM;++mi){
    #pragma unroll
    for (int ni=0;ni<FN;++ni){
      const int col = bn0 + wn0 + ni*16 + r;
      #pragma unroll
      for (int rr=0;rr<4;++rr){
        const int row = bm0 + wm0 + mi*16 + q*4 + rr;
        const float v = acc[mi][ni][rr];
        if constexpr (CFG==0){
          OF[((size_t)z*TPD + row)*1024 + col] = v;
        } else if constexpr (CFG==1){
          OF[((size_t)z*TPD + row)*256 + col] = v;
        } else if constexpr (CFG==2){
          const int dir = z>>2, e = z&3;
          const float xv = v + P0[(size_t)dir*(NL*NE*HM) + (size_t)e*HM + col];
          const float ge = 0.5f*xv*(1.f + erff(xv*0.70710678118654752f));
          const float gt = P1[((size_t)dir*TPD + row)*4 + e];
          OB[((size_t)dir*TPD + row)*4096 + (size_t)e*1024 + col] = f2b(ge*gt);
        } else {
          OF[((size_t)z*TPD + row)*256 + col] = v;   // partial[z=e*2+dir]
        }
      }
    }
  }
}

// ---------------- MoE partial reduce: res += sum_e partial_e + gate_e*b2_e ----------------
__global__ __launch_bounds__(256)
void moered_k(const float* __restrict__ part, const float* __restrict__ gate,
              const float* __restrict__ b2, float* __restrict__ res)
{
  const int i4 = blockIdx.x*256 + threadIdx.x;       // 0 .. TOK*64-1
  const int tok = i4 >> 6;
  const int c4 = i4 & 63;
  const int dir = tok >> 12, rr = tok & 4095;
  const float* gp = gate + (size_t)tok*4;
  const float* b2p = b2 + (size_t)dir*(NL*NE*256);
  f32x4 acc = *(f32x4*)(res + (size_t)tok*256 + c4*4);
  #pragma unroll
  for (int e=0;e<4;++e){
    const f32x4 pv = *(const f32x4*)(part + ((size_t)(e*2+dir)*TPD + rr)*256 + c4*4);
    const f32x4 bv = *(const f32x4*)(b2p + e*256 + c4*4);
    const float g = gp[e];
    acc += pv;
    acc += g*bv;
  }
  *(f32x4*)(res + (size_t)tok*256 + c4*4) = acc;
}

// ---------------- fused conv + silu + x_proj + dt_proj (8 tokens/block, f32x4) ----------------
__global__ __launch_bounds__(256)
void convproj_k(const float* __restrict__ xz,
                const float* __restrict__ cw, const float* __restrict__ cb,
                const float* __restrict__ xpw,
                const float* __restrict__ dtw, const float* __restrict__ dtb,
                float* __restrict__ uo, float* __restrict__ dto,
                float* __restrict__ xdo)
{
  __shared__ float sxs[11*516];
  __shared__ float sxd[8*48];
  const int tid = threadIdx.x;
  const int blk = blockIdx.x;                       // 1024 blocks
  const int tc = blk & 127, bb = (blk>>7)&3, dir = blk>>9;
  const int t0 = tc*8;
  const size_t tokbase = (size_t)(dir*4+bb)*1024;

  for (int idx = tid; idx < 11*128; idx += 256){
    const int rr = idx >> 7, c4 = idx & 127;
    const int t = t0 - 3 + rr;
    f32x4 v = (f32x4){0.f,0.f,0.f,0.f};
    if (t >= 0) v = *(const f32x4*)(xz + (tokbase + t)*1024 + c4*4);
    *(f32x4*)(sxs + rr*516 + c4*4) = v;
  }
  __syncthreads();

  const float* cwp = cw + (size_t)dir*(NL*DIN_*4);
  const float* cbp = cb + (size_t)dir*(NL*DIN_);
  f32x4 ur[4];
  #pragma unroll
  for (int s=0;s<4;++s){
    const int o4 = tid + s*256;                     // 0..1023
    const int tk = o4 >> 7, c4 = o4 & 127;
    const f32x4 w0 = *(const f32x4*)(cwp + c4*16);
    const f32x4 w1 = *(const f32x4*)(cwp + c4*16 + 4);
    const f32x4 w2 = *(const f32x4*)(cwp + c4*16 + 8);
    const f32x4 w3 = *(const f32x4*)(cwp + c4*16 + 12);
    const f32x4 cb4 = *(const f32x4*)(cbp + c4*4);
    const f32x4 x0 = *(const f32x4*)(sxs + (tk+0)*516 + c4*4);
    const f32x4 x1 = *(const f32x4*)(sxs + (tk+1)*516 + c4*4);
    const f32x4 x2 = *(const f32x4*)(sxs + (tk+2)*516 + c4*4);
    const f32x4 x3 = *(const f32x4*)(sxs + (tk+3)*516 + c4*4);
    f32x4 a;
    a[0] = cb4[0] + x0[0]*w0[0] + x1[0]*w0[1] + x2[0]*w0[2] + x3[0]*w0[3];
    a[1] = cb4[1] + x0[1]*w1[0] + x1[1]*w1[1] + x2[1]*w1[2] + x3[1]*w1[3];
    a[2] = cb4[2] + x0[2]*w2[0] + x1[2]*w2[1] + x2[2]*w2[2] + x3[2]*w2[3];
    a[3] = cb4[3] + x0[3]*w3[0] + x1[3]*w3[1] + x2[3]*w3[2] + x3[3]*w3[3];
    f32x4 uv;
    #pragma unroll
    for (int j=0;j<4;++j) uv[j] = a[j]*sigm(a[j]);
    ur[s] = uv;
    *(f32x4*)(uo + (tokbase + t0 + tk)*DIN_ + c4*4) = uv;
  }
  __syncthreads();
  float* su = sxs;                                   // reuse as [8][516]
  #pragma unroll
  for (int s=0;s<4;++s){
    const int o4 = tid + s*256;
    const int tk = o4 >> 7, c4 = o4 & 127;
    *(f32x4*)(su + tk*516 + c4*4) = ur[s];
  }
  __syncthreads();

  // x_proj: 384 outputs (48 j x 8 tk); 4 independent accumulator chains
  const float* xpwp = xpw + (size_t)dir*(NL*48*DIN_);
  #pragma unroll
  for (int s=0;s<2;++s){
    const int o = tid + s*256;
    if (o < 384){
      const int j = o >> 3, tk = o & 7;
      const float* wr = xpwp + (size_t)j*DIN_;
      const float* sur = su + tk*516;
      f32x4 a0 = (f32x4){0.f,0.f,0.f,0.f};
      f32x4 a1 = (f32x4){0.f,0.f,0.f,0.f};
      f32x4 a2 = (f32x4){0.f,0.f,0.f,0.f};
      f32x4 a3 = (f32x4){0.f,0.f,0.f,0.f};
      #pragma unroll 8
      for (int k4=0;k4<32;++k4){
        a0 += (*(const f32x4*)(sur + k4*4))       * (*(const f32x4*)(wr + k4*4));
        a1 += (*(const f32x4*)(sur + 128 + k4*4)) * (*(const f32x4*)(wr + 128 + k4*4));
        a2 += (*(const f32x4*)(sur + 256 + k4*4)) * (*(const f32x4*)(wr + 256 + k4*4));
        a3 += (*(const f32x4*)(sur + 384 + k4*4)) * (*(const f32x4*)(wr + 384 + k4*4));
      }
      const f32x4 at = (a0+a1) + (a2+a3);
      const float a = at[0]+at[1]+at[2]+at[3];
      sxd[tk*48 + j] = a;
      if (j >= 16) xdo[(tokbase + t0 + tk)*48 + j] = a;   // scan reads only 16..47
    }
  }
  __syncthreads();

  const float* dtwp = dtw + (size_t)dir*(NL*DIN_*16);
  const float* dtbp = dtb + (size_t)dir*(NL*DIN_);
  #pragma unroll
  for (int s=0;s<16;++s){
    const int o = tid + s*256;
    const int tk = o >> 9, c = o & 511;
    const float* wr = dtwp + (size_t)c*16;
    const float* xr = sxd + tk*48;
    f32x4 acc4 = (f32x4){0.f,0.f,0.f,0.f};
    #pragma unroll
    for (int r4=0;r4<4;++r4){
      const f32x4 xv = *(const f32x4*)(xr + r4*4);
      const f32x4 wv = *(const f32x4*)(wr + r4*4);
      acc4 += xv*wv;
    }
    const float a = dtbp[c] + acc4[0]+acc4[1]+acc4[2]+acc4[3];
    dto[(tokbase + t0 + tk)*DIN_ + c] = (a > 20.f) ? a : log1pf(__expf(a));
  }
}

// ---------------- chunked selective scan (64 chunks x 16 steps) ----------------
template<int PASS>
__global__ __launch_bounds__(512)
void scan_k(const float* __restrict__ dt, const float* __restrict__ u,
            const float* __restrict__ xd, const float* __restrict__ an,
            const float* __restrict__ xz, const float* __restrict__ dsk,
            float* __restrict__ hp, float* __restrict__ pp,
            u16* __restrict__ ybar)
{
  const int ch = threadIdx.x;                         // 0..511
  const int blk = blockIdx.x;                         // (dir*4+b)*NCH + chunk
  const int chunk = blk & (NCH-1), bb = (blk>>6)&3, dir = blk>>8;
  const size_t tokbase = (size_t)(dir*4+bb)*1024 + (size_t)chunk*CLEN;
  const float* ap = an + (size_t)dir*(NL*DIN_*16) + (size_t)ch*16;
  float A_[16];
  #pragma unroll
  for (int n=0;n<16;++n) A_[n] = ap[n];
  const size_t scanid = (size_t)(dir*4+bb)*512 + ch;
  const size_t hbase = (scanid*NCH + chunk)*16;
  float h[16], P[16];
  if constexpr (PASS==1){
    #pragma unroll
    for (int n=0;n<16;++n){ h[n]=0.f; P[n]=1.f; }
  } else {
    #pragma unroll
    for (int n=0;n<16;++n) h[n] = hp[hbase+n];
  }
  float dval = 0.f;
  if constexpr (PASS==2) dval = dsk[(size_t)dir*(NL*DIN_) + ch];
  for (int t=0;t<CLEN;++t){
    const size_t tok = tokbase + t;
    const float dtv = dt[tok*DIN_ + ch];
    const float uv  = u[tok*DIN_ + ch];
    const float dtu = dtv*uv;
    const float* xr = xd + tok*48;
    float y = 0.f;
    #pragma unroll
    for (int n=0;n<16;++n){
      const float e = __expf(dtv*A_[n]);
      const float hn2 = h[n]*e + dtu*xr[16+n];
      h[n] = hn2;
      if constexpr (PASS==1) P[n] *= e;
      else y += hn2*xr[32+n];
    }
    if constexpr (PASS==2){
      const float zv = xz[tok*1024 + 512 + ch];
      ybar[tok*DIN_ + ch] = f2b((y + uv*dval) * (zv * sigm(zv)));
    }
  }
  if constexpr (PASS==1){
    #pragma unroll
    for (int n=0;n<16;++n){ hp[hbase+n] = h[n]; pp[hbase+n] = P[n]; }
  }
}

// parallel fixup over (scan-id, state): 65536 threads, n-major coalescing
__global__ __launch_bounds__(256)
void scanfix_k(float* __restrict__ hp, const float* __restrict__ pp){
  const int id2 = blockIdx.x*256 + threadIdx.x;       // 0..65535
  const int id = id2 >> 4, n = id2 & 15;
  float s = 0.f;
  for (int c=0;c<NCH;++c){
    const size_t base = ((size_t)id*NCH + c)*16 + n;
    const float hv = hp[base];
    const float pv = pp[base];
    hp[base] = s;
    s = hv + pv*s;
  }
}

// ---------------- curr = states + resid ; gating (f32) ----------------
__global__ __launch_bounds__(256)
void currgate_k(const float* __restrict__ st, const float* __restrict__ rs,
                const float* __restrict__ gw, const float* __restrict__ gb,
                u16* __restrict__ currb, float* __restrict__ gate)
{
  const int wv = threadIdx.x>>6, lane = threadIdx.x&63;
  const int tok = blockIdx.x*4 + wv;
  const int dir = tok>>12;
  const size_t base = (size_t)tok*256 + lane*4;
  f32x4 a = *(const f32x4*)(st+base);
  { f32x4 c = *(const f32x4*)(rs+base); a += c; }
  s16x4 cc;
  #pragma unroll
  for (int j=0;j<4;++j) cc[j] = (short)f2b(a[j]);
  *(s16x4*)(currb+base) = cc;
  const float* gwp = gw + (size_t)dir*(NL*NE*256);
  float lg[4];
  #pragma unroll
  for (int e=0;e<4;++e){
    const float* w4 = gwp + e*256 + lane*4;
    lg[e] = a[0]*w4[0] + a[1]*w4[1] + a[2]*w4[2] + a[3]*w4[3];
  }
  #pragma unroll
  for (int o=32;o;o>>=1){
    #pragma unroll
    for (int e=0;e<4;++e) lg[e] += __shfl_xor(lg[e], o);
  }
  if (lane==0){
    const float* gbp = gb + dir*(NL*NE);
    float sc[4]; float mx = -1e30f;
    #pragma unroll
    for (int e=0;e<4;++e){ sc[e] = lg[e] + gbp[e]; mx = fmaxf(mx, sc[e]); }
    float den = 0.f;
    #pragma unroll
    for (int e=0;e<4;++e){ sc[e] = __expf(sc[e]-mx); den += sc[e]; }
    const float rden = 1.f/den;
    #pragma unroll
    for (int e=0;e<4;++e) sc[e] *= rden;
    int i1 = 0;
    #pragma unroll
    for (int e=1;e<4;++e) if (sc[e] > sc[i1]) i1 = e;
    int i2 = (i1==0)?1:0;
    #pragma unroll
    for (int e=0;e<4;++e) if (e!=i1 && sc[e] > sc[i2]) i2 = e;
    const float ssum = sc[i1] + sc[i2] + 1e-6f;
    #pragma unroll
    for (int e=0;e<4;++e)
      gate[(size_t)tok*4+e] = (e==i1) ? sc[i1]/ssum : ((e==i2) ? sc[i2]/ssum : 0.f);
  }
}

// ---------------- pooling (parallel) ----------------
__global__ __launch_bounds__(256)
void poolscore_k(const float* __restrict__ fin, const float* __restrict__ fw,
                 const float* __restrict__ fb, const float* __restrict__ bw,
                 const float* __restrict__ bbs, float* __restrict__ score)
{
  const int blk = blockIdx.x;                   // p = blk>>3, g = blk&7
  const int p = blk >> 3, g = blk & 7;
  const int dir = p >> 2;
  const float* pw = dir ? bw : fw;
  const float pb = dir ? bbs[0] : fb[0];
  const int wv = threadIdx.x>>6, lane = threadIdx.x&63;
  const size_t fbase = (size_t)p*1024*256;
  const f32x4 w4 = *(const f32x4*)(pw + lane*4);
  for (int l = g*128 + wv; l < (g+1)*128; l += 4){
    const f32x4 f4 = *(const f32x4*)(fin + fbase + (size_t)l*256 + lane*4);
    float pv = f4[0]*w4[0] + f4[1]*w4[1] + f4[2]*w4[2] + f4[3]*w4[3];
    #pragma unroll
    for (int o=32;o;o>>=1) pv += __shfl_xor(pv,o);
    if (lane==0) score[p*1024 + l] = pv + pb;
  }
}

__global__ __launch_bounds__(256)
void poolnorm_k(float* __restrict__ score)
{
  __shared__ float red[8];
  const int p = blockIdx.x;
  const int tid = threadIdx.x, wv = tid>>6, lane = tid&63;
  float* s = score + p*1024;
  float v[4];
  float m = -1e30f;
  #pragma unroll
  for (int j=0;j<4;++j){ v[j] = s[tid + j*256]; m = fmaxf(m, v[j]); }
  #pragma unroll
  for (int o=32;o;o>>=1) m = fmaxf(m, __shfl_xor(m,o));
  if (lane==0) red[wv] = m;
  __syncthreads();
  m = fmaxf(fmaxf(red[0],red[1]), fmaxf(red[2],red[3]));
  float ssum = 0.f;
  #pragma unroll
  for (int j=0;j<4;++j){ v[j] = __expf(v[j]-m); ssum += v[j]; }
  #pragma unroll
  for (int o=32;o;o>>=1) ssum += __shfl_xor(ssum,o);
  if (lane==0) red[4+wv] = ssum;
  __syncthreads();
  const float inv = 1.f/(red[4]+red[5]+red[6]+red[7]);
  #pragma unroll
  for (int j=0;j<4;++j) s[tid + j*256] = v[j]*inv;
}

__global__ __launch_bounds__(256)
void poolsum_k(const float* __restrict__ fin, const float* __restrict__ score,
               float* __restrict__ part)
{
  const int blk = blockIdx.x;                   // p = blk>>4, g = blk&15
  const int p = blk >> 4, g = blk & 15;
  const int d = threadIdx.x;
  const size_t fbase = (size_t)p*1024*256;
  float acc = 0.f;
  #pragma unroll 4
  for (int l = g*64; l < (g+1)*64; ++l)
    acc += score[p*1024 + l] * fin[fbase + (size_t)l*256 + d];
  part[((size_t)p*16 + g)*256 + d] = acc;
}

// head: 4 blocks (one per batch), vectorized weight loads
__global__ __launch_bounds__(256)
void head_k(const float* __restrict__ part, const float* __restrict__ llw,
            const float* __restrict__ llb, float* __restrict__ out)
{
  __shared__ float sp[2*256];
  const int d = threadIdx.x;
  const int b = blockIdx.x;                     // 0..3
  float a0 = 0.f, a1 = 0.f;
  #pragma unroll
  for (int g=0;g<16;++g){
    a0 += part[((size_t)b*16 + g)*256 + d];
    a1 += part[((size_t)(4+b)*16 + g)*256 + d];
  }
  sp[d] = a0; sp[256 + d] = a1;
  __syncthreads();
  const int o = d;
  const float* wr = llw + (size_t)o*512;
  f32x4 acc4 = (f32x4){0.f,0.f,0.f,0.f};
  #pragma unroll 8
  for (int k4=0;k4<64;++k4){
    acc4 += (*(const f32x4*)(sp + k4*4)) * (*(const f32x4*)(wr + k4*4));
  }
  #pragma unroll 8
  for (int k4=0;k4<64;++k4){
    acc4 += (*(const f32x4*)(sp + 256 + k4*4)) * (*(const f32x4*)(wr + 256 + k4*4));
  }
  out[b*256 + o] = llb[o] + acc4[0]+acc4[1]+acc4[2]+acc4[3];
}

// ---------------- host ----------------
extern "C" void kernel_launch(void* const* d_in, const int* in_sizes, int n_in,
                              void* d_out, int out_size, void* d_ws, size_t ws_size,
                              hipStream_t stream)
{
  const float* in_x    = (const float*)d_in[0];
  const float* in_inw  = (const float*)d_in[1];
  const float* in_cw   = (const float*)d_in[2];
  const float* in_cb   = (const float*)d_in[3];
  const float* in_xpw  = (const float*)d_in[4];
  const float* in_dtw  = (const float*)d_in[5];
  const float* in_dtb  = (const float*)d_in[6];
  const float* in_alog = (const float*)d_in[7];
  const float* in_dsk  = (const float*)d_in[8];
  const float* in_ow   = (const float*)d_in[9];
  const float* in_nw   = (const float*)d_in[10];
  const float* in_nb   = (const float*)d_in[11];
  const float* in_gw   = (const float*)d_in[12];
  const float* in_gb   = (const float*)d_in[13];
  const float* in_e1w  = (const float*)d_in[14];
  const float* in_e1b  = (const float*)d_in[15];
  const float* in_e2w  = (const float*)d_in[16];
  const float* in_e2b  = (const float*)d_in[17];
  const float* in_nfw  = (const float*)d_in[18];
  const float* in_nfb  = (const float*)d_in[19];
  const float* in_fpw  = (const float*)d_in[20];
  const float* in_fpb  = (const float*)d_in[21];
  const float* in_bpw  = (const float*)d_in[22];
  const float* in_bpb  = (const float*)d_in[23];
  const float* in_llw  = (const float*)d_in[24];
  const float* in_llb  = (const float*)d_in[25];

  uint8_t* ws = (uint8_t*)d_ws;
  size_t off = 0;
  auto take = [&](size_t bytes)->size_t{
    size_t o = off; off += (bytes + 255) & ~(size_t)255; return o;
  };
  float* f_xall = (float*)(ws + take((size_t)TOK*256*4));   // reused as f_fin
  float* f_res  = (float*)(ws + take((size_t)TOK*256*4));
  float* f_st   = (float*)(ws + take((size_t)TOK*256*4));
  float* f_xz   = (float*)(ws + take((size_t)TOK*1024*4));  // aliased as MoE partials after scan<2>
  float* f_u    = (float*)(ws + take((size_t)TOK*DIN_*4));
  float* f_dt   = (float*)(ws + take((size_t)TOK*DIN_*4));
  float* f_xd   = (float*)(ws + take((size_t)TOK*48*4));
  float* f_hp   = (float*)(ws + take((size_t)4096*NCH*16*4));
  float* f_pp   = (float*)(ws + take((size_t)4096*NCH*16*4));
  float* f_gate = (float*)(ws + take((size_t)TOK*4*4));
  float* f_an   = (float*)(ws + take((size_t)2*NL*DIN_*16*4));
  float* f_score= (float*)(ws + take((size_t)8*1024*4));
  float* f_part = (float*)(ws + take((size_t)8*16*256*4));
  u16* b_hn   = (u16*)(ws + take((size_t)TOK*256*2));
  u16* b_ybar = (u16*)(ws + take((size_t)TOK*DIN_*2));
  u16* b_curr = (u16*)(ws + take((size_t)TOK*256*2));
  u16* b_h    = (u16*)(ws + take((size_t)TOK*4096*2));
  u16* b_win  = (u16*)(ws + take((size_t)2*NL*1024*256*2));
  u16* b_wout = (u16*)(ws + take((size_t)2*NL*256*512*2));
  u16* b_we1  = (u16*)(ws + take((size_t)2*NL*NE*HM*256*2));
  u16* b_we2  = (u16*)(ws + take((size_t)2*NL*NE*256*HM*2));
  float* f_fin  = f_xall;
  float* f_mp   = f_xz;       // MoE partials: [8][TPD][256] f32 = 32 MB (f_xz free then)
  (void)ws_size; (void)in_sizes; (void)n_in; (void)out_size;

  // prep: weights -> bf16
  cvt_bf16_k<<<1024,256,0,stream>>>(in_inw, b_win, 2*NL*1024*256/4);
  cvt_bf16_k<<<1024,256,0,stream>>>(in_ow,  b_wout, 2*NL*256*512/4);
  cvt_bf16_k<<<2048,256,0,stream>>>(in_e1w, b_we1, 2*NL*NE*HM*256/4);
  cvt_bf16_k<<<2048,256,0,stream>>>(in_e2w, b_we2, 2*NL*NE*256*HM/4);
  aneg_k<<<256,256,0,stream>>>(in_alog, f_an, 2*NL*DIN_*16);
  xall_k<<<8192,256,0,stream>>>(in_x, f_xall);

  for (int i=0;i<NL;++i){
    lnres_k<0><<<2048,256,0,stream>>>(i==0 ? f_xall : f_res, i==0 ? nullptr : f_st,
                                      in_nw + i*256, in_nb + i*256, f_res, b_hn);
    gemm_k<0><<<dim3(32,8,2),256,0,stream>>>(b_hn, b_win + (size_t)i*1024*256,
                                             f_xz, nullptr, nullptr, nullptr, nullptr);
    convproj_k<<<1024,256,0,stream>>>(f_xz, in_cw + i*DIN_*4, in_cb + i*DIN_,
                                     in_xpw + i*48*DIN_, in_dtw + i*DIN_*16, in_dtb + i*DIN_,
                                     f_u, f_dt, f_xd);
    scan_k<1><<<512,512,0,stream>>>(f_dt, f_u, f_xd, f_an + i*DIN_*16,
                                    nullptr, nullptr, f_hp, f_pp, nullptr);
    scanfix_k<<<256,256,0,stream>>>(f_hp, f_pp);
    scan_k<2><<<512,512,0,stream>>>(f_dt, f_u, f_xd, f_an + i*DIN_*16,
                                    f_xz, in_dsk + i*DIN_, f_hp, f_pp, b_ybar);
    gemm_k<1><<<dim3(32,4,2),256,0,stream>>>(b_ybar, b_wout + (size_t)i*256*512,
                                             f_st, nullptr, nullptr, nullptr, nullptr);
    currgate_k<<<2048,256,0,stream>>>(f_st, f_res, in_gw + i*NE*256, in_gb + i*NE,
                                      b_curr, f_gate);
    gemm_k<2><<<dim3(32,8,8),256,0,stream>>>(b_curr, b_we1 + (size_t)i*NE*HM*256,
                                             nullptr, b_h,
                                             in_e1b + i*NE*HM, f_gate, nullptr);
    gemm_k<3><<<dim3(32,4,8),256,0,stream>>>(b_h, b_we2 + (size_t)i*NE*256*HM,
                                             f_mp, nullptr,
                                             nullptr, nullptr, nullptr);
    moered_k<<<2048,256,0,stream>>>(f_mp, f_gate, in_e2b + i*NE*256, f_res);
  }

  lnres_k<1><<<2048,256,0,stream>>>(f_res, f_st, in_nfw, in_nfb, f_fin, nullptr);
  poolscore_k<<<64,256,0,stream>>>(f_fin, in_fpw, in_fpb, in_bpw, in_bpb, f_score);
  poolnorm_k<<<8,256,0,stream>>>(f_score);
  poolsum_k<<<128,256,0,stream>>>(f_fin, f_score, f_part);
  head_k<<<4,256,0,stream>>>(f_part, in_llw, in_llb, (float*)d_out);
}

// Round 13
// 1014.988 us; speedup vs baseline: 8.4795x; 1.0023x over previous
//
#include <hip/hip_runtime.h>
#include <cstdint>
#include <cstddef>

typedef __attribute__((ext_vector_type(4))) float f32x4;
typedef __attribute__((ext_vector_type(8))) short s16x8;
typedef __attribute__((ext_vector_type(4))) short s16x4;
using u16 = unsigned short;

constexpr int NL   = 4;
constexpr int DIN_ = 512;
constexpr int HM   = 1024;
constexpr int NE   = 4;
constexpr int TPD  = 4096;   // tokens per direction (B*L)
constexpr int TOK  = 8192;   // both directions
constexpr int NCH  = 64;     // scan chunks per sequence
constexpr int CLEN = 16;     // steps per chunk

__device__ __forceinline__ u16 f2b(float f){
  unsigned u = __builtin_bit_cast(unsigned, f);
  u += 0x7fffu + ((u >> 16) & 1u);
  return (u16)(u >> 16);
}
__device__ __forceinline__ float b2f(u16 h){
  return __builtin_bit_cast(float, (unsigned)h << 16);
}
__device__ __forceinline__ float sigm(float x){ return 1.f/(1.f + __expf(-x)); }

// ---------------- prep kernels ----------------
__global__ void cvt_bf16_k(const float* __restrict__ s, u16* __restrict__ d, int n4){
  int i = blockIdx.x*blockDim.x + threadIdx.x;
  const int st = gridDim.x*blockDim.x;
  for (; i < n4; i += st){
    const f32x4 v = *(const f32x4*)(s + (size_t)i*4);
    s16x4 o;
    #pragma unroll
    for (int j=0;j<4;++j) o[j] = (short)f2b(v[j]);
    *(s16x4*)(d + (size_t)i*4) = o;
  }
}

// pack xpw (2,NL,48,512) -> [dir][NL][64][512] bf16 hi/lo (rows 48..63 zero)
__global__ void xpack_k(const float* __restrict__ xpw, u16* __restrict__ whi,
                        u16* __restrict__ wlo){
  const int i = blockIdx.x*256 + threadIdx.x;       // 2*NL*64*512
  const int col = i & 511, row = (i>>9) & 63, dl = i>>15;
  float w = 0.f;
  if (row < 48) w = xpw[(size_t)dl*48*512 + (size_t)row*512 + col];
  const u16 h = f2b(w);
  whi[i] = h;
  wlo[i] = f2b(w - b2f(h));
}

__global__ void aneg_k(const float* __restrict__ a, float* __restrict__ o, int n){
  int i = blockIdx.x*256 + threadIdx.x;
  if (i < n) o[i] = -__expf(a[i]);
}

__global__ void xall_k(const float* __restrict__ x, float* __restrict__ o){
  const int i = blockIdx.x*256 + threadIdx.x;           // [0, 2*4*1024*256)
  const int d = i & 255, l = (i>>8)&1023, b2 = (i>>18)&3, dir = i>>20;
  const int ls = dir ? (1023 - l) : l;
  o[i] = x[((size_t)(b2<<10) + ls)*256 + d];
}

// ---------------- LN (+residual) ----------------
template<int MODE>
__global__ __launch_bounds__(256)
void lnres_k(const float* __restrict__ s1, const float* __restrict__ s2,
             const float* __restrict__ w, const float* __restrict__ b,
             float* __restrict__ fout, u16* __restrict__ hnout)
{
  const int wv = threadIdx.x >> 6, lane = threadIdx.x & 63;
  const int tok = blockIdx.x*4 + wv;
  const int dir = tok >> 12;
  const size_t base = (size_t)tok*256 + lane*4;
  f32x4 r = *(const f32x4*)(s1 + base);
  if (s2){ f32x4 c = *(const f32x4*)(s2 + base); r += c; }
  float sv = r[0]+r[1]+r[2]+r[3];
  float qv = r[0]*r[0]+r[1]*r[1]+r[2]*r[2]+r[3]*r[3];
  #pragma unroll
  for (int o=32;o;o>>=1){ sv += __shfl_xor(sv,o); qv += __shfl_xor(qv,o); }
  const float mu = sv*(1.f/256.f);
  const float var = qv*(1.f/256.f) - mu*mu;
  const float inv = rsqrtf(var + 1e-5f);
  const int woff = (MODE==0) ? dir*(NL*256) : 0;
  const f32x4 w4 = *(const f32x4*)(w + woff + lane*4);
  const f32x4 b4 = *(const f32x4*)(b + woff + lane*4);
  f32x4 y;
  #pragma unroll
  for (int j=0;j<4;++j) y[j] = (r[j]-mu)*inv*w4[j] + b4[j];
  if constexpr (MODE==0){
    *(f32x4*)(fout + base) = r;
    s16x4 hh;
    #pragma unroll
    for (int j=0;j<4;++j) hh[j] = (short)f2b(y[j]);
    *(s16x4*)(hnout + base) = hh;
  } else {
    *(f32x4*)(fout + base) = y;
  }
}

// ---------------- MFMA bf16 GEMM: C = A @ W^T ----------------
// LDS slot-swizzle: physical slot p of row m holds logical slot p ^ ((m>>2)&3).
// CFG 0: in_proj  N=1024 K=256  -> OF f32 (f_xz)
// CFG 1: out_proj N=256  K=512  -> OF f32 (f_st)
// CFG 2: moe h    z=dir*4+e, N=1024 K=256 -> OB bf16 = gate*gelu(acc+b1)
// CFG 3: moe o2   z=e*2+dir, per-expert K=1024 -> OF f32 partial[z]
// CFG 4: x_proj   split-bf16 compensated: acc = Ahi*Whi + Alo*Whi + Ahi*Wlo
//         M=TPD/z N=64(48 used) K=512; P0=u_lo, P1=w_lo (cast)
template<int CFG>
__global__ __launch_bounds__(256, 2)
void gemm_k(const u16* __restrict__ A0, const u16* __restrict__ W0,
            float* OF, u16* OB,
            const float* __restrict__ P0, const float* __restrict__ P1,
            const float* __restrict__ P2)
{
  constexpr int BM = (CFG==4) ? 64 : 128;
  constexpr int BN = (CFG==1 || CFG==3 || CFG==4) ? 64 : 128;
  constexpr int KD = (CFG==0 || CFG==2) ? 256 : ((CFG==1) ? 512 : ((CFG==3) ? 1024 : 512));
  constexpr int LDA = (CFG==3) ? 4096 : KD;
  constexpr int FM = BM/32;
  constexpr int FN = BN/32;
  constexpr int IA = BM/64;
  constexpr int IB = BN/64;
  constexpr int NPH = (CFG==4) ? 3 : 1;

  __shared__ u16 sA[BM*32];
  __shared__ u16 sB[BN*32];

  const int tid = threadIdx.x;
  const int wave = tid >> 6, lane = tid & 63;
  const int bm0 = blockIdx.x * BM, bn0 = blockIdx.y * BN;
  const int z = blockIdx.z;
  const int wm0 = (wave >> 1) * (BM/2);
  const int wn0 = (wave & 1) * (BN/2);

  const u16* Az; const u16* Wz;
  int koff = 0, eoff = 0;
  if constexpr (CFG==0){ Az = A0 + (size_t)z*TPD*256;  Wz = W0 + (size_t)z*(NL*1024*256); }
  else if constexpr (CFG==1){ Az = A0 + (size_t)z*TPD*512; Wz = W0 + (size_t)z*(NL*256*512); }
  else if constexpr (CFG==2){ Az = A0 + (size_t)(z>>2)*TPD*256;
                              Wz = W0 + (size_t)(z>>2)*((size_t)NL*NE*HM*256) + (size_t)(z&3)*(HM*256); }
  else if constexpr (CFG==3){ Az = A0 + (size_t)(z&1)*TPD*4096;
         Wz = W0 + (size_t)(z&1)*((size_t)NL*NE*256*HM);
         koff = (z>>1)*1024; eoff = (z>>1)*256; }
  else { Az = A0 + (size_t)z*TPD*512; Wz = W0 + (size_t)z*(NL*64*512); }

  f32x4 acc[FM][FN];
  #pragma unroll
  for (int i=0;i<FM;++i)
    #pragma unroll
    for (int j=0;j<FN;++j) acc[i][j] = (f32x4){0.f,0.f,0.f,0.f};

  const int r = lane & 15, q = lane >> 4;
  const int qs8 = (q ^ ((r>>2)&3))*8;     // swizzled 16B-slot for LDS reads

  #pragma unroll
  for (int ph=0; ph<NPH; ++ph){
    const u16* Ap = Az; const u16* Wp = Wz;
    if constexpr (CFG==4){
      if (ph==1) Ap = (const u16*)P0 + (size_t)z*TPD*512;
      if (ph==2) Wp = (const u16*)P1 + (size_t)z*(NL*64*512);
    }
    for (int k0 = 0; k0 < KD; k0 += 32){
      #pragma unroll
      for (int j=0;j<IA;++j){
        const int c = (wave*IA + j)*64 + lane;
        const int m = c >> 2, kq = (c & 3) ^ ((m>>2)&3);
        const u16* g;
        if constexpr (CFG==3) g = Ap + (size_t)(bm0 + m)*LDA + (koff + k0 + kq*8);
        else                  g = Ap + (size_t)(bm0 + m)*LDA + (k0 + kq*8);
        __builtin_amdgcn_global_load_lds((const __attribute__((address_space(1))) void*)g,
            (__attribute__((address_space(3))) void*)(sA + (size_t)(wave*IA + j)*512), 16, 0, 0);
      }
      #pragma unroll
      for (int j=0;j<IB;++j){
        const int c = (wave*IB + j)*64 + lane;
        const int n = c >> 2, kq = (c & 3) ^ ((n>>2)&3);
        const u16* g;
        if constexpr (CFG==3){
          g = Wp + ((size_t)eoff + (bn0 + n))*1024 + (k0 + kq*8);
        } else {
          g = Wp + (size_t)(bn0 + n)*KD + (k0 + kq*8);
        }
        __builtin_amdgcn_global_load_lds((const __attribute__((address_space(1))) void*)g,
            (__attribute__((address_space(3))) void*)(sB + (size_t)(wave*IB + j)*512), 16, 0, 0);
      }
      __syncthreads();
      s16x8 av[FM], bv[FN];
      #pragma unroll
      for (int mi=0;mi<FM;++mi) av[mi] = *(const s16x8*)(sA + (wm0 + mi*16 + r)*32 + qs8);
      #pragma unroll
      for (int ni=0;ni<FN;++ni) bv[ni] = *(const s16x8*)(sB + (wn0 + ni*16 + r)*32 + qs8);
      #pragma unroll
      for (int mi=0;mi<FM;++mi)
        #pragma unroll
        for (int ni=0;ni<FN;++ni)
          acc[mi][ni] = __builtin_amdgcn_mfma_f32_16x16x32_bf16(av[mi], bv[ni], acc[mi][ni], 0, 0, 0);
      __syncthreads();
    }
  }

  #pragma unroll
  for (int mi=0;mi<FM;++mi){
    #pragma unroll
    for (int ni=0;ni<FN;++ni){
      const int col = bn0 + wn0 + ni*16 + r;
      #pragma unroll
      for (int rr=0;rr<4;++rr){
        const int row = bm0 + wm0 + mi*16 + q*4 + rr;
        const float v = acc[mi][ni][rr];
        if constexpr (CFG==0){
          OF[((size_t)z*TPD + row)*1024 + col] = v;
        } else if constexpr (CFG==1){
          OF[((size_t)z*TPD + row)*256 + col] = v;
        } else if constexpr (CFG==2){
          const int dir = z>>2, e = z&3;
          const float xv = v + P0[(size_t)dir*(NL*NE*HM) + (size_t)e*HM + col];
          const float ge = 0.5f*xv*(1.f + erff(xv*0.70710678118654752f));
          const float gt = P1[((size_t)dir*TPD + row)*4 + e];
          OB[((size_t)dir*TPD + row)*4096 + (size_t)e*1024 + col] = f2b(ge*gt);
        } else if constexpr (CFG==3){
          OF[((size_t)z*TPD + row)*256 + col] = v;   // partial[z=e*2+dir]
        } else {
          if (col < 48) OF[((size_t)z*TPD + row)*48 + col] = v;
        }
      }
    }
  }
}

// ---------------- MoE partial reduce ----------------
__global__ __launch_bounds__(256)
void moered_k(const float* __restrict__ part, const float* __restrict__ gate,
              const float* __restrict__ b2, float* __restrict__ res)
{
  const int i4 = blockIdx.x*256 + threadIdx.x;       // 0 .. TOK*64-1
  const int tok = i4 >> 6;
  const int c4 = i4 & 63;
  const int dir = tok >> 12, rr = tok & 4095;
  const float* gp = gate + (size_t)tok*4;
  const float* b2p = b2 + (size_t)dir*(NL*NE*256);
  f32x4 acc = *(f32x4*)(res + (size_t)tok*256 + c4*4);
  #pragma unroll
  for (int e=0;e<4;++e){
    const f32x4 pv = *(const f32x4*)(part + ((size_t)(e*2+dir)*TPD + rr)*256 + c4*4);
    const f32x4 bv = *(const f32x4*)(b2p + e*256 + c4*4);
    const float g = gp[e];
    acc += pv;
    acc += g*bv;
  }
  *(f32x4*)(res + (size_t)tok*256 + c4*4) = acc;
}

// ---------------- conv + silu -> split-bf16 u (for x_proj GEMM) ----------------
__global__ __launch_bounds__(256)
void conv_silu_k(const float* __restrict__ xz,
                 const float* __restrict__ cw, const float* __restrict__ cb,
                 u16* __restrict__ uhi, u16* __restrict__ ulo)
{
  const int idx = blockIdx.x*256 + threadIdx.x;     // TOK*128
  const int c4 = idx & 127;
  const int tok = idx >> 7;
  const int dir = tok >> 12, t = tok & 1023;
  const float* cwp = cw + (size_t)dir*(NL*DIN_*4) + (size_t)c4*16;
  const float* cbp = cb + (size_t)dir*(NL*DIN_);
  const f32x4 w0 = *(const f32x4*)(cwp);
  const f32x4 w1 = *(const f32x4*)(cwp + 4);
  const f32x4 w2 = *(const f32x4*)(cwp + 8);
  const f32x4 w3 = *(const f32x4*)(cwp + 12);
  const f32x4 cb4 = *(const f32x4*)(cbp + c4*4);
  f32x4 x0 = (f32x4){0,0,0,0}, x1 = x0, x2 = x0;
  if (t >= 3) x0 = *(const f32x4*)(xz + ((size_t)tok-3)*1024 + c4*4);
  if (t >= 2) x1 = *(const f32x4*)(xz + ((size_t)tok-2)*1024 + c4*4);
  if (t >= 1) x2 = *(const f32x4*)(xz + ((size_t)tok-1)*1024 + c4*4);
  const f32x4 x3 = *(const f32x4*)(xz + (size_t)tok*1024 + c4*4);
  f32x4 a;
  a[0] = cb4[0] + x0[0]*w0[0] + x1[0]*w0[1] + x2[0]*w0[2] + x3[0]*w0[3];
  a[1] = cb4[1] + x0[1]*w1[0] + x1[1]*w1[1] + x2[1]*w1[2] + x3[1]*w1[3];
  a[2] = cb4[2] + x0[2]*w2[0] + x1[2]*w2[1] + x2[2]*w2[2] + x3[2]*w2[3];
  a[3] = cb4[3] + x0[3]*w3[0] + x1[3]*w3[1] + x2[3]*w3[2] + x3[3]*w3[3];
  s16x4 hh, ll;
  #pragma unroll
  for (int j=0;j<4;++j){
    const float uv = a[j]*sigm(a[j]);
    const u16 h = f2b(uv);
    hh[j] = (short)h;
    ll[j] = (short)f2b(uv - b2f(h));
  }
  *(s16x4*)(uhi + (size_t)tok*DIN_ + c4*4) = hh;
  *(s16x4*)(ulo + (size_t)tok*DIN_ + c4*4) = ll;
}

// ---------------- chunked scan w/ fused conv (sliding window) + dt_proj ----------------
template<int PASS>
__global__ __launch_bounds__(512)
void scan_k(const float* __restrict__ xz, const float* __restrict__ xd,
            const float* __restrict__ an,
            const float* __restrict__ cw, const float* __restrict__ cb,
            const float* __restrict__ dtw, const float* __restrict__ dtb,
            const float* __restrict__ dsk,
            float* __restrict__ hp, float* __restrict__ pp,
            u16* __restrict__ ybar)
{
  const int ch = threadIdx.x;                         // 0..511
  const int blk = blockIdx.x;                         // (dir*4+b)*NCH + chunk
  const int chunk = blk & (NCH-1), bb = (blk>>6)&3, dir = blk>>8;
  const size_t seqbase = (size_t)(dir*4+bb)*1024;
  const int ltb = chunk*CLEN;
  const float* ap = an + (size_t)dir*(NL*DIN_*16) + (size_t)ch*16;
  float A_[16];
  #pragma unroll
  for (int n=0;n<16;++n) A_[n] = ap[n];
  const float* dtp = dtw + (size_t)dir*(NL*DIN_*16) + (size_t)ch*16;
  f32x4 D4[4];
  #pragma unroll
  for (int r4=0;r4<4;++r4) D4[r4] = *(const f32x4*)(dtp + r4*4);
  const float dtbc = dtb[(size_t)dir*(NL*DIN_) + ch];
  const float* cwp = cw + (size_t)dir*(NL*DIN_*4) + (size_t)ch*4;
  const float cw0 = cwp[0], cw1 = cwp[1], cw2 = cwp[2], cw3 = cwp[3];
  const float cbc = cb[(size_t)dir*(NL*DIN_) + ch];
  const size_t scanid = (size_t)(dir*4+bb)*512 + ch;
  const size_t hbase = (scanid*NCH + chunk)*16;
  float h[16], P[16];
  if constexpr (PASS==1){
    #pragma unroll
    for (int n=0;n<16;++n){ h[n]=0.f; P[n]=1.f; }
  } else {
    #pragma unroll
    for (int n=0;n<16;++n) h[n] = hp[hbase+n];
  }
  float dval = 0.f;
  if constexpr (PASS==2) dval = dsk[(size_t)dir*(NL*DIN_) + ch];
  // sliding conv window (exact f32 recompute)
  float x0 = (ltb>=3) ? xz[(seqbase+ltb-3)*1024 + ch] : 0.f;
  float x1 = (ltb>=2) ? xz[(seqbase+ltb-2)*1024 + ch] : 0.f;
  float x2 = (ltb>=1) ? xz[(seqbase+ltb-1)*1024 + ch] : 0.f;
  for (int t=0;t<CLEN;++t){
    const size_t tok = seqbase + ltb + t;
    const float x3 = xz[tok*1024 + ch];
    const float a = cbc + x0*cw0 + x1*cw1 + x2*cw2 + x3*cw3;
    const float uv = a*sigm(a);
    x0 = x1; x1 = x2; x2 = x3;
    const float* xr = xd + tok*48;
    f32x4 dacc = (f32x4){0.f,0.f,0.f,0.f};
    #pragma unroll
    for (int r4=0;r4<4;++r4) dacc += (*(const f32x4*)(xr + r4*4)) * D4[r4];
    const float draw = dtbc + dacc[0]+dacc[1]+dacc[2]+dacc[3];
    const float dtv = (draw > 20.f) ? draw : log1pf(__expf(draw));
    const float dtu = dtv*uv;
    float y = 0.f;
    #pragma unroll
    for (int n=0;n<16;++n){
      const float e = __expf(dtv*A_[n]);
      const float hn2 = h[n]*e + dtu*xr[16+n];
      h[n] = hn2;
      if constexpr (PASS==1) P[n] *= e;
      else y += hn2*xr[32+n];
    }
    if constexpr (PASS==2){
      const float zv = xz[tok*1024 + 512 + ch];
      ybar[tok*DIN_ + ch] = f2b((y + uv*dval) * (zv * sigm(zv)));
    }
  }
  if constexpr (PASS==1){
    #pragma unroll
    for (int n=0;n<16;++n){ hp[hbase+n] = h[n]; pp[hbase+n] = P[n]; }
  }
}

// parallel fixup over (scan-id, state)
__global__ __launch_bounds__(256)
void scanfix_k(float* __restrict__ hp, const float* __restrict__ pp){
  const int id2 = blockIdx.x*256 + threadIdx.x;       // 0..65535
  const int id = id2 >> 4, n = id2 & 15;
  float s = 0.f;
  for (int c=0;c<NCH;++c){
    const size_t base = ((size_t)id*NCH + c)*16 + n;
    const float hv = hp[base];
    const float pv = pp[base];
    hp[base] = s;
    s = hv + pv*s;
  }
}

// ---------------- curr = states + resid ; gating (f32) ----------------
__global__ __launch_bounds__(256)
void currgate_k(const float* __restrict__ st, const float* __restrict__ rs,
                const float* __restrict__ gw, const float* __restrict__ gb,
                u16* __restrict__ currb, float* __restrict__ gate)
{
  const int wv = threadIdx.x>>6, lane = threadIdx.x&63;
  const int tok = blockIdx.x*4 + wv;
  const int dir = tok>>12;
  const size_t base = (size_t)tok*256 + lane*4;
  f32x4 a = *(const f32x4*)(st+base);
  { f32x4 c = *(const f32x4*)(rs+base); a += c; }
  s16x4 cc;
  #pragma unroll
  for (int j=0;j<4;++j) cc[j] = (short)f2b(a[j]);
  *(s16x4*)(currb+base) = cc;
  const float* gwp = gw + (size_t)dir*(NL*NE*256);
  float lg[4];
  #pragma unroll
  for (int e=0;e<4;++e){
    const float* w4 = gwp + e*256 + lane*4;
    lg[e] = a[0]*w4[0] + a[1]*w4[1] + a[2]*w4[2] + a[3]*w4[3];
  }
  #pragma unroll
  for (int o=32;o;o>>=1){
    #pragma unroll
    for (int e=0;e<4;++e) lg[e] += __shfl_xor(lg[e], o);
  }
  if (lane==0){
    const float* gbp = gb + dir*(NL*NE);
    float sc[4]; float mx = -1e30f;
    #pragma unroll
    for (int e=0;e<4;++e){ sc[e] = lg[e] + gbp[e]; mx = fmaxf(mx, sc[e]); }
    float den = 0.f;
    #pragma unroll
    for (int e=0;e<4;++e){ sc[e] = __expf(sc[e]-mx); den += sc[e]; }
    const float rden = 1.f/den;
    #pragma unroll
    for (int e=0;e<4;++e) sc[e] *= rden;
    int i1 = 0;
    #pragma unroll
    for (int e=1;e<4;++e) if (sc[e] > sc[i1]) i1 = e;
    int i2 = (i1==0)?1:0;
    #pragma unroll
    for (int e=0;e<4;++e) if (e!=i1 && sc[e] > sc[i2]) i2 = e;
    const float ssum = sc[i1] + sc[i2] + 1e-6f;
    #pragma unroll
    for (int e=0;e<4;++e)
      gate[(size_t)tok*4+e] = (e==i1) ? sc[i1]/ssum : ((e==i2) ? sc[i2]/ssum : 0.f);
  }
}

// ---------------- pooling (parallel) ----------------
__global__ __launch_bounds__(256)
void poolscore_k(const float* __restrict__ fin, const float* __restrict__ fw,
                 const float* __restrict__ fb, const float* __restrict__ bw,
                 const float* __restrict__ bbs, float* __restrict__ score)
{
  const int blk = blockIdx.x;                   // p = blk>>3, g = blk&7
  const int p = blk >> 3, g = blk & 7;
  const int dir = p >> 2;
  const float* pw = dir ? bw : fw;
  const float pb = dir ? bbs[0] : fb[0];
  const int wv = threadIdx.x>>6, lane = threadIdx.x&63;
  const size_t fbase = (size_t)p*1024*256;
  const f32x4 w4 = *(const f32x4*)(pw + lane*4);
  for (int l = g*128 + wv; l < (g+1)*128; l += 4){
    const f32x4 f4 = *(const f32x4*)(fin + fbase + (size_t)l*256 + lane*4);
    float pv = f4[0]*w4[0] + f4[1]*w4[1] + f4[2]*w4[2] + f4[3]*w4[3];
    #pragma unroll
    for (int o=32;o;o>>=1) pv += __shfl_xor(pv,o);
    if (lane==0) score[p*1024 + l] = pv + pb;
  }
}

__global__ __launch_bounds__(256)
void poolnorm_k(float* __restrict__ score)
{
  __shared__ float red[8];
  const int p = blockIdx.x;
  const int tid = threadIdx.x, wv = tid>>6, lane = tid&63;
  float* s = score + p*1024;
  float v[4];
  float m = -1e30f;
  #pragma unroll
  for (int j=0;j<4;++j){ v[j] = s[tid + j*256]; m = fmaxf(m, v[j]); }
  #pragma unroll
  for (int o=32;o;o>>=1) m = fmaxf(m, __shfl_xor(m,o));
  if (lane==0) red[wv] = m;
  __syncthreads();
  m = fmaxf(fmaxf(red[0],red[1]), fmaxf(red[2],red[3]));
  float ssum = 0.f;
  #pragma unroll
  for (int j=0;j<4;++j){ v[j] = __expf(v[j]-m); ssum += v[j]; }
  #pragma unroll
  for (int o=32;o;o>>=1) ssum += __shfl_xor(ssum,o);
  if (lane==0) red[4+wv] = ssum;
  __syncthreads();
  const float inv = 1.f/(red[4]+red[5]+red[6]+red[7]);
  #pragma unroll
  for (int j=0;j<4;++j) s[tid + j*256] = v[j]*inv;
}

__global__ __launch_bounds__(256)
void poolsum_k(const float* __restrict__ fin, const float* __restrict__ score,
               float* __restrict__ part)
{
  const int blk = blockIdx.x;                   // p = blk>>4, g = blk&15
  const int p = blk >> 4, g = blk & 15;
  const int d = threadIdx.x;
  const size_t fbase = (size_t)p*1024*256;
  float acc = 0.f;
  #pragma unroll 4
  for (int l = g*64; l < (g+1)*64; ++l)
    acc += score[p*1024 + l] * fin[fbase + (size_t)l*256 + d];
  part[((size_t)p*16 + g)*256 + d] = acc;
}

__global__ __launch_bounds__(256)
void head_k(const float* __restrict__ part, const float* __restrict__ llw,
            const float* __restrict__ llb, float* __restrict__ out)
{
  __shared__ float sp[2*256];
  const int d = threadIdx.x;
  const int b = blockIdx.x;                     // 0..3
  float a0 = 0.f, a1 = 0.f;
  #pragma unroll
  for (int g=0;g<16;++g){
    a0 += part[((size_t)b*16 + g)*256 + d];
    a1 += part[((size_t)(4+b)*16 + g)*256 + d];
  }
  sp[d] = a0; sp[256 + d] = a1;
  __syncthreads();
  const int o = d;
  const float* wr = llw + (size_t)o*512;
  f32x4 acc4 = (f32x4){0.f,0.f,0.f,0.f};
  #pragma unroll 8
  for (int k4=0;k4<64;++k4){
    acc4 += (*(const f32x4*)(sp + k4*4)) * (*(const f32x4*)(wr + k4*4));
  }
  #pragma unroll 8
  for (int k4=0;k4<64;++k4){
    acc4 += (*(const f32x4*)(sp + 256 + k4*4)) * (*(const f32x4*)(wr + 256 + k4*4));
  }
  out[b*256 + o] = llb[o] + acc4[0]+acc4[1]+acc4[2]+acc4[3];
}

// ---------------- host ----------------
extern "C" void kernel_launch(void* const* d_in, const int* in_sizes, int n_in,
                              void* d_out, int out_size, void* d_ws, size_t ws_size,
                              hipStream_t stream)
{
  const float* in_x    = (const float*)d_in[0];
  const float* in_inw  = (const float*)d_in[1];
  const float* in_cw   = (const float*)d_in[2];
  const float* in_cb   = (const float*)d_in[3];
  const float* in_xpw  = (const float*)d_in[4];
  const float* in_dtw  = (const float*)d_in[5];
  const float* in_dtb  = (const float*)d_in[6];
  const float* in_alog = (const float*)d_in[7];
  const float* in_dsk  = (const float*)d_in[8];
  const float* in_ow   = (const float*)d_in[9];
  const float* in_nw   = (const float*)d_in[10];
  const float* in_nb   = (const float*)d_in[11];
  const float* in_gw   = (const float*)d_in[12];
  const float* in_gb   = (const float*)d_in[13];
  const float* in_e1w  = (const float*)d_in[14];
  const float* in_e1b  = (const float*)d_in[15];
  const float* in_e2w  = (const float*)d_in[16];
  const float* in_e2b  = (const float*)d_in[17];
  const float* in_nfw  = (const float*)d_in[18];
  const float* in_nfb  = (const float*)d_in[19];
  const float* in_fpw  = (const float*)d_in[20];
  const float* in_fpb  = (const float*)d_in[21];
  const float* in_bpw  = (const float*)d_in[22];
  const float* in_bpb  = (const float*)d_in[23];
  const float* in_llw  = (const float*)d_in[24];
  const float* in_llb  = (const float*)d_in[25];

  uint8_t* ws = (uint8_t*)d_ws;
  size_t off = 0;
  auto take = [&](size_t bytes)->size_t{
    size_t o = off; off += (bytes + 255) & ~(size_t)255; return o;
  };
  float* f_xall = (float*)(ws + take((size_t)TOK*256*4));   // reused as f_fin
  float* f_res  = (float*)(ws + take((size_t)TOK*256*4));
  float* f_st   = (float*)(ws + take((size_t)TOK*256*4));
  float* f_xz   = (float*)(ws + take((size_t)TOK*1024*4));  // aliased as MoE partials
  float* f_xd   = (float*)(ws + take((size_t)TOK*48*4));
  float* f_hp   = (float*)(ws + take((size_t)4096*NCH*16*4));
  float* f_pp   = (float*)(ws + take((size_t)4096*NCH*16*4));
  float* f_gate = (float*)(ws + take((size_t)TOK*4*4));
  float* f_an   = (float*)(ws + take((size_t)2*NL*DIN_*16*4));
  float* f_score= (float*)(ws + take((size_t)8*1024*4));
  float* f_part = (float*)(ws + take((size_t)8*16*256*4));
  u16* b_hn   = (u16*)(ws + take((size_t)TOK*256*2));
  u16* b_ybar = (u16*)(ws + take((size_t)TOK*DIN_*2));
  u16* b_curr = (u16*)(ws + take((size_t)TOK*256*2));
  u16* b_uhi  = (u16*)(ws + take((size_t)TOK*DIN_*2));
  u16* b_ulo  = (u16*)(ws + take((size_t)TOK*DIN_*2));
  u16* b_h    = (u16*)(ws + take((size_t)TOK*4096*2));
  u16* b_win  = (u16*)(ws + take((size_t)2*NL*1024*256*2));
  u16* b_wout = (u16*)(ws + take((size_t)2*NL*256*512*2));
  u16* b_we1  = (u16*)(ws + take((size_t)2*NL*NE*HM*256*2));
  u16* b_we2  = (u16*)(ws + take((size_t)2*NL*NE*256*HM*2));
  u16* b_wxhi = (u16*)(ws + take((size_t)2*NL*64*512*2));
  u16* b_wxlo = (u16*)(ws + take((size_t)2*NL*64*512*2));
  float* f_fin  = f_xall;
  float* f_mp   = f_xz;       // MoE partials: [8][TPD][256] f32 (f_xz free then)
  (void)ws_size; (void)in_sizes; (void)n_in; (void)out_size;

  // prep: weights -> bf16
  cvt_bf16_k<<<1024,256,0,stream>>>(in_inw, b_win, 2*NL*1024*256/4);
  cvt_bf16_k<<<1024,256,0,stream>>>(in_ow,  b_wout, 2*NL*256*512/4);
  cvt_bf16_k<<<2048,256,0,stream>>>(in_e1w, b_we1, 2*NL*NE*HM*256/4);
  cvt_bf16_k<<<2048,256,0,stream>>>(in_e2w, b_we2, 2*NL*NE*256*HM/4);
  xpack_k<<<1024,256,0,stream>>>(in_xpw, b_wxhi, b_wxlo);
  aneg_k<<<256,256,0,stream>>>(in_alog, f_an, 2*NL*DIN_*16);
  xall_k<<<8192,256,0,stream>>>(in_x, f_xall);

  for (int i=0;i<NL;++i){
    lnres_k<0><<<2048,256,0,stream>>>(i==0 ? f_xall : f_res, i==0 ? nullptr : f_st,
                                      in_nw + i*256, in_nb + i*256, f_res, b_hn);
    gemm_k<0><<<dim3(32,8,2),256,0,stream>>>(b_hn, b_win + (size_t)i*1024*256,
                                             f_xz, nullptr, nullptr, nullptr, nullptr);
    conv_silu_k<<<4096,256,0,stream>>>(f_xz, in_cw + i*DIN_*4, in_cb + i*DIN_,
                                       b_uhi, b_ulo);
    gemm_k<4><<<dim3(64,1,2),256,0,stream>>>(b_uhi, b_wxhi + (size_t)i*64*512,
                                             f_xd, nullptr,
                                             (const float*)b_ulo,
                                             (const float*)(b_wxlo + (size_t)i*64*512),
                                             nullptr);
    scan_k<1><<<512,512,0,stream>>>(f_xz, f_xd, f_an + i*DIN_*16,
                                    in_cw + i*DIN_*4, in_cb + i*DIN_,
                                    in_dtw + i*DIN_*16, in_dtb + i*DIN_,
                                    nullptr, f_hp, f_pp, nullptr);
    scanfix_k<<<256,256,0,stream>>>(f_hp, f_pp);
    scan_k<2><<<512,512,0,stream>>>(f_xz, f_xd, f_an + i*DIN_*16,
                                    in_cw + i*DIN_*4, in_cb + i*DIN_,
                                    in_dtw + i*DIN_*16, in_dtb + i*DIN_,
                                    in_dsk + i*DIN_, f_hp, f_pp, b_ybar);
    gemm_k<1><<<dim3(32,4,2),256,0,stream>>>(b_ybar, b_wout + (size_t)i*256*512,
                                             f_st, nullptr, nullptr, nullptr, nullptr);
    currgate_k<<<2048,256,0,stream>>>(f_st, f_res, in_gw + i*NE*256, in_gb + i*NE,
                                      b_curr, f_gate);
    gemm_k<2><<<dim3(32,8,8),256,0,stream>>>(b_curr, b_we1 + (size_t)i*NE*HM*256,
                                             nullptr, b_h,
                                             in_e1b + i*NE*HM, f_gate, nullptr);
    gemm_k<3><<<dim3(32,4,8),256,0,stream>>>(b_h, b_we2 + (size_t)i*NE*256*HM,
                                             f_mp, nullptr,
                                             nullptr, nullptr, nullptr);
    moered_k<<<2048,256,0,stream>>>(f_mp, f_gate, in_e2b + i*NE*256, f_res);
  }

  lnres_k<1><<<2048,256,0,stream>>>(f_res, f_st, in_nfw, in_nfb, f_fin, nullptr);
  poolscore_k<<<64,256,0,stream>>>(f_fin, in_fpw, in_fpb, in_bpw, in_bpb, f_score);
  poolnorm_k<<<8,256,0,stream>>>(f_score);
  poolsum_k<<<128,256,0,stream>>>(f_fin, f_score, f_part);
  head_k<<<4,256,0,stream>>>(f_part, in_llw, in_llb, (float*)d_out);
}

// Round 14
// 985.817 us; speedup vs baseline: 8.7304x; 1.0296x over previous
//
#include <hip/hip_runtime.h>
#include <cstdint>
#include <cstddef>

typedef __attribute__((ext_vector_type(4))) float f32x4;
typedef __attribute__((ext_vector_type(8))) short s16x8;
typedef __attribute__((ext_vector_type(4))) short s16x4;
using u16 = unsigned short;

constexpr int NL   = 4;
constexpr int DIN_ = 512;
constexpr int HM   = 1024;
constexpr int NE   = 4;
constexpr int TPD  = 4096;   // tokens per direction (B*L)
constexpr int TOK  = 8192;   // both directions
constexpr int NCH  = 64;     // scan chunks per sequence
constexpr int CLEN = 16;     // steps per chunk

__device__ __forceinline__ u16 f2b(float f){
  unsigned u = __builtin_bit_cast(unsigned, f);
  u += 0x7fffu + ((u >> 16) & 1u);
  return (u16)(u >> 16);
}
__device__ __forceinline__ float b2f(u16 h){
  return __builtin_bit_cast(float, (unsigned)h << 16);
}
__device__ __forceinline__ float sigm(float x){ return 1.f/(1.f + __expf(-x)); }

// ---------------- prep kernels ----------------
__global__ void cvt_bf16_k(const float* __restrict__ s, u16* __restrict__ d, int n4){
  int i = blockIdx.x*blockDim.x + threadIdx.x;
  const int st = gridDim.x*blockDim.x;
  for (; i < n4; i += st){
    const f32x4 v = *(const f32x4*)(s + (size_t)i*4);
    s16x4 o;
    #pragma unroll
    for (int j=0;j<4;++j) o[j] = (short)f2b(v[j]);
    *(s16x4*)(d + (size_t)i*4) = o;
  }
}

// pack xpw (2,NL,48,512) -> [dir][NL][64][512] bf16 hi/lo (rows 48..63 zero)
__global__ void xpack_k(const float* __restrict__ xpw, u16* __restrict__ whi,
                        u16* __restrict__ wlo){
  const int i = blockIdx.x*256 + threadIdx.x;       // 2*NL*64*512
  const int col = i & 511, row = (i>>9) & 63, dl = i>>15;
  float w = 0.f;
  if (row < 48) w = xpw[(size_t)dl*48*512 + (size_t)row*512 + col];
  const u16 h = f2b(w);
  whi[i] = h;
  wlo[i] = f2b(w - b2f(h));
}

__global__ void aneg_k(const float* __restrict__ a, float* __restrict__ o, int n){
  int i = blockIdx.x*256 + threadIdx.x;
  if (i < n) o[i] = -__expf(a[i]);
}

__global__ void xall_k(const float* __restrict__ x, float* __restrict__ o){
  const int i = blockIdx.x*256 + threadIdx.x;           // [0, 2*4*1024*256)
  const int d = i & 255, l = (i>>8)&1023, b2 = (i>>18)&3, dir = i>>20;
  const int ls = dir ? (1023 - l) : l;
  o[i] = x[((size_t)(b2<<10) + ls)*256 + d];
}

// ---------------- LN (+residual) ----------------
template<int MODE>
__global__ __launch_bounds__(256)
void lnres_k(const float* __restrict__ s1, const float* __restrict__ s2,
             const float* __restrict__ w, const float* __restrict__ b,
             float* __restrict__ fout, u16* __restrict__ hnout)
{
  const int wv = threadIdx.x >> 6, lane = threadIdx.x & 63;
  const int tok = blockIdx.x*4 + wv;
  const int dir = tok >> 12;
  const size_t base = (size_t)tok*256 + lane*4;
  f32x4 r = *(const f32x4*)(s1 + base);
  if (s2){ f32x4 c = *(const f32x4*)(s2 + base); r += c; }
  float sv = r[0]+r[1]+r[2]+r[3];
  float qv = r[0]*r[0]+r[1]*r[1]+r[2]*r[2]+r[3]*r[3];
  #pragma unroll
  for (int o=32;o;o>>=1){ sv += __shfl_xor(sv,o); qv += __shfl_xor(qv,o); }
  const float mu = sv*(1.f/256.f);
  const float var = qv*(1.f/256.f) - mu*mu;
  const float inv = rsqrtf(var + 1e-5f);
  const int woff = (MODE==0) ? dir*(NL*256) : 0;
  const f32x4 w4 = *(const f32x4*)(w + woff + lane*4);
  const f32x4 b4 = *(const f32x4*)(b + woff + lane*4);
  f32x4 y;
  #pragma unroll
  for (int j=0;j<4;++j) y[j] = (r[j]-mu)*inv*w4[j] + b4[j];
  if constexpr (MODE==0){
    *(f32x4*)(fout + base) = r;
    s16x4 hh;
    #pragma unroll
    for (int j=0;j<4;++j) hh[j] = (short)f2b(y[j]);
    *(s16x4*)(hnout + base) = hh;
  } else {
    *(f32x4*)(fout + base) = y;
  }
}

// ---------------- MFMA bf16 GEMM: C = A @ W^T ----------------
// LDS slot-swizzle (conflict-free for ds_read_b128 8-lane phases):
// physical slot p of row m holds logical slot p ^ ((m>>1)&3);
// stage fetches inverse-permuted global slice, reads use q ^ ((r>>1)&3).
// BK=64: two 32-panels per barrier pair (half the sync/drain count).
// CFG 0: in_proj  N=1024 K=256  -> OF f32 (f_xz)
// CFG 1: out_proj N=256  K=512  -> OF f32 (f_st)
// CFG 2: moe h    z=dir*4+e, N=1024 K=256 -> OB bf16 = gate*gelu(acc+b1)
// CFG 3: moe o2   z=e*2+dir, per-expert K=1024 -> OF f32 partial[z]
// CFG 4: x_proj   split-bf16 compensated (3 phases)
template<int CFG>
__global__ __launch_bounds__(256, 2)
void gemm_k(const u16* __restrict__ A0, const u16* __restrict__ W0,
            float* OF, u16* OB,
            const float* __restrict__ P0, const float* __restrict__ P1,
            const float* __restrict__ P2)
{
  constexpr int BM = (CFG==4) ? 64 : 128;
  constexpr int BN = (CFG==1 || CFG==3 || CFG==4) ? 64 : 128;
  constexpr int KD = (CFG==0 || CFG==2) ? 256 : ((CFG==1) ? 512 : ((CFG==3) ? 1024 : 512));
  constexpr int LDA = (CFG==3) ? 4096 : KD;
  constexpr int FM = BM/32;
  constexpr int FN = BN/32;
  constexpr int IA = BM/64;
  constexpr int IB = BN/64;
  constexpr int NPH = (CFG==4) ? 3 : 1;

  __shared__ u16 sA[2*BM*32];
  __shared__ u16 sB[2*BN*32];

  const int tid = threadIdx.x;
  const int wave = tid >> 6, lane = tid & 63;
  const int bm0 = blockIdx.x * BM, bn0 = blockIdx.y * BN;
  const int z = blockIdx.z;
  const int wm0 = (wave >> 1) * (BM/2);
  const int wn0 = (wave & 1) * (BN/2);

  const u16* Az; const u16* Wz;
  int koff = 0, eoff = 0;
  if constexpr (CFG==0){ Az = A0 + (size_t)z*TPD*256;  Wz = W0 + (size_t)z*(NL*1024*256); }
  else if constexpr (CFG==1){ Az = A0 + (size_t)z*TPD*512; Wz = W0 + (size_t)z*(NL*256*512); }
  else if constexpr (CFG==2){ Az = A0 + (size_t)(z>>2)*TPD*256;
                              Wz = W0 + (size_t)(z>>2)*((size_t)NL*NE*HM*256) + (size_t)(z&3)*(HM*256); }
  else if constexpr (CFG==3){ Az = A0 + (size_t)(z&1)*TPD*4096;
         Wz = W0 + (size_t)(z&1)*((size_t)NL*NE*256*HM);
         koff = (z>>1)*1024; eoff = (z>>1)*256; }
  else { Az = A0 + (size_t)z*TPD*512; Wz = W0 + (size_t)z*(NL*64*512); }

  f32x4 acc[FM][FN];
  #pragma unroll
  for (int i=0;i<FM;++i)
    #pragma unroll
    for (int j=0;j<FN;++j) acc[i][j] = (f32x4){0.f,0.f,0.f,0.f};

  const int r = lane & 15, q = lane >> 4;
  const int qs8 = (q ^ ((r>>1)&3))*8;     // swizzled 16B-slot for LDS reads

  #pragma unroll
  for (int ph=0; ph<NPH; ++ph){
    const u16* Ap = Az; const u16* Wp = Wz;
    if constexpr (CFG==4){
      if (ph==1) Ap = (const u16*)P0 + (size_t)z*TPD*512;
      if (ph==2) Wp = (const u16*)P1 + (size_t)z*(NL*64*512);
    }
    for (int k0 = 0; k0 < KD; k0 += 64){
      #pragma unroll
      for (int pp=0;pp<2;++pp){
        const int kb = k0 + pp*32;
        #pragma unroll
        for (int j=0;j<IA;++j){
          const int c = (wave*IA + j)*64 + lane;
          const int m = c >> 2, kq = (c & 3) ^ ((m>>1)&3);
          const u16* g;
          if constexpr (CFG==3) g = Ap + (size_t)(bm0 + m)*LDA + (koff + kb + kq*8);
          else                  g = Ap + (size_t)(bm0 + m)*LDA + (kb + kq*8);
          __builtin_amdgcn_global_load_lds((const __attribute__((address_space(1))) void*)g,
              (__attribute__((address_space(3))) void*)(sA + (size_t)pp*BM*32 + (size_t)(wave*IA + j)*512), 16, 0, 0);
        }
        #pragma unroll
        for (int j=0;j<IB;++j){
          const int c = (wave*IB + j)*64 + lane;
          const int n = c >> 2, kq = (c & 3) ^ ((n>>1)&3);
          const u16* g;
          if constexpr (CFG==3){
            g = Wp + ((size_t)eoff + (bn0 + n))*1024 + (kb + kq*8);
          } else {
            g = Wp + (size_t)(bn0 + n)*KD + (kb + kq*8);
          }
          __builtin_amdgcn_global_load_lds((const __attribute__((address_space(1))) void*)g,
              (__attribute__((address_space(3))) void*)(sB + (size_t)pp*BN*32 + (size_t)(wave*IB + j)*512), 16, 0, 0);
        }
      }
      __syncthreads();
      #pragma unroll
      for (int pp=0;pp<2;++pp){
        s16x8 av[FM], bv[FN];
        #pragma unroll
        for (int mi=0;mi<FM;++mi) av[mi] = *(const s16x8*)(sA + pp*BM*32 + (wm0 + mi*16 + r)*32 + qs8);
        #pragma unroll
        for (int ni=0;ni<FN;++ni) bv[ni] = *(const s16x8*)(sB + pp*BN*32 + (wn0 + ni*16 + r)*32 + qs8);
        #pragma unroll
        for (int mi=0;mi<FM;++mi)
          #pragma unroll
          for (int ni=0;ni<FN;++ni)
            acc[mi][ni] = __builtin_amdgcn_mfma_f32_16x16x32_bf16(av[mi], bv[ni], acc[mi][ni], 0, 0, 0);
      }
      __syncthreads();
    }
  }

  #pragma unroll
  for (int mi=0;mi<FM;++mi){
    #pragma unroll
    for (int ni=0;ni<FN;++ni){
      const int col = bn0 + wn0 + ni*16 + r;
      #pragma unroll
      for (int rr=0;rr<4;++rr){
        const int row = bm0 + wm0 + mi*16 + q*4 + rr;
        const float v = acc[mi][ni][rr];
        if constexpr (CFG==0){
          OF[((size_t)z*TPD + row)*1024 + col] = v;
        } else if constexpr (CFG==1){
          OF[((size_t)z*TPD + row)*256 + col] = v;
        } else if constexpr (CFG==2){
          const int dir = z>>2, e = z&3;
          const float xv = v + P0[(size_t)dir*(NL*NE*HM) + (size_t)e*HM + col];
          const float ge = 0.5f*xv*(1.f + erff(xv*0.70710678118654752f));
          const float gt = P1[((size_t)dir*TPD + row)*4 + e];
          OB[((size_t)dir*TPD + row)*4096 + (size_t)e*1024 + col] = f2b(ge*gt);
        } else if constexpr (CFG==3){
          OF[((size_t)z*TPD + row)*256 + col] = v;   // partial[z=e*2+dir]
        } else {
          if (col < 48) OF[((size_t)z*TPD + row)*48 + col] = v;
        }
      }
    }
  }
}

// ---------------- MoE partial reduce ----------------
__global__ __launch_bounds__(256)
void moered_k(const float* __restrict__ part, const float* __restrict__ gate,
              const float* __restrict__ b2, float* __restrict__ res)
{
  const int i4 = blockIdx.x*256 + threadIdx.x;       // 0 .. TOK*64-1
  const int tok = i4 >> 6;
  const int c4 = i4 & 63;
  const int dir = tok >> 12, rr = tok & 4095;
  const float* gp = gate + (size_t)tok*4;
  const float* b2p = b2 + (size_t)dir*(NL*NE*256);
  f32x4 acc = *(f32x4*)(res + (size_t)tok*256 + c4*4);
  #pragma unroll
  for (int e=0;e<4;++e){
    const f32x4 pv = *(const f32x4*)(part + ((size_t)(e*2+dir)*TPD + rr)*256 + c4*4);
    const f32x4 bv = *(const f32x4*)(b2p + e*256 + c4*4);
    const float g = gp[e];
    acc += pv;
    acc += g*bv;
  }
  *(f32x4*)(res + (size_t)tok*256 + c4*4) = acc;
}

// ---------------- conv + silu -> split-bf16 u (for x_proj GEMM) ----------------
__global__ __launch_bounds__(256)
void conv_silu_k(const float* __restrict__ xz,
                 const float* __restrict__ cw, const float* __restrict__ cb,
                 u16* __restrict__ uhi, u16* __restrict__ ulo)
{
  const int idx = blockIdx.x*256 + threadIdx.x;     // TOK*128
  const int c4 = idx & 127;
  const int tok = idx >> 7;
  const int dir = tok >> 12, t = tok & 1023;
  const float* cwp = cw + (size_t)dir*(NL*DIN_*4) + (size_t)c4*16;
  const float* cbp = cb + (size_t)dir*(NL*DIN_);
  const f32x4 w0 = *(const f32x4*)(cwp);
  const f32x4 w1 = *(const f32x4*)(cwp + 4);
  const f32x4 w2 = *(const f32x4*)(cwp + 8);
  const f32x4 w3 = *(const f32x4*)(cwp + 12);
  const f32x4 cb4 = *(const f32x4*)(cbp + c4*4);
  f32x4 x0 = (f32x4){0,0,0,0}, x1 = x0, x2 = x0;
  if (t >= 3) x0 = *(const f32x4*)(xz + ((size_t)tok-3)*1024 + c4*4);
  if (t >= 2) x1 = *(const f32x4*)(xz + ((size_t)tok-2)*1024 + c4*4);
  if (t >= 1) x2 = *(const f32x4*)(xz + ((size_t)tok-1)*1024 + c4*4);
  const f32x4 x3 = *(const f32x4*)(xz + (size_t)tok*1024 + c4*4);
  f32x4 a;
  a[0] = cb4[0] + x0[0]*w0[0] + x1[0]*w0[1] + x2[0]*w0[2] + x3[0]*w0[3];
  a[1] = cb4[1] + x0[1]*w1[0] + x1[1]*w1[1] + x2[1]*w1[2] + x3[1]*w1[3];
  a[2] = cb4[2] + x0[2]*w2[0] + x1[2]*w2[1] + x2[2]*w2[2] + x3[2]*w2[3];
  a[3] = cb4[3] + x0[3]*w3[0] + x1[3]*w3[1] + x2[3]*w3[2] + x3[3]*w3[3];
  s16x4 hh, ll;
  #pragma unroll
  for (int j=0;j<4;++j){
    const float uv = a[j]*sigm(a[j]);
    const u16 h = f2b(uv);
    hh[j] = (short)h;
    ll[j] = (short)f2b(uv - b2f(h));
  }
  *(s16x4*)(uhi + (size_t)tok*DIN_ + c4*4) = hh;
  *(s16x4*)(ulo + (size_t)tok*DIN_ + c4*4) = ll;
}

// ---------------- chunked scan w/ fused conv (sliding window) + dt_proj ----------------
template<int PASS>
__global__ __launch_bounds__(512)
void scan_k(const float* __restrict__ xz, const float* __restrict__ xd,
            const float* __restrict__ an,
            const float* __restrict__ cw, const float* __restrict__ cb,
            const float* __restrict__ dtw, const float* __restrict__ dtb,
            const float* __restrict__ dsk,
            float* __restrict__ hp, float* __restrict__ pp,
            u16* __restrict__ ybar)
{
  const int ch = threadIdx.x;                         // 0..511
  const int blk = blockIdx.x;                         // (dir*4+b)*NCH + chunk
  const int chunk = blk & (NCH-1), bb = (blk>>6)&3, dir = blk>>8;
  const size_t seqbase = (size_t)(dir*4+bb)*1024;
  const int ltb = chunk*CLEN;
  const float* ap = an + (size_t)dir*(NL*DIN_*16) + (size_t)ch*16;
  float A_[16];
  #pragma unroll
  for (int n=0;n<16;++n) A_[n] = ap[n];
  const float* dtp = dtw + (size_t)dir*(NL*DIN_*16) + (size_t)ch*16;
  f32x4 D4[4];
  #pragma unroll
  for (int r4=0;r4<4;++r4) D4[r4] = *(const f32x4*)(dtp + r4*4);
  const float dtbc = dtb[(size_t)dir*(NL*DIN_) + ch];
  const float* cwp = cw + (size_t)dir*(NL*DIN_*4) + (size_t)ch*4;
  const float cw0 = cwp[0], cw1 = cwp[1], cw2 = cwp[2], cw3 = cwp[3];
  const float cbc = cb[(size_t)dir*(NL*DIN_) + ch];
  const size_t scanid = (size_t)(dir*4+bb)*512 + ch;
  const size_t hbase = (scanid*NCH + chunk)*16;
  float h[16], P[16];
  if constexpr (PASS==1){
    #pragma unroll
    for (int n=0;n<16;++n){ h[n]=0.f; P[n]=1.f; }
  } else {
    #pragma unroll
    for (int n=0;n<16;++n) h[n] = hp[hbase+n];
  }
  float dval = 0.f;
  if constexpr (PASS==2) dval = dsk[(size_t)dir*(NL*DIN_) + ch];
  float x0 = (ltb>=3) ? xz[(seqbase+ltb-3)*1024 + ch] : 0.f;
  float x1 = (ltb>=2) ? xz[(seqbase+ltb-2)*1024 + ch] : 0.f;
  float x2 = (ltb>=1) ? xz[(seqbase+ltb-1)*1024 + ch] : 0.f;
  for (int t=0;t<CLEN;++t){
    const size_t tok = seqbase + ltb + t;
    const float x3 = xz[tok*1024 + ch];
    const float a = cbc + x0*cw0 + x1*cw1 + x2*cw2 + x3*cw3;
    const float uv = a*sigm(a);
    x0 = x1; x1 = x2; x2 = x3;
    const float* xr = xd + tok*48;
    f32x4 dacc = (f32x4){0.f,0.f,0.f,0.f};
    #pragma unroll
    for (int r4=0;r4<4;++r4) dacc += (*(const f32x4*)(xr + r4*4)) * D4[r4];
    const float draw = dtbc + dacc[0]+dacc[1]+dacc[2]+dacc[3];
    const float dtv = (draw > 20.f) ? draw : log1pf(__expf(draw));
    const float dtu = dtv*uv;
    float y = 0.f;
    #pragma unroll
    for (int n=0;n<16;++n){
      const float e = __expf(dtv*A_[n]);
      const float hn2 = h[n]*e + dtu*xr[16+n];
      h[n] = hn2;
      if constexpr (PASS==1) P[n] *= e;
      else y += hn2*xr[32+n];
    }
    if constexpr (PASS==2){
      const float zv = xz[tok*1024 + 512 + ch];
      ybar[tok*DIN_ + ch] = f2b((y + uv*dval) * (zv * sigm(zv)));
    }
  }
  if constexpr (PASS==1){
    #pragma unroll
    for (int n=0;n<16;++n){ hp[hbase+n] = h[n]; pp[hbase+n] = P[n]; }
  }
}

// parallel fixup over (scan-id, state)
__global__ __launch_bounds__(256)
void scanfix_k(float* __restrict__ hp, const float* __restrict__ pp){
  const int id2 = blockIdx.x*256 + threadIdx.x;       // 0..65535
  const int id = id2 >> 4, n = id2 & 15;
  float s = 0.f;
  for (int c=0;c<NCH;++c){
    const size_t base = ((size_t)id*NCH + c)*16 + n;
    const float hv = hp[base];
    const float pv = pp[base];
    hp[base] = s;
    s = hv + pv*s;
  }
}

// ---------------- curr = states + resid ; gating (f32) ----------------
__global__ __launch_bounds__(256)
void currgate_k(const float* __restrict__ st, const float* __restrict__ rs,
                const float* __restrict__ gw, const float* __restrict__ gb,
                u16* __restrict__ currb, float* __restrict__ gate)
{
  const int wv = threadIdx.x>>6, lane = threadIdx.x&63;
  const int tok = blockIdx.x*4 + wv;
  const int dir = tok>>12;
  const size_t base = (size_t)tok*256 + lane*4;
  f32x4 a = *(const f32x4*)(st+base);
  { f32x4 c = *(const f32x4*)(rs+base); a += c; }
  s16x4 cc;
  #pragma unroll
  for (int j=0;j<4;++j) cc[j] = (short)f2b(a[j]);
  *(s16x4*)(currb+base) = cc;
  const float* gwp = gw + (size_t)dir*(NL*NE*256);
  float lg[4];
  #pragma unroll
  for (int e=0;e<4;++e){
    const float* w4 = gwp + e*256 + lane*4;
    lg[e] = a[0]*w4[0] + a[1]*w4[1] + a[2]*w4[2] + a[3]*w4[3];
  }
  #pragma unroll
  for (int o=32;o;o>>=1){
    #pragma unroll
    for (int e=0;e<4;++e) lg[e] += __shfl_xor(lg[e], o);
  }
  if (lane==0){
    const float* gbp = gb + dir*(NL*NE);
    float sc[4]; float mx = -1e30f;
    #pragma unroll
    for (int e=0;e<4;++e){ sc[e] = lg[e] + gbp[e]; mx = fmaxf(mx, sc[e]); }
    float den = 0.f;
    #pragma unroll
    for (int e=0;e<4;++e){ sc[e] = __expf(sc[e]-mx); den += sc[e]; }
    const float rden = 1.f/den;
    #pragma unroll
    for (int e=0;e<4;++e) sc[e] *= rden;
    int i1 = 0;
    #pragma unroll
    for (int e=1;e<4;++e) if (sc[e] > sc[i1]) i1 = e;
    int i2 = (i1==0)?1:0;
    #pragma unroll
    for (int e=0;e<4;++e) if (e!=i1 && sc[e] > sc[i2]) i2 = e;
    const float ssum = sc[i1] + sc[i2] + 1e-6f;
    #pragma unroll
    for (int e=0;e<4;++e)
      gate[(size_t)tok*4+e] = (e==i1) ? sc[i1]/ssum : ((e==i2) ? sc[i2]/ssum : 0.f);
  }
}

// ---------------- pooling (parallel) ----------------
__global__ __launch_bounds__(256)
void poolscore_k(const float* __restrict__ fin, const float* __restrict__ fw,
                 const float* __restrict__ fb, const float* __restrict__ bw,
                 const float* __restrict__ bbs, float* __restrict__ score)
{
  const int blk = blockIdx.x;                   // p = blk>>3, g = blk&7
  const int p = blk >> 3, g = blk & 7;
  const int dir = p >> 2;
  const float* pw = dir ? bw : fw;
  const float pb = dir ? bbs[0] : fb[0];
  const int wv = threadIdx.x>>6, lane = threadIdx.x&63;
  const size_t fbase = (size_t)p*1024*256;
  const f32x4 w4 = *(const f32x4*)(pw + lane*4);
  for (int l = g*128 + wv; l < (g+1)*128; l += 4){
    const f32x4 f4 = *(const f32x4*)(fin + fbase + (size_t)l*256 + lane*4);
    float pv = f4[0]*w4[0] + f4[1]*w4[1] + f4[2]*w4[2] + f4[3]*w4[3];
    #pragma unroll
    for (int o=32;o;o>>=1) pv += __shfl_xor(pv,o);
    if (lane==0) score[p*1024 + l] = pv + pb;
  }
}

__global__ __launch_bounds__(256)
void poolnorm_k(float* __restrict__ score)
{
  __shared__ float red[8];
  const int p = blockIdx.x;
  const int tid = threadIdx.x, wv = tid>>6, lane = tid&63;
  float* s = score + p*1024;
  float v[4];
  float m = -1e30f;
  #pragma unroll
  for (int j=0;j<4;++j){ v[j] = s[tid + j*256]; m = fmaxf(m, v[j]); }
  #pragma unroll
  for (int o=32;o;o>>=1) m = fmaxf(m, __shfl_xor(m,o));
  if (lane==0) red[wv] = m;
  __syncthreads();
  m = fmaxf(fmaxf(red[0],red[1]), fmaxf(red[2],red[3]));
  float ssum = 0.f;
  #pragma unroll
  for (int j=0;j<4;++j){ v[j] = __expf(v[j]-m); ssum += v[j]; }
  #pragma unroll
  for (int o=32;o;o>>=1) ssum += __shfl_xor(ssum,o);
  if (lane==0) red[4+wv] = ssum;
  __syncthreads();
  const float inv = 1.f/(red[4]+red[5]+red[6]+red[7]);
  #pragma unroll
  for (int j=0;j<4;++j) s[tid + j*256] = v[j]*inv;
}

__global__ __launch_bounds__(256)
void poolsum_k(const float* __restrict__ fin, const float* __restrict__ score,
               float* __restrict__ part)
{
  const int blk = blockIdx.x;                   // p = blk>>4, g = blk&15
  const int p = blk >> 4, g = blk & 15;
  const int d = threadIdx.x;
  const size_t fbase = (size_t)p*1024*256;
  float acc = 0.f;
  #pragma unroll 4
  for (int l = g*64; l < (g+1)*64; ++l)
    acc += score[p*1024 + l] * fin[fbase + (size_t)l*256 + d];
  part[((size_t)p*16 + g)*256 + d] = acc;
}

__global__ __launch_bounds__(256)
void head_k(const float* __restrict__ part, const float* __restrict__ llw,
            const float* __restrict__ llb, float* __restrict__ out)
{
  __shared__ float sp[2*256];
  const int d = threadIdx.x;
  const int b = blockIdx.x;                     // 0..3
  float a0 = 0.f, a1 = 0.f;
  #pragma unroll
  for (int g=0;g<16;++g){
    a0 += part[((size_t)b*16 + g)*256 + d];
    a1 += part[((size_t)(4+b)*16 + g)*256 + d];
  }
  sp[d] = a0; sp[256 + d] = a1;
  __syncthreads();
  const int o = d;
  const float* wr = llw + (size_t)o*512;
  f32x4 acc4 = (f32x4){0.f,0.f,0.f,0.f};
  #pragma unroll 8
  for (int k4=0;k4<64;++k4){
    acc4 += (*(const f32x4*)(sp + k4*4)) * (*(const f32x4*)(wr + k4*4));
  }
  #pragma unroll 8
  for (int k4=0;k4<64;++k4){
    acc4 += (*(const f32x4*)(sp + 256 + k4*4)) * (*(const f32x4*)(wr + 256 + k4*4));
  }
  out[b*256 + o] = llb[o] + acc4[0]+acc4[1]+acc4[2]+acc4[3];
}

// ---------------- host ----------------
extern "C" void kernel_launch(void* const* d_in, const int* in_sizes, int n_in,
                              void* d_out, int out_size, void* d_ws, size_t ws_size,
                              hipStream_t stream)
{
  const float* in_x    = (const float*)d_in[0];
  const float* in_inw  = (const float*)d_in[1];
  const float* in_cw   = (const float*)d_in[2];
  const float* in_cb   = (const float*)d_in[3];
  const float* in_xpw  = (const float*)d_in[4];
  const float* in_dtw  = (const float*)d_in[5];
  const float* in_dtb  = (const float*)d_in[6];
  const float* in_alog = (const float*)d_in[7];
  const float* in_dsk  = (const float*)d_in[8];
  const float* in_ow   = (const float*)d_in[9];
  const float* in_nw   = (const float*)d_in[10];
  const float* in_nb   = (const float*)d_in[11];
  const float* in_gw   = (const float*)d_in[12];
  const float* in_gb   = (const float*)d_in[13];
  const float* in_e1w  = (const float*)d_in[14];
  const float* in_e1b  = (const float*)d_in[15];
  const float* in_e2w  = (const float*)d_in[16];
  const float* in_e2b  = (const float*)d_in[17];
  const float* in_nfw  = (const float*)d_in[18];
  const float* in_nfb  = (const float*)d_in[19];
  const float* in_fpw  = (const float*)d_in[20];
  const float* in_fpb  = (const float*)d_in[21];
  const float* in_bpw  = (const float*)d_in[22];
  const float* in_bpb  = (const float*)d_in[23];
  const float* in_llw  = (const float*)d_in[24];
  const float* in_llb  = (const float*)d_in[25];

  uint8_t* ws = (uint8_t*)d_ws;
  size_t off = 0;
  auto take = [&](size_t bytes)->size_t{
    size_t o = off; off += (bytes + 255) & ~(size_t)255; return o;
  };
  float* f_xall = (float*)(ws + take((size_t)TOK*256*4));   // reused as f_fin
  float* f_res  = (float*)(ws + take((size_t)TOK*256*4));
  float* f_st   = (float*)(ws + take((size_t)TOK*256*4));
  float* f_xz   = (float*)(ws + take((size_t)TOK*1024*4));  // aliased as MoE partials
  float* f_xd   = (float*)(ws + take((size_t)TOK*48*4));
  float* f_hp   = (float*)(ws + take((size_t)4096*NCH*16*4));
  float* f_pp   = (float*)(ws + take((size_t)4096*NCH*16*4));
  float* f_gate = (float*)(ws + take((size_t)TOK*4*4));
  float* f_an   = (float*)(ws + take((size_t)2*NL*DIN_*16*4));
  float* f_score= (float*)(ws + take((size_t)8*1024*4));
  float* f_part = (float*)(ws + take((size_t)8*16*256*4));
  u16* b_hn   = (u16*)(ws + take((size_t)TOK*256*2));
  u16* b_ybar = (u16*)(ws + take((size_t)TOK*DIN_*2));
  u16* b_curr = (u16*)(ws + take((size_t)TOK*256*2));
  u16* b_uhi  = (u16*)(ws + take((size_t)TOK*DIN_*2));
  u16* b_ulo  = (u16*)(ws + take((size_t)TOK*DIN_*2));
  u16* b_h    = (u16*)(ws + take((size_t)TOK*4096*2));
  u16* b_win  = (u16*)(ws + take((size_t)2*NL*1024*256*2));
  u16* b_wout = (u16*)(ws + take((size_t)2*NL*256*512*2));
  u16* b_we1  = (u16*)(ws + take((size_t)2*NL*NE*HM*256*2));
  u16* b_we2  = (u16*)(ws + take((size_t)2*NL*NE*256*HM*2));
  u16* b_wxhi = (u16*)(ws + take((size_t)2*NL*64*512*2));
  u16* b_wxlo = (u16*)(ws + take((size_t)2*NL*64*512*2));
  float* f_fin  = f_xall;
  float* f_mp   = f_xz;       // MoE partials: [8][TPD][256] f32 (f_xz free then)
  (void)ws_size; (void)in_sizes; (void)n_in; (void)out_size;

  // prep: weights -> bf16
  cvt_bf16_k<<<1024,256,0,stream>>>(in_inw, b_win, 2*NL*1024*256/4);
  cvt_bf16_k<<<1024,256,0,stream>>>(in_ow,  b_wout, 2*NL*256*512/4);
  cvt_bf16_k<<<2048,256,0,stream>>>(in_e1w, b_we1, 2*NL*NE*HM*256/4);
  cvt_bf16_k<<<2048,256,0,stream>>>(in_e2w, b_we2, 2*NL*NE*256*HM/4);
  xpack_k<<<1024,256,0,stream>>>(in_xpw, b_wxhi, b_wxlo);
  aneg_k<<<256,256,0,stream>>>(in_alog, f_an, 2*NL*DIN_*16);
  xall_k<<<8192,256,0,stream>>>(in_x, f_xall);

  for (int i=0;i<NL;++i){
    lnres_k<0><<<2048,256,0,stream>>>(i==0 ? f_xall : f_res, i==0 ? nullptr : f_st,
                                      in_nw + i*256, in_nb + i*256, f_res, b_hn);
    gemm_k<0><<<dim3(32,8,2),256,0,stream>>>(b_hn, b_win + (size_t)i*1024*256,
                                             f_xz, nullptr, nullptr, nullptr, nullptr);
    conv_silu_k<<<4096,256,0,stream>>>(f_xz, in_cw + i*DIN_*4, in_cb + i*DIN_,
                                       b_uhi, b_ulo);
    gemm_k<4><<<dim3(64,1,2),256,0,stream>>>(b_uhi, b_wxhi + (size_t)i*64*512,
                                             f_xd, nullptr,
                                             (const float*)b_ulo,
                                             (const float*)(b_wxlo + (size_t)i*64*512),
                                             nullptr);
    scan_k<1><<<512,512,0,stream>>>(f_xz, f_xd, f_an + i*DIN_*16,
                                    in_cw + i*DIN_*4, in_cb + i*DIN_,
                                    in_dtw + i*DIN_*16, in_dtb + i*DIN_,
                                    nullptr, f_hp, f_pp, nullptr);
    scanfix_k<<<256,256,0,stream>>>(f_hp, f_pp);
    scan_k<2><<<512,512,0,stream>>>(f_xz, f_xd, f_an + i*DIN_*16,
                                    in_cw + i*DIN_*4, in_cb + i*DIN_,
                                    in_dtw + i*DIN_*16, in_dtb + i*DIN_,
                                    in_dsk + i*DIN_, f_hp, f_pp, b_ybar);
    gemm_k<1><<<dim3(32,4,2),256,0,stream>>>(b_ybar, b_wout + (size_t)i*256*512,
                                             f_st, nullptr, nullptr, nullptr, nullptr);
    currgate_k<<<2048,256,0,stream>>>(f_st, f_res, in_gw + i*NE*256, in_gb + i*NE,
                                      b_curr, f_gate);
    gemm_k<2><<<dim3(32,8,8),256,0,stream>>>(b_curr, b_we1 + (size_t)i*NE*HM*256,
                                             nullptr, b_h,
                                             in_e1b + i*NE*HM, f_gate, nullptr);
    gemm_k<3><<<dim3(32,4,8),256,0,stream>>>(b_h, b_we2 + (size_t)i*NE*256*HM,
                                             f_mp, nullptr,
                                             nullptr, nullptr, nullptr);
    moered_k<<<2048,256,0,stream>>>(f_mp, f_gate, in_e2b + i*NE*256, f_res);
  }

  lnres_k<1><<<2048,256,0,stream>>>(f_res, f_st, in_nfw, in_nfb, f_fin, nullptr);
  poolscore_k<<<64,256,0,stream>>>(f_fin, in_fpw, in_fpb, in_bpw, in_bpb, f_score);
  poolnorm_k<<<8,256,0,stream>>>(f_score);
  poolsum_k<<<128,256,0,stream>>>(f_fin, f_score, f_part);
  head_k<<<4,256,0,stream>>>(f_part, in_llw, in_llb, (float*)d_out);
}